// Round 1
// baseline (1040.752 us; speedup 1.0000x reference)
//
#include <hip/hip_runtime.h>
#include <cstddef>

// ---- problem constants (from reference) ----
#define N_U   100000
#define N_I   50000
#define DD    64
#define NNZ_  1000000
#define LL    2
#define TEMP_ 0.2f
#define LAM1  0.2f
#define DROP_ 0.1f
#define EPS_  0.05f
#define BB    2048
#define KCH   512
#define NCH_I ((N_I + KCH - 1) / KCH)   /* 98  */
#define NCH_U ((N_U + KCH - 1) / KCH)   /* 196 */
#define REGION_SZ 2097152               /* floats, time-shared scratch */

__device__ __forceinline__ float leaky(float x) { return x >= 0.0f ? x : 0.5f * x; }

__device__ __forceinline__ float waveReduceSum(float v) {
#pragma unroll
  for (int m = 32; m >= 1; m >>= 1) v += __shfl_xor(v, m, 64);
  return v;
}

__device__ __forceinline__ int rlanei(int v, int l) {
  return __builtin_amdgcn_readlane(v, l);
}
__device__ __forceinline__ float rlanef(float v, int l) {
  return __int_as_float(__builtin_amdgcn_readlane(__float_as_int(v), l));
}

// ===========================================================================
// CSR build: histogram -> scan (3-phase) -> scatter (+ edge payload build)
// ===========================================================================
__global__ void hist_kernel(const int* __restrict__ rows, const int* __restrict__ cols,
                            int* __restrict__ deg_u, int* __restrict__ deg_i, int nnz) {
  int e = blockIdx.x * blockDim.x + threadIdx.x;
  if (e >= nnz) return;
  atomicAdd(&deg_u[rows[e]], 1);
  atomicAdd(&deg_i[cols[e]], 1);
}

__global__ void scan1(const int* __restrict__ in, int* __restrict__ tmp,
                      int* __restrict__ partial, int n) {
  __shared__ int s[256];
  int t = threadIdx.x;
  int base = blockIdx.x * 1024;
  int v[4]; int tsum = 0;
#pragma unroll
  for (int k = 0; k < 4; ++k) {
    int idx = base + t * 4 + k;
    v[k] = (idx < n) ? in[idx] : 0;
    tsum += v[k];
  }
  s[t] = tsum;
  __syncthreads();
  for (int ofs = 1; ofs < 256; ofs <<= 1) {
    int x = (t >= ofs) ? s[t - ofs] : 0;
    __syncthreads();
    s[t] += x;
    __syncthreads();
  }
  if (t == 255) partial[blockIdx.x] = s[255];
  int run = (t == 0) ? 0 : s[t - 1];
#pragma unroll
  for (int k = 0; k < 4; ++k) {
    run += v[k];
    int idx = base + t * 4 + k;
    if (idx < n) tmp[idx] = run;
  }
}

__global__ void scan2(int* __restrict__ partial, int nb) {
  __shared__ int s[256];
  int t = threadIdx.x;
  s[t] = (t < nb) ? partial[t] : 0;
  __syncthreads();
  for (int ofs = 1; ofs < 256; ofs <<= 1) {
    int x = (t >= ofs) ? s[t - ofs] : 0;
    __syncthreads();
    s[t] += x;
    __syncthreads();
  }
  if (t < nb) partial[t] = (t == 0) ? 0 : s[t - 1];
}

__global__ void scan3(const int* __restrict__ tmp, const int* __restrict__ partial,
                      int* __restrict__ off, int n) {
  int i = blockIdx.x * blockDim.x + threadIdx.x;
  if (i == 0) off[0] = 0;
  if (i < n) off[i + 1] = tmp[i] + partial[i >> 10];
}

__global__ void scatter_build(const int* __restrict__ rows, const int* __restrict__ cols,
                              const float* __restrict__ vals, const float* __restrict__ dropr,
                              const int* __restrict__ off_u, const int* __restrict__ off_i,
                              int* __restrict__ cur_u, int* __restrict__ cur_i,
                              int* __restrict__ gat_u, int* __restrict__ gat_i,
                              float* __restrict__ dvu1, float* __restrict__ dvu2,
                              float* __restrict__ dvi1, float* __restrict__ dvi2,
                              int nnz) {
  int e = blockIdx.x * blockDim.x + threadIdx.x;
  if (e >= nnz) return;
  int r = rows[e], c = cols[e];
  float v = vals[e] * (1.0f / (1.0f - DROP_));
  float k0 = (dropr[e] >= DROP_) ? v : 0.0f;
  float k1 = (dropr[(size_t)NNZ_ + e] >= DROP_) ? v : 0.0f;
  float k2 = (dropr[(size_t)2 * NNZ_ + e] >= DROP_) ? v : 0.0f;
  float k3 = (dropr[(size_t)3 * NNZ_ + e] >= DROP_) ? v : 0.0f;
  int p = off_u[r] + atomicAdd(&cur_u[r], 1);
  gat_u[p] = c; dvu1[p] = k0; dvu2[p] = k2;
  int q = off_i[c] + atomicAdd(&cur_i[c], 1);
  gat_i[q] = r; dvi1[q] = k1; dvi2[q] = k3;
}

// ===========================================================================
// Layer-1 SpMM, both sides in one launch. One wave per row; lane = dim.
// ===========================================================================
__global__ void spmm_all(const int* __restrict__ off_u, const int* __restrict__ gat_u,
                         const float* __restrict__ dvu,
                         const int* __restrict__ off_i, const int* __restrict__ gat_i,
                         const float* __restrict__ dvi,
                         const float* __restrict__ Eu0, const float* __restrict__ Ei0,
                         float* __restrict__ EU1, float* __restrict__ EI1) {
  int wid = threadIdx.x >> 6, lane = threadIdx.x & 63;
  int r = blockIdx.x * 4 + wid;
  const int* off; const int* gat; const float* dv;
  const float* Esrc; const float* base; float* out;
  if (r < N_U) {
    off = off_u; gat = gat_u; dv = dvu; Esrc = Ei0; base = Eu0; out = EU1;
  } else {
    r -= N_U;
    if (r >= N_I) return;
    off = off_i; gat = gat_i; dv = dvi; Esrc = Eu0; base = Ei0; out = EI1;
  }
  int i0 = off[r], i1 = off[r + 1];
  float acc = 0.0f;
  for (int p = i0; p < i1; p += 64) {
    int cn = min(64, i1 - p);
    float dvl = 0.0f; int gl = 0;
    if (lane < cn) { dvl = dv[p + lane]; gl = gat[p + lane]; }
    int j = 0;
    for (; j + 3 < cn; j += 4) {
      float d0 = rlanef(dvl, j), d1 = rlanef(dvl, j + 1),
            d2 = rlanef(dvl, j + 2), d3 = rlanef(dvl, j + 3);
      int g0 = rlanei(gl, j), g1 = rlanei(gl, j + 1),
          g2 = rlanei(gl, j + 2), g3 = rlanei(gl, j + 3);
      float e0 = Esrc[(size_t)g0 * DD + lane];
      float e1 = Esrc[(size_t)g1 * DD + lane];
      float e2 = Esrc[(size_t)g2 * DD + lane];
      float e3 = Esrc[(size_t)g3 * DD + lane];
      acc += d0 * e0; acc += d1 * e1; acc += d2 * e2; acc += d3 * e3;
    }
    for (; j < cn; ++j)
      acc += rlanef(dvl, j) * Esrc[(size_t)rlanei(gl, j) * DD + lane];
  }
  size_t o = (size_t)r * DD + lane;
  out[o] = base[o] + leaky(acc);
}

// Layer-2 SpMM only at gathered batch rows (uids | pos | neg via blockIdx.y).
__global__ void spmm_batch3(const int* __restrict__ uids, const int* __restrict__ pos,
                            const int* __restrict__ neg,
                            const int* __restrict__ off_u, const int* __restrict__ gat_u,
                            const float* __restrict__ dvu2,
                            const int* __restrict__ off_i, const int* __restrict__ gat_i,
                            const float* __restrict__ dvi2,
                            const float* __restrict__ EU1, const float* __restrict__ EI1,
                            float* __restrict__ bu, float* __restrict__ bpos,
                            float* __restrict__ bneg) {
  int z = blockIdx.y;
  const int* ids = (z == 0) ? uids : ((z == 1) ? pos : neg);
  const int* off = (z == 0) ? off_u : off_i;
  const int* gat = (z == 0) ? gat_u : gat_i;
  const float* dv = (z == 0) ? dvu2 : dvi2;
  const float* Esrc = (z == 0) ? EI1 : EU1;
  const float* base = (z == 0) ? EU1 : EI1;
  float* out = (z == 0) ? bu : ((z == 1) ? bpos : bneg);
  int wid = threadIdx.x >> 6, lane = threadIdx.x & 63;
  int i = blockIdx.x * 4 + wid;
  int r = ids[i];
  int i0 = off[r], i1 = off[r + 1];
  float acc = 0.0f;
  for (int p = i0; p < i1; p += 64) {
    int cn = min(64, i1 - p);
    float dvl = 0.0f; int gl = 0;
    if (lane < cn) { dvl = dv[p + lane]; gl = gat[p + lane]; }
    int j = 0;
    for (; j + 3 < cn; j += 4) {
      float d0 = rlanef(dvl, j), d1 = rlanef(dvl, j + 1),
            d2 = rlanef(dvl, j + 2), d3 = rlanef(dvl, j + 3);
      int g0 = rlanei(gl, j), g1 = rlanei(gl, j + 1),
          g2 = rlanei(gl, j + 2), g3 = rlanei(gl, j + 3);
      acc += d0 * Esrc[(size_t)g0 * DD + lane];
      acc += d1 * Esrc[(size_t)g1 * DD + lane];
      acc += d2 * Esrc[(size_t)g2 * DD + lane];
      acc += d3 * Esrc[(size_t)g3 * DD + lane];
    }
    for (; j < cn; ++j)
      acc += rlanef(dvl, j) * Esrc[(size_t)rlanei(gl, j) * DD + lane];
  }
  out[(size_t)i * DD + lane] = base[(size_t)r * DD + lane] + leaky(acc);
}

// ===========================================================================
// LDS-tiled dual GEMM: C[64][64] = A[64][N] @ B[N][64], outer-product 4x4
// register tiles; one K-chunk (KCH) per block; per-chunk partials, no atomics.
// Problems packed along blockIdx.x: [0,NCH_I) -> (A0,B0,N_I), rest -> (A1,B1,N_U)
// ===========================================================================
__global__ void gemm_tiled(const float* __restrict__ A0, const float* __restrict__ B0,
                           const float* __restrict__ A1, const float* __restrict__ B1,
                           float* __restrict__ Cp) {
  __shared__ float sA[64][68];
  __shared__ float sB[64][68];
  int bx = blockIdx.x;
  const float* A; const float* B; int N; int k0;
  if (bx < NCH_I) { A = A0; B = B0; N = N_I; k0 = bx * KCH; }
  else            { A = A1; B = B1; N = N_U; k0 = (bx - NCH_I) * KCH; }
  int t = threadIdx.x;
  int ti = t >> 4, tj = t & 15;
  float acc[4][4];
#pragma unroll
  for (int x = 0; x < 4; ++x)
#pragma unroll
    for (int y = 0; y < 4; ++y) acc[x][y] = 0.0f;

  for (int tt = 0; tt < KCH / 64; ++tt) {
    int kb = k0 + tt * 64;
    if (kb >= N) break;            // uniform across block (k0,N uniform)
    __syncthreads();
#pragma unroll
    for (int it = 0; it < 16; ++it) {
      int lin = t + it * 256;
      int r = lin >> 6, c = lin & 63;
      sA[r][c] = (kb + c < N) ? A[(size_t)r * N + kb + c] : 0.0f;          // A[r][k]
      sB[r][c] = (kb + r < N) ? B[(size_t)(kb + r) * DD + c] : 0.0f;       // B[k][d]
    }
    __syncthreads();
#pragma unroll 8
    for (int k = 0; k < 64; ++k) {
      float4 b = *(const float4*)&sB[k][tj * 4];
      float a0 = sA[ti * 4 + 0][k];
      float a1 = sA[ti * 4 + 1][k];
      float a2 = sA[ti * 4 + 2][k];
      float a3 = sA[ti * 4 + 3][k];
      acc[0][0] += a0 * b.x; acc[0][1] += a0 * b.y; acc[0][2] += a0 * b.z; acc[0][3] += a0 * b.w;
      acc[1][0] += a1 * b.x; acc[1][1] += a1 * b.y; acc[1][2] += a1 * b.z; acc[1][3] += a1 * b.w;
      acc[2][0] += a2 * b.x; acc[2][1] += a2 * b.y; acc[2][2] += a2 * b.z; acc[2][3] += a2 * b.w;
      acc[3][0] += a3 * b.x; acc[3][1] += a3 * b.y; acc[3][2] += a3 * b.z; acc[3][3] += a3 * b.w;
    }
  }
  float* cp = Cp + (size_t)bx * 4096;
#pragma unroll
  for (int x = 0; x < 4; ++x)
#pragma unroll
    for (int y = 0; y < 4; ++y)
      cp[(ti * 4 + x) * DD + tj * 4 + y] = acc[x][y];
}

// fold partials: y=0 -> problem0 (NCH_I partials) -> C0; y=1 -> C1.
__global__ void gemm_reduce2(const float* __restrict__ Cp,
                             float* __restrict__ C0, float* __restrict__ C1) {
  int y = blockIdx.y;
  const float* base = Cp + (y ? (size_t)NCH_I * 4096 : 0);
  int cnt = y ? NCH_U : NCH_I;
  float* C = y ? C1 : C0;
  int idx = blockIdx.x * 256 + threadIdx.x;
  float s = 0.0f;
  for (int b = 0; b < cnt; ++b) s += base[(size_t)b * 4096 + idx];
  C[idx] = s;
}

// ===========================================================================
// h for both views and both layers of one side. hout [layer][view][BB][64].
// ===========================================================================
__global__ void h_kernel2(const float* __restrict__ svd,
                          const float* __restrict__ n1, const float* __restrict__ n2,
                          const float* __restrict__ sdiag,
                          const float* __restrict__ Mb,
                          const float* __restrict__ Wb,
                          const int*   __restrict__ ids,
                          float*       __restrict__ hout) {
  int layer = blockIdx.y;
  const float* M = Mb + layer * 4096;
  const float* W = Wb + layer * 4096;
  int wid  = threadIdx.x >> 6;
  int lane = threadIdx.x & 63;
  int i = blockIdx.x * 4 + wid;
  int id = ids[i];
  float sv = svd[(size_t)id * DD + lane];
  float sgn = (sv > 0.0f) ? 1.0f : ((sv < 0.0f) ? -1.0f : 0.0f);
  float sd = sdiag[lane];

  float z1 = n1[(size_t)id * DD + lane];
  float z2 = n2[(size_t)id * DD + lane];
  float d1 = fmaxf(sqrtf(waveReduceSum(z1 * z1)), 1e-12f);
  float d2 = fmaxf(sqrtf(waveReduceSum(z2 * z2)), 1e-12f);
  float g1 = (sv + sgn * (z1 / d1) * EPS_) * sd;
  float g2 = (sv + sgn * (z2 / d2) * EPS_) * sd;

  float a1 = 0.0f, a2 = 0.0f;
#pragma unroll
  for (int k = 0; k < 64; ++k) {
    float m = M[k * DD + lane];
    a1 += rlanef(g1, k) * m;
    a2 += rlanef(g2, k) * m;
  }
  a1 = leaky(a1); a2 = leaky(a2);
  float s1 = fmaxf(sqrtf(waveReduceSum(a1 * a1)), 1e-12f);
  float s2 = fmaxf(sqrtf(waveReduceSum(a2 * a2)), 1e-12f);
  float gn1 = a1 / s1, gn2 = a2 / s2;

  float h1 = 0.0f, h2 = 0.0f;
#pragma unroll
  for (int k = 0; k < 64; ++k) {
    float w = W[k * DD + lane];
    h1 += rlanef(gn1, k) * w;
    h2 += rlanef(gn2, k) * w;
  }
  size_t b0 = ((size_t)(layer * 2 + 0) * BB + i) * DD + lane;
  size_t b1 = ((size_t)(layer * 2 + 1) * BB + i) * DD + lane;
  hout[b0] = h1;
  hout[b1] = h2;
}

// ===========================================================================
// score tiles: 64x64 tile of exp(S/T), row-sum partials (non-atomic)
// ===========================================================================
__global__ void score_tiles(const float* __restrict__ hu, const float* __restrict__ hv,
                            float* __restrict__ negpart) {
  __shared__ float s1[64][65];
  __shared__ float s2[64][65];
  int z = blockIdx.z;
  int layer = z >> 1, side = z & 1;
  const float* hb = side ? hv : hu;
  const float* h1 = hb + (size_t)(layer * 2 + 0) * BB * DD;
  const float* h2 = hb + (size_t)(layer * 2 + 1) * BB * DD;
  int i0 = blockIdx.x * 64, j0 = blockIdx.y * 64;
  int t = threadIdx.x;
#pragma unroll
  for (int k = 0; k < 16; ++k) {
    int lin = t + k * 256;
    int r = lin >> 6, c = lin & 63;
    s1[r][c] = h1[(size_t)(i0 + r) * DD + c];
    s2[r][c] = h2[(size_t)(j0 + r) * DD + c];
  }
  __syncthreads();
  int ti = t >> 4, tj = t & 15;
  float acc[4][4];
#pragma unroll
  for (int x = 0; x < 4; ++x)
#pragma unroll
    for (int y = 0; y < 4; ++y) acc[x][y] = 0.0f;
  for (int d = 0; d < 64; ++d) {
    float a[4], b[4];
#pragma unroll
    for (int k = 0; k < 4; ++k) { a[k] = s1[ti * 4 + k][d]; b[k] = s2[tj * 4 + k][d]; }
#pragma unroll
    for (int x = 0; x < 4; ++x)
#pragma unroll
      for (int y = 0; y < 4; ++y) acc[x][y] += a[x] * b[y];
  }
  float rsum[4];
#pragma unroll
  for (int x = 0; x < 4; ++x) {
    float s = 0.0f;
#pragma unroll
    for (int y = 0; y < 4; ++y) s += expf(acc[x][y] * (1.0f / TEMP_));
    rsum[x] = s;
  }
  __syncthreads();
#pragma unroll
  for (int x = 0; x < 4; ++x) s1[ti * 4 + x][tj] = rsum[x];
  __syncthreads();
  if (t < 64) {
    float s = 0.0f;
#pragma unroll
    for (int c = 0; c < 16; ++c) s += s1[t][c];
    negpart[((size_t)z * 32 + blockIdx.y) * BB + i0 + t] = s;
  }
}

__global__ void score_loss(const float* __restrict__ hu, const float* __restrict__ hv,
                           const float* __restrict__ negpart,
                           const float* __restrict__ u_mask, const float* __restrict__ i_mask,
                           float* __restrict__ loss_acc) {
  __shared__ float red[256];
  int z = blockIdx.y;
  int layer = z >> 1, side = z & 1;
  const float* hb = side ? hv : hu;
  const float* h1 = hb + (size_t)(layer * 2 + 0) * BB * DD;
  const float* h2 = hb + (size_t)(layer * 2 + 1) * BB * DD;
  const float* mask = (side ? i_mask : u_mask) + layer * BB;
  int i = blockIdx.x * 256 + threadIdx.x;
  const float4* a = (const float4*)(h1 + (size_t)i * DD);
  const float4* b = (const float4*)(h2 + (size_t)i * DD);
  float pos = 0.0f;
#pragma unroll
  for (int k = 0; k < 16; ++k) {
    float4 av = a[k], bv = b[k];
    pos += av.x * bv.x + av.y * bv.y + av.z * bv.z + av.w * bv.w;
  }
  float ng = 0.0f;
  for (int jt = 0; jt < 32; ++jt) ng += negpart[((size_t)z * 32 + jt) * BB + i];
  float ps = expf(pos * (1.0f / TEMP_));
  float m = (mask[i] > 0.5f) ? 1.0f : 0.0f;
  float li = -logf(ps / (ng + 1e-8f) + 1e-8f) * m;
  red[threadIdx.x] = li;
  __syncthreads();
  for (int ofs = 128; ofs >= 1; ofs >>= 1) {
    if (threadIdx.x < ofs) red[threadIdx.x] += red[threadIdx.x + ofs];
    __syncthreads();
  }
  if (threadIdx.x == 0) unsafeAtomicAdd(loss_acc, red[0]);
}

// ===========================================================================
// BPR
// ===========================================================================
__global__ void bpr_kernel(const float* __restrict__ Eu0, const float* __restrict__ EU1,
                           const float* __restrict__ bu,
                           const float* __restrict__ Ei0, const float* __restrict__ EI1,
                           const float* __restrict__ bpos, const float* __restrict__ bneg,
                           const int* __restrict__ uids, const int* __restrict__ pos,
                           const int* __restrict__ neg,
                           float* __restrict__ acc_r) {
  __shared__ float red[256];
  int i = blockIdx.x * 256 + threadIdx.x;
  const float4* u0 = (const float4*)(Eu0 + (size_t)uids[i] * DD);
  const float4* u1 = (const float4*)(EU1 + (size_t)uids[i] * DD);
  const float4* u2 = (const float4*)(bu  + (size_t)i * DD);
  const float4* p0 = (const float4*)(Ei0 + (size_t)pos[i] * DD);
  const float4* p1 = (const float4*)(EI1 + (size_t)pos[i] * DD);
  const float4* p2 = (const float4*)(bpos + (size_t)i * DD);
  const float4* n0 = (const float4*)(Ei0 + (size_t)neg[i] * DD);
  const float4* n1 = (const float4*)(EI1 + (size_t)neg[i] * DD);
  const float4* n2 = (const float4*)(bneg + (size_t)i * DD);
  float ps = 0.0f, ns = 0.0f;
#pragma unroll
  for (int k = 0; k < 16; ++k) {
    float4 ua = u0[k], ub = u1[k], uc = u2[k];
    float4 pa = p0[k], pb = p1[k], pc = p2[k];
    float4 na = n0[k], nb = n1[k], nc = n2[k];
    float ux = ua.x + ub.x + uc.x, uy = ua.y + ub.y + uc.y,
          uz = ua.z + ub.z + uc.z, uw = ua.w + ub.w + uc.w;
    ps += ux * (pa.x + pb.x + pc.x) + uy * (pa.y + pb.y + pc.y)
        + uz * (pa.z + pb.z + pc.z) + uw * (pa.w + pb.w + pc.w);
    ns += ux * (na.x + nb.x + nc.x) + uy * (na.y + nb.y + nc.y)
        + uz * (na.z + nb.z + nc.z) + uw * (na.w + nb.w + nc.w);
  }
  red[threadIdx.x] = fmaxf(1.0f - ps + ns, 0.0f);
  __syncthreads();
  for (int ofs = 128; ofs >= 1; ofs >>= 1) {
    if (threadIdx.x < ofs) red[threadIdx.x] += red[threadIdx.x + ofs];
    __syncthreads();
  }
  if (threadIdx.x == 0) unsafeAtomicAdd(acc_r, red[0]);
}

__global__ void finalize_kernel(const float* __restrict__ acc, float* __restrict__ out) {
  float lr = acc[0] / (float)BB;
  float ls = acc[1];
  out[0] = lr + LAM1 * ls;
  out[1] = lr;
  out[2] = ls;
}

// ===========================================================================
extern "C" void kernel_launch(void* const* d_in, const int* in_sizes, int n_in,
                              void* d_out, int out_size, void* d_ws, size_t ws_size,
                              hipStream_t stream) {
  const float* E_u_0   = (const float*)d_in[0];
  const float* E_i_0   = (const float*)d_in[1];
  const float* svd_u   = (const float*)d_in[2];
  const float* svd_v   = (const float*)d_in[3];
  const float* sdiag   = (const float*)d_in[4];
  const float* ut      = (const float*)d_in[5];
  const float* vt      = (const float*)d_in[6];
  const float* W_u     = (const float*)d_in[7];
  const float* W_i     = (const float*)d_in[8];
  const float* adjv    = (const float*)d_in[9];
  const float* dropr   = (const float*)d_in[10];
  const float* noise_u1= (const float*)d_in[11];
  const float* noise_v1= (const float*)d_in[12];
  const float* noise_u2= (const float*)d_in[13];
  const float* noise_v2= (const float*)d_in[14];
  const float* u_mask  = (const float*)d_in[15];
  const float* i_mask  = (const float*)d_in[16];
  const int*   rows    = (const int*)d_in[17];
  const int*   cols    = (const int*)d_in[18];
  const int*   uids    = (const int*)d_in[19];
  const int*   iids    = (const int*)d_in[20];
  const int*   pos     = (const int*)d_in[21];
  const int*   neg     = (const int*)d_in[22];
  float* out = (float*)d_out;

  // ---- workspace layout (~72 MB, with aliasing) ----
  float* ws     = (float*)d_ws;
  float* EU1    = ws;                           // 6,400,000
  float* EI1    = EU1 + (size_t)N_U * DD;       // 3,200,000
  float* vtei   = EI1 + (size_t)N_I * DD;       // 2*4096
  float* uteu   = vtei + 2 * DD * DD;           // 2*4096
  float* accs   = uteu + 2 * DD * DD;           // 16
  float* region = accs + 16;                    // REGION_SZ floats (time-shared)
  // phase A (gemm partials): (NCH_I+NCH_U)*4096 = 1,204,224 < REGION_SZ
  float* Cp   = region;
  // phase B (post-gemm buffers):
  float* bu   = region;                          // 131072
  float* bpos = bu   + (size_t)BB * DD;          // 131072
  float* bneg = bpos + (size_t)BB * DD;          // 131072
  float* hu   = bneg + (size_t)BB * DD;          // 524288
  float* hv   = hu   + (size_t)4 * BB * DD;      // 524288
  float* negp = hv   + (size_t)4 * BB * DD;      // 262144 (sum 1,703,936 < REGION_SZ)
  float* dvu1 = region + (size_t)REGION_SZ;      // 1,000,000
  float* dvu2 = dvu1 + NNZ_;                    // 1,000,000
  float* dvi1 = dvu2 + NNZ_;                    // 1,000,000
  float* dvi2 = dvi1 + NNZ_;                    // 1,000,000
  int* gat_u = (int*)(dvi2 + NNZ_);             // 1,000,000
  int* gat_i = gat_u + NNZ_;                    // 1,000,000
  int* off_u = gat_i + NNZ_;                    // 100,001
  int* off_i = off_u + (N_U + 1);               // 50,001
  int* cur_u = off_i + (N_I + 1);               // 100,000
  int* cur_i = cur_u + N_U;                     // 50,000
  int* spart = cur_i + N_I;                     // 256
  // scan temps alias edge-payload space (free until scatter_build):
  int* stmp  = (int*)dvu1;                      // <= N_U
  int* deg_u = (int*)dvu2;                      // N_U
  int* deg_i = deg_u + N_U;                     // N_I

  const int TB = 256;
  dim3 blk(TB);
  int eg = (NNZ_ + TB - 1) / TB;
  int row_grid = BB / 4;

  hipMemsetAsync(deg_u, 0, (size_t)(N_U + N_I) * sizeof(int), stream);
  hipMemsetAsync(cur_u, 0, (size_t)(N_U + N_I) * sizeof(int), stream);
  hipMemsetAsync(accs, 0, 16 * sizeof(float), stream);

  // ---- CSR build + edge payloads ----
  hist_kernel<<<eg, blk, 0, stream>>>(rows, cols, deg_u, deg_i, NNZ_);
  {
    int nb_u = (N_U + 1023) / 1024, nb_i = (N_I + 1023) / 1024;
    scan1<<<nb_u, blk, 0, stream>>>(deg_u, stmp, spart, N_U);
    scan2<<<1, blk, 0, stream>>>(spart, nb_u);
    scan3<<<(N_U + TB - 1) / TB, blk, 0, stream>>>(stmp, spart, off_u, N_U);
    scan1<<<nb_i, blk, 0, stream>>>(deg_i, stmp, spart, N_I);
    scan2<<<1, blk, 0, stream>>>(spart, nb_i);
    scan3<<<(N_I + TB - 1) / TB, blk, 0, stream>>>(stmp, spart, off_i, N_I);
  }
  scatter_build<<<eg, blk, 0, stream>>>(rows, cols, adjv, dropr, off_u, off_i,
                                        cur_u, cur_i, gat_u, gat_i,
                                        dvu1, dvu2, dvi1, dvi2, NNZ_);

  // ---- layer-1 small GEMMs (LDS-tiled outer-product, partials, reduce) ----
  gemm_tiled<<<NCH_I + NCH_U, blk, 0, stream>>>(vt, E_i_0, ut, E_u_0, Cp);
  gemm_reduce2<<<dim3(16, 2), blk, 0, stream>>>(Cp, vtei, uteu);

  // ---- layer-1 full SpMM, both sides fused ----
  spmm_all<<<(N_U + N_I + 3) / 4, blk, 0, stream>>>(off_u, gat_u, dvu1,
                                                    off_i, gat_i, dvi1,
                                                    E_u_0, E_i_0, EU1, EI1);

  // ---- layer-2 small GEMMs ----
  gemm_tiled<<<NCH_I + NCH_U, blk, 0, stream>>>(vt, EI1, ut, EU1, Cp);
  gemm_reduce2<<<dim3(16, 2), blk, 0, stream>>>(Cp, vtei + 4096, uteu + 4096);

  // ---- layer-2 SpMM at batch rows only (region now free for phase B) ----
  spmm_batch3<<<dim3(row_grid, 3), blk, 0, stream>>>(uids, pos, neg,
      off_u, gat_u, dvu2, off_i, gat_i, dvi2, EU1, EI1, bu, bpos, bneg);

  // ---- contrastive ----
  h_kernel2<<<dim3(row_grid, LL), blk, 0, stream>>>(svd_u, noise_u1, noise_u2, sdiag,
                                                    vtei, W_u, uids, hu);
  h_kernel2<<<dim3(row_grid, LL), blk, 0, stream>>>(svd_v, noise_v1, noise_v2, sdiag,
                                                    uteu, W_i, iids, hv);
  score_tiles<<<dim3(32, 32, 4), blk, 0, stream>>>(hu, hv, negp);
  score_loss<<<dim3(8, 4), blk, 0, stream>>>(hu, hv, negp, u_mask, i_mask, accs + 1);

  // ---- BPR ----
  bpr_kernel<<<8, blk, 0, stream>>>(E_u_0, EU1, bu, E_i_0, EI1, bpos, bneg,
                                    uids, pos, neg, accs);

  finalize_kernel<<<1, 1, 0, stream>>>(accs, out);
}

// Round 3
// 970.313 us; speedup vs baseline: 1.0726x; 1.0726x over previous
//
#include <hip/hip_runtime.h>
#include <cstddef>

// ---- problem constants (from reference) ----
#define N_U   100000
#define N_I   50000
#define DD    64
#define NNZ_  1000000
#define LL    2
#define TEMP_ 0.2f
#define LAM1  0.2f
#define DROP_ 0.1f
#define EPS_  0.05f
#define BB    2048
#define KCH   512
#define NCH_I ((N_I + KCH - 1) / KCH)   /* 98  */
#define NCH_U ((N_U + KCH - 1) / KCH)   /* 196 */
#define REGION_SZ 2097152               /* floats, time-shared scratch */

__device__ __forceinline__ float leaky(float x) { return x >= 0.0f ? x : 0.5f * x; }

__device__ __forceinline__ float waveReduceSum(float v) {
#pragma unroll
  for (int m = 32; m >= 1; m >>= 1) v += __shfl_xor(v, m, 64);
  return v;
}

__device__ __forceinline__ int rlanei(int v, int l) {
  return __builtin_amdgcn_readlane(v, l);
}
__device__ __forceinline__ float rlanef(float v, int l) {
  return __int_as_float(__builtin_amdgcn_readlane(__float_as_int(v), l));
}

// ===========================================================================
// CSR build: histogram -> scan (3-phase) -> scatter (+ packed edge payload)
// Payload per side per edge: float4 { bitcast(gather_id), k_layer1, k_layer2, 0 }
// -> ONE 16B store per side (1 cache line) instead of three 4B stores
//    (3 lines).  This is the write-amplification fix: 6 dirty lines/edge -> 2.
// ===========================================================================
__global__ void hist_kernel(const int* __restrict__ rows, const int* __restrict__ cols,
                            int* __restrict__ deg_u, int* __restrict__ deg_i, int nnz) {
  int e = blockIdx.x * blockDim.x + threadIdx.x;
  if (e >= nnz) return;
  atomicAdd(&deg_u[rows[e]], 1);
  atomicAdd(&deg_i[cols[e]], 1);
}

__global__ void scan1(const int* __restrict__ in, int* __restrict__ tmp,
                      int* __restrict__ partial, int n) {
  __shared__ int s[256];
  int t = threadIdx.x;
  int base = blockIdx.x * 1024;
  int v[4]; int tsum = 0;
#pragma unroll
  for (int k = 0; k < 4; ++k) {
    int idx = base + t * 4 + k;
    v[k] = (idx < n) ? in[idx] : 0;
    tsum += v[k];
  }
  s[t] = tsum;
  __syncthreads();
  for (int ofs = 1; ofs < 256; ofs <<= 1) {
    int x = (t >= ofs) ? s[t - ofs] : 0;
    __syncthreads();
    s[t] += x;
    __syncthreads();
  }
  if (t == 255) partial[blockIdx.x] = s[255];
  int run = (t == 0) ? 0 : s[t - 1];
#pragma unroll
  for (int k = 0; k < 4; ++k) {
    run += v[k];
    int idx = base + t * 4 + k;
    if (idx < n) tmp[idx] = run;
  }
}

__global__ void scan2(int* __restrict__ partial, int nb) {
  __shared__ int s[256];
  int t = threadIdx.x;
  s[t] = (t < nb) ? partial[t] : 0;
  __syncthreads();
  for (int ofs = 1; ofs < 256; ofs <<= 1) {
    int x = (t >= ofs) ? s[t - ofs] : 0;
    __syncthreads();
    s[t] += x;
    __syncthreads();
  }
  if (t < nb) partial[t] = (t == 0) ? 0 : s[t - 1];
}

__global__ void scan3(const int* __restrict__ tmp, const int* __restrict__ partial,
                      int* __restrict__ off, int n) {
  int i = blockIdx.x * blockDim.x + threadIdx.x;
  if (i == 0) off[0] = 0;
  if (i < n) off[i + 1] = tmp[i] + partial[i >> 10];
}

__global__ void scatter_build(const int* __restrict__ rows, const int* __restrict__ cols,
                              const float* __restrict__ vals, const float* __restrict__ dropr,
                              const int* __restrict__ off_u, const int* __restrict__ off_i,
                              int* __restrict__ cur_u, int* __restrict__ cur_i,
                              float4* __restrict__ pu, float4* __restrict__ pi,
                              int nnz) {
  int e = blockIdx.x * blockDim.x + threadIdx.x;
  if (e >= nnz) return;
  int r = rows[e], c = cols[e];
  float v = vals[e] * (1.0f / (1.0f - DROP_));
  float k0 = (dropr[e] >= DROP_) ? v : 0.0f;                      // layer1, u-side
  float k1 = (dropr[(size_t)NNZ_ + e] >= DROP_) ? v : 0.0f;       // layer1, i-side
  float k2 = (dropr[(size_t)2 * NNZ_ + e] >= DROP_) ? v : 0.0f;   // layer2, u-side
  float k3 = (dropr[(size_t)3 * NNZ_ + e] >= DROP_) ? v : 0.0f;   // layer2, i-side
  int p = off_u[r] + atomicAdd(&cur_u[r], 1);
  pu[p] = make_float4(__int_as_float(c), k0, k2, 0.0f);
  int q = off_i[c] + atomicAdd(&cur_i[c], 1);
  pi[q] = make_float4(__int_as_float(r), k1, k3, 0.0f);
}

// ===========================================================================
// Layer-1 SpMM, both sides in one launch. One wave per row; lane = dim.
// Payload read: one float4 per lane (.x = gather id bits, .y = layer-1 dv).
// ===========================================================================
__global__ void spmm_all(const int* __restrict__ off_u, const float4* __restrict__ pu,
                         const int* __restrict__ off_i, const float4* __restrict__ pi,
                         const float* __restrict__ Eu0, const float* __restrict__ Ei0,
                         float* __restrict__ EU1, float* __restrict__ EI1) {
  int wid = threadIdx.x >> 6, lane = threadIdx.x & 63;
  int r = blockIdx.x * 4 + wid;
  const int* off; const float4* pay;
  const float* Esrc; const float* base; float* out;
  if (r < N_U) {
    off = off_u; pay = pu; Esrc = Ei0; base = Eu0; out = EU1;
  } else {
    r -= N_U;
    if (r >= N_I) return;
    off = off_i; pay = pi; Esrc = Eu0; base = Ei0; out = EI1;
  }
  int i0 = off[r], i1 = off[r + 1];
  float acc = 0.0f;
  for (int p = i0; p < i1; p += 64) {
    int cn = min(64, i1 - p);
    float dvl = 0.0f; int gl = 0;
    if (lane < cn) {
      float4 pl = pay[p + lane];
      gl = __float_as_int(pl.x);
      dvl = pl.y;
    }
    int j = 0;
    for (; j + 3 < cn; j += 4) {
      float d0 = rlanef(dvl, j), d1 = rlanef(dvl, j + 1),
            d2 = rlanef(dvl, j + 2), d3 = rlanef(dvl, j + 3);
      int g0 = rlanei(gl, j), g1 = rlanei(gl, j + 1),
          g2 = rlanei(gl, j + 2), g3 = rlanei(gl, j + 3);
      float e0 = Esrc[(size_t)g0 * DD + lane];
      float e1 = Esrc[(size_t)g1 * DD + lane];
      float e2 = Esrc[(size_t)g2 * DD + lane];
      float e3 = Esrc[(size_t)g3 * DD + lane];
      acc += d0 * e0; acc += d1 * e1; acc += d2 * e2; acc += d3 * e3;
    }
    for (; j < cn; ++j)
      acc += rlanef(dvl, j) * Esrc[(size_t)rlanei(gl, j) * DD + lane];
  }
  size_t o = (size_t)r * DD + lane;
  out[o] = base[o] + leaky(acc);
}

// Layer-2 SpMM only at gathered batch rows (uids | pos | neg via blockIdx.y).
// Payload read: .x = gather id bits, .z = layer-2 dv.
__global__ void spmm_batch3(const int* __restrict__ uids, const int* __restrict__ pos,
                            const int* __restrict__ neg,
                            const int* __restrict__ off_u, const float4* __restrict__ pu,
                            const int* __restrict__ off_i, const float4* __restrict__ pi,
                            const float* __restrict__ EU1, const float* __restrict__ EI1,
                            float* __restrict__ bu, float* __restrict__ bpos,
                            float* __restrict__ bneg) {
  int z = blockIdx.y;
  const int* ids = (z == 0) ? uids : ((z == 1) ? pos : neg);
  const int* off = (z == 0) ? off_u : off_i;
  const float4* pay = (z == 0) ? pu : pi;
  const float* Esrc = (z == 0) ? EI1 : EU1;
  const float* base = (z == 0) ? EU1 : EI1;
  float* out = (z == 0) ? bu : ((z == 1) ? bpos : bneg);
  int wid = threadIdx.x >> 6, lane = threadIdx.x & 63;
  int i = blockIdx.x * 4 + wid;
  int r = ids[i];
  int i0 = off[r], i1 = off[r + 1];
  float acc = 0.0f;
  for (int p = i0; p < i1; p += 64) {
    int cn = min(64, i1 - p);
    float dvl = 0.0f; int gl = 0;
    if (lane < cn) {
      float4 pl = pay[p + lane];
      gl = __float_as_int(pl.x);
      dvl = pl.z;
    }
    int j = 0;
    for (; j + 3 < cn; j += 4) {
      float d0 = rlanef(dvl, j), d1 = rlanef(dvl, j + 1),
            d2 = rlanef(dvl, j + 2), d3 = rlanef(dvl, j + 3);
      int g0 = rlanei(gl, j), g1 = rlanei(gl, j + 1),
          g2 = rlanei(gl, j + 2), g3 = rlanei(gl, j + 3);
      acc += d0 * Esrc[(size_t)g0 * DD + lane];
      acc += d1 * Esrc[(size_t)g1 * DD + lane];
      acc += d2 * Esrc[(size_t)g2 * DD + lane];
      acc += d3 * Esrc[(size_t)g3 * DD + lane];
    }
    for (; j < cn; ++j)
      acc += rlanef(dvl, j) * Esrc[(size_t)rlanei(gl, j) * DD + lane];
  }
  out[(size_t)i * DD + lane] = base[(size_t)r * DD + lane] + leaky(acc);
}

// ===========================================================================
// LDS-tiled dual GEMM: C[64][64] = A[64][N] @ B[N][64], outer-product 4x4
// register tiles; one K-chunk (KCH) per block; per-chunk partials, no atomics.
// Problems packed along blockIdx.x: [0,NCH_I) -> (A0,B0,N_I), rest -> (A1,B1,N_U)
// ===========================================================================
__global__ void gemm_tiled(const float* __restrict__ A0, const float* __restrict__ B0,
                           const float* __restrict__ A1, const float* __restrict__ B1,
                           float* __restrict__ Cp) {
  __shared__ float sA[64][68];
  __shared__ float sB[64][68];
  int bx = blockIdx.x;
  const float* A; const float* B; int N; int k0;
  if (bx < NCH_I) { A = A0; B = B0; N = N_I; k0 = bx * KCH; }
  else            { A = A1; B = B1; N = N_U; k0 = (bx - NCH_I) * KCH; }
  int t = threadIdx.x;
  int ti = t >> 4, tj = t & 15;
  float acc[4][4];
#pragma unroll
  for (int x = 0; x < 4; ++x)
#pragma unroll
    for (int y = 0; y < 4; ++y) acc[x][y] = 0.0f;

  for (int tt = 0; tt < KCH / 64; ++tt) {
    int kb = k0 + tt * 64;
    if (kb >= N) break;            // uniform across block (k0,N uniform)
    __syncthreads();
#pragma unroll
    for (int it = 0; it < 16; ++it) {
      int lin = t + it * 256;
      int r = lin >> 6, c = lin & 63;
      sA[r][c] = (kb + c < N) ? A[(size_t)r * N + kb + c] : 0.0f;          // A[r][k]
      sB[r][c] = (kb + r < N) ? B[(size_t)(kb + r) * DD + c] : 0.0f;       // B[k][d]
    }
    __syncthreads();
#pragma unroll 8
    for (int k = 0; k < 64; ++k) {
      float4 b = *(const float4*)&sB[k][tj * 4];
      float a0 = sA[ti * 4 + 0][k];
      float a1 = sA[ti * 4 + 1][k];
      float a2 = sA[ti * 4 + 2][k];
      float a3 = sA[ti * 4 + 3][k];
      acc[0][0] += a0 * b.x; acc[0][1] += a0 * b.y; acc[0][2] += a0 * b.z; acc[0][3] += a0 * b.w;
      acc[1][0] += a1 * b.x; acc[1][1] += a1 * b.y; acc[1][2] += a1 * b.z; acc[1][3] += a1 * b.w;
      acc[2][0] += a2 * b.x; acc[2][1] += a2 * b.y; acc[2][2] += a2 * b.z; acc[2][3] += a2 * b.w;
      acc[3][0] += a3 * b.x; acc[3][1] += a3 * b.y; acc[3][2] += a3 * b.z; acc[3][3] += a3 * b.w;
    }
  }
  float* cp = Cp + (size_t)bx * 4096;
#pragma unroll
  for (int x = 0; x < 4; ++x)
#pragma unroll
    for (int y = 0; y < 4; ++y)
      cp[(ti * 4 + x) * DD + tj * 4 + y] = acc[x][y];
}

// fold partials: y=0 -> problem0 (NCH_I partials) -> C0; y=1 -> C1.
__global__ void gemm_reduce2(const float* __restrict__ Cp,
                             float* __restrict__ C0, float* __restrict__ C1) {
  int y = blockIdx.y;
  const float* base = Cp + (y ? (size_t)NCH_I * 4096 : 0);
  int cnt = y ? NCH_U : NCH_I;
  float* C = y ? C1 : C0;
  int idx = blockIdx.x * 256 + threadIdx.x;
  float s = 0.0f;
  for (int b = 0; b < cnt; ++b) s += base[(size_t)b * 4096 + idx];
  C[idx] = s;
}

// ===========================================================================
// h for both views and both layers of one side. hout [layer][view][BB][64].
// ===========================================================================
__global__ void h_kernel2(const float* __restrict__ svd,
                          const float* __restrict__ n1, const float* __restrict__ n2,
                          const float* __restrict__ sdiag,
                          const float* __restrict__ Mb,
                          const float* __restrict__ Wb,
                          const int*   __restrict__ ids,
                          float*       __restrict__ hout) {
  int layer = blockIdx.y;
  const float* M = Mb + layer * 4096;
  const float* W = Wb + layer * 4096;
  int wid  = threadIdx.x >> 6;
  int lane = threadIdx.x & 63;
  int i = blockIdx.x * 4 + wid;
  int id = ids[i];
  float sv = svd[(size_t)id * DD + lane];
  float sgn = (sv > 0.0f) ? 1.0f : ((sv < 0.0f) ? -1.0f : 0.0f);
  float sd = sdiag[lane];

  float z1 = n1[(size_t)id * DD + lane];
  float z2 = n2[(size_t)id * DD + lane];
  float d1 = fmaxf(sqrtf(waveReduceSum(z1 * z1)), 1e-12f);
  float d2 = fmaxf(sqrtf(waveReduceSum(z2 * z2)), 1e-12f);
  float g1 = (sv + sgn * (z1 / d1) * EPS_) * sd;
  float g2 = (sv + sgn * (z2 / d2) * EPS_) * sd;

  float a1 = 0.0f, a2 = 0.0f;
#pragma unroll
  for (int k = 0; k < 64; ++k) {
    float m = M[k * DD + lane];
    a1 += rlanef(g1, k) * m;
    a2 += rlanef(g2, k) * m;
  }
  a1 = leaky(a1); a2 = leaky(a2);
  float s1 = fmaxf(sqrtf(waveReduceSum(a1 * a1)), 1e-12f);
  float s2 = fmaxf(sqrtf(waveReduceSum(a2 * a2)), 1e-12f);
  float gn1 = a1 / s1, gn2 = a2 / s2;

  float h1 = 0.0f, h2 = 0.0f;
#pragma unroll
  for (int k = 0; k < 64; ++k) {
    float w = W[k * DD + lane];
    h1 += rlanef(gn1, k) * w;
    h2 += rlanef(gn2, k) * w;
  }
  size_t b0 = ((size_t)(layer * 2 + 0) * BB + i) * DD + lane;
  size_t b1 = ((size_t)(layer * 2 + 1) * BB + i) * DD + lane;
  hout[b0] = h1;
  hout[b1] = h2;
}

// ===========================================================================
// score tiles: 64x64 tile of exp(S/T), row-sum partials (non-atomic)
// ===========================================================================
__global__ void score_tiles(const float* __restrict__ hu, const float* __restrict__ hv,
                            float* __restrict__ negpart) {
  __shared__ float s1[64][65];
  __shared__ float s2[64][65];
  int z = blockIdx.z;
  int layer = z >> 1, side = z & 1;
  const float* hb = side ? hv : hu;
  const float* h1 = hb + (size_t)(layer * 2 + 0) * BB * DD;
  const float* h2 = hb + (size_t)(layer * 2 + 1) * BB * DD;
  int i0 = blockIdx.x * 64, j0 = blockIdx.y * 64;
  int t = threadIdx.x;
#pragma unroll
  for (int k = 0; k < 16; ++k) {
    int lin = t + k * 256;
    int r = lin >> 6, c = lin & 63;
    s1[r][c] = h1[(size_t)(i0 + r) * DD + c];
    s2[r][c] = h2[(size_t)(j0 + r) * DD + c];
  }
  __syncthreads();
  int ti = t >> 4, tj = t & 15;
  float acc[4][4];
#pragma unroll
  for (int x = 0; x < 4; ++x)
#pragma unroll
    for (int y = 0; y < 4; ++y) acc[x][y] = 0.0f;
  for (int d = 0; d < 64; ++d) {
    float a[4], b[4];
#pragma unroll
    for (int k = 0; k < 4; ++k) { a[k] = s1[ti * 4 + k][d]; b[k] = s2[tj * 4 + k][d]; }
#pragma unroll
    for (int x = 0; x < 4; ++x)
#pragma unroll
      for (int y = 0; y < 4; ++y) acc[x][y] += a[x] * b[y];
  }
  float rsum[4];
#pragma unroll
  for (int x = 0; x < 4; ++x) {
    float s = 0.0f;
#pragma unroll
    for (int y = 0; y < 4; ++y) s += expf(acc[x][y] * (1.0f / TEMP_));
    rsum[x] = s;
  }
  __syncthreads();
#pragma unroll
  for (int x = 0; x < 4; ++x) s1[ti * 4 + x][tj] = rsum[x];
  __syncthreads();
  if (t < 64) {
    float s = 0.0f;
#pragma unroll
    for (int c = 0; c < 16; ++c) s += s1[t][c];
    negpart[((size_t)z * 32 + blockIdx.y) * BB + i0 + t] = s;
  }
}

__global__ void score_loss(const float* __restrict__ hu, const float* __restrict__ hv,
                           const float* __restrict__ negpart,
                           const float* __restrict__ u_mask, const float* __restrict__ i_mask,
                           float* __restrict__ loss_acc) {
  __shared__ float red[256];
  int z = blockIdx.y;
  int layer = z >> 1, side = z & 1;
  const float* hb = side ? hv : hu;
  const float* h1 = hb + (size_t)(layer * 2 + 0) * BB * DD;
  const float* h2 = hb + (size_t)(layer * 2 + 1) * BB * DD;
  const float* mask = (side ? i_mask : u_mask) + layer * BB;
  int i = blockIdx.x * 256 + threadIdx.x;
  const float4* a = (const float4*)(h1 + (size_t)i * DD);
  const float4* b = (const float4*)(h2 + (size_t)i * DD);
  float pos = 0.0f;
#pragma unroll
  for (int k = 0; k < 16; ++k) {
    float4 av = a[k], bv = b[k];
    pos += av.x * bv.x + av.y * bv.y + av.z * bv.z + av.w * bv.w;
  }
  float ng = 0.0f;
  for (int jt = 0; jt < 32; ++jt) ng += negpart[((size_t)z * 32 + jt) * BB + i];
  float ps = expf(pos * (1.0f / TEMP_));
  float m = (mask[i] > 0.5f) ? 1.0f : 0.0f;
  float li = -logf(ps / (ng + 1e-8f) + 1e-8f) * m;
  red[threadIdx.x] = li;
  __syncthreads();
  for (int ofs = 128; ofs >= 1; ofs >>= 1) {
    if (threadIdx.x < ofs) red[threadIdx.x] += red[threadIdx.x + ofs];
    __syncthreads();
  }
  if (threadIdx.x == 0) unsafeAtomicAdd(loss_acc, red[0]);
}

// ===========================================================================
// BPR
// ===========================================================================
__global__ void bpr_kernel(const float* __restrict__ Eu0, const float* __restrict__ EU1,
                           const float* __restrict__ bu,
                           const float* __restrict__ Ei0, const float* __restrict__ EI1,
                           const float* __restrict__ bpos, const float* __restrict__ bneg,
                           const int* __restrict__ uids, const int* __restrict__ pos,
                           const int* __restrict__ neg,
                           float* __restrict__ acc_r) {
  __shared__ float red[256];
  int i = blockIdx.x * 256 + threadIdx.x;
  const float4* u0 = (const float4*)(Eu0 + (size_t)uids[i] * DD);
  const float4* u1 = (const float4*)(EU1 + (size_t)uids[i] * DD);
  const float4* u2 = (const float4*)(bu  + (size_t)i * DD);
  const float4* p0 = (const float4*)(Ei0 + (size_t)pos[i] * DD);
  const float4* p1 = (const float4*)(EI1 + (size_t)pos[i] * DD);
  const float4* p2 = (const float4*)(bpos + (size_t)i * DD);
  const float4* n0 = (const float4*)(Ei0 + (size_t)neg[i] * DD);
  const float4* n1 = (const float4*)(EI1 + (size_t)neg[i] * DD);
  const float4* n2 = (const float4*)(bneg + (size_t)i * DD);
  float ps = 0.0f, ns = 0.0f;
#pragma unroll
  for (int k = 0; k < 16; ++k) {
    float4 ua = u0[k], ub = u1[k], uc = u2[k];
    float4 pa = p0[k], pb = p1[k], pc = p2[k];
    float4 na = n0[k], nb = n1[k], nc = n2[k];
    float ux = ua.x + ub.x + uc.x, uy = ua.y + ub.y + uc.y,
          uz = ua.z + ub.z + uc.z, uw = ua.w + ub.w + uc.w;
    ps += ux * (pa.x + pb.x + pc.x) + uy * (pa.y + pb.y + pc.y)
        + uz * (pa.z + pb.z + pc.z) + uw * (pa.w + pb.w + pc.w);
    ns += ux * (na.x + nb.x + nc.x) + uy * (na.y + nb.y + nc.y)
        + uz * (na.z + nb.z + nc.z) + uw * (na.w + nb.w + nc.w);
  }
  red[threadIdx.x] = fmaxf(1.0f - ps + ns, 0.0f);
  __syncthreads();
  for (int ofs = 128; ofs >= 1; ofs >>= 1) {
    if (threadIdx.x < ofs) red[threadIdx.x] += red[threadIdx.x + ofs];
    __syncthreads();
  }
  if (threadIdx.x == 0) unsafeAtomicAdd(acc_r, red[0]);
}

__global__ void finalize_kernel(const float* __restrict__ acc, float* __restrict__ out) {
  float lr = acc[0] / (float)BB;
  float ls = acc[1];
  out[0] = lr + LAM1 * ls;
  out[1] = lr;
  out[2] = ls;
}

// ===========================================================================
extern "C" void kernel_launch(void* const* d_in, const int* in_sizes, int n_in,
                              void* d_out, int out_size, void* d_ws, size_t ws_size,
                              hipStream_t stream) {
  const float* E_u_0   = (const float*)d_in[0];
  const float* E_i_0   = (const float*)d_in[1];
  const float* svd_u   = (const float*)d_in[2];
  const float* svd_v   = (const float*)d_in[3];
  const float* sdiag   = (const float*)d_in[4];
  const float* ut      = (const float*)d_in[5];
  const float* vt      = (const float*)d_in[6];
  const float* W_u     = (const float*)d_in[7];
  const float* W_i     = (const float*)d_in[8];
  const float* adjv    = (const float*)d_in[9];
  const float* dropr   = (const float*)d_in[10];
  const float* noise_u1= (const float*)d_in[11];
  const float* noise_v1= (const float*)d_in[12];
  const float* noise_u2= (const float*)d_in[13];
  const float* noise_v2= (const float*)d_in[14];
  const float* u_mask  = (const float*)d_in[15];
  const float* i_mask  = (const float*)d_in[16];
  const int*   rows    = (const int*)d_in[17];
  const int*   cols    = (const int*)d_in[18];
  const int*   uids    = (const int*)d_in[19];
  const int*   iids    = (const int*)d_in[20];
  const int*   pos     = (const int*)d_in[21];
  const int*   neg     = (const int*)d_in[22];
  float* out = (float*)d_out;

  // ---- workspace layout (~80 MB, with aliasing) ----
  float* ws     = (float*)d_ws;
  float* EU1    = ws;                           // 6,400,000
  float* EI1    = EU1 + (size_t)N_U * DD;       // 3,200,000
  float* vtei   = EI1 + (size_t)N_I * DD;       // 2*4096
  float* uteu   = vtei + 2 * DD * DD;           // 2*4096
  float* accs   = uteu + 2 * DD * DD;           // 16
  float* region = accs + 16;                    // REGION_SZ floats (time-shared)
  // phase A (gemm partials): (NCH_I+NCH_U)*4096 = 1,204,224 < REGION_SZ
  float* Cp   = region;
  // phase B (post-gemm buffers):
  float* bu   = region;                          // 131072
  float* bpos = bu   + (size_t)BB * DD;          // 131072
  float* bneg = bpos + (size_t)BB * DD;          // 131072
  float* hu   = bneg + (size_t)BB * DD;          // 524288
  float* hv   = hu   + (size_t)4 * BB * DD;      // 524288
  float* negp = hv   + (size_t)4 * BB * DD;      // 262144 (sum 1,703,936 < REGION_SZ)
  // packed edge payloads (float4 per edge per side); base is 16B aligned:
  // region offset in floats is divisible by 4 (see static layout above).
  float4* pu  = (float4*)(region + (size_t)REGION_SZ);  // NNZ_ float4 = 16 MB
  float4* pi  = pu + NNZ_;                              // NNZ_ float4 = 16 MB
  int* off_u = (int*)(pi + NNZ_);               // 100,001
  int* off_i = off_u + (N_U + 1);               // 50,001
  int* cur_u = off_i + (N_I + 1);               // 100,000
  int* cur_i = cur_u + N_U;                     // 50,000
  int* spart = cur_i + N_I;                     // 256
  // scan temps alias payload space (dead until scatter_build):
  int* stmp  = (int*)pu;                        // <= N_U
  int* deg_u = (int*)pi;                        // N_U
  int* deg_i = deg_u + N_U;                     // N_I

  const int TB = 256;
  dim3 blk(TB);
  int eg = (NNZ_ + TB - 1) / TB;
  int row_grid = BB / 4;

  hipMemsetAsync(deg_u, 0, (size_t)(N_U + N_I) * sizeof(int), stream);
  hipMemsetAsync(cur_u, 0, (size_t)(N_U + N_I) * sizeof(int), stream);
  hipMemsetAsync(accs, 0, 16 * sizeof(float), stream);

  // ---- CSR build + packed edge payloads ----
  hist_kernel<<<eg, blk, 0, stream>>>(rows, cols, deg_u, deg_i, NNZ_);
  {
    int nb_u = (N_U + 1023) / 1024, nb_i = (N_I + 1023) / 1024;
    scan1<<<nb_u, blk, 0, stream>>>(deg_u, stmp, spart, N_U);
    scan2<<<1, blk, 0, stream>>>(spart, nb_u);
    scan3<<<(N_U + TB - 1) / TB, blk, 0, stream>>>(stmp, spart, off_u, N_U);
    scan1<<<nb_i, blk, 0, stream>>>(deg_i, stmp, spart, N_I);
    scan2<<<1, blk, 0, stream>>>(spart, nb_i);
    scan3<<<(N_I + TB - 1) / TB, blk, 0, stream>>>(stmp, spart, off_i, N_I);
  }
  scatter_build<<<eg, blk, 0, stream>>>(rows, cols, adjv, dropr, off_u, off_i,
                                        cur_u, cur_i, pu, pi, NNZ_);

  // ---- layer-1 small GEMMs (LDS-tiled outer-product, partials, reduce) ----
  gemm_tiled<<<NCH_I + NCH_U, blk, 0, stream>>>(vt, E_i_0, ut, E_u_0, Cp);
  gemm_reduce2<<<dim3(16, 2), blk, 0, stream>>>(Cp, vtei, uteu);

  // ---- layer-1 full SpMM, both sides fused ----
  spmm_all<<<(N_U + N_I + 3) / 4, blk, 0, stream>>>(off_u, pu, off_i, pi,
                                                    E_u_0, E_i_0, EU1, EI1);

  // ---- layer-2 small GEMMs ----
  gemm_tiled<<<NCH_I + NCH_U, blk, 0, stream>>>(vt, EI1, ut, EU1, Cp);
  gemm_reduce2<<<dim3(16, 2), blk, 0, stream>>>(Cp, vtei + 4096, uteu + 4096);

  // ---- layer-2 SpMM at batch rows only (region now free for phase B) ----
  spmm_batch3<<<dim3(row_grid, 3), blk, 0, stream>>>(uids, pos, neg,
      off_u, pu, off_i, pi, EU1, EI1, bu, bpos, bneg);

  // ---- contrastive ----
  h_kernel2<<<dim3(row_grid, LL), blk, 0, stream>>>(svd_u, noise_u1, noise_u2, sdiag,
                                                    vtei, W_u, uids, hu);
  h_kernel2<<<dim3(row_grid, LL), blk, 0, stream>>>(svd_v, noise_v1, noise_v2, sdiag,
                                                    uteu, W_i, iids, hv);
  score_tiles<<<dim3(32, 32, 4), blk, 0, stream>>>(hu, hv, negp);
  score_loss<<<dim3(8, 4), blk, 0, stream>>>(hu, hv, negp, u_mask, i_mask, accs + 1);

  // ---- BPR ----
  bpr_kernel<<<8, blk, 0, stream>>>(E_u_0, EU1, bu, E_i_0, EI1, bpos, bneg,
                                    uids, pos, neg, accs);

  finalize_kernel<<<1, 1, 0, stream>>>(accs, out);
}

// Round 4
// 729.867 us; speedup vs baseline: 1.4259x; 1.3294x over previous
//
#include <hip/hip_runtime.h>
#include <cstddef>

// ---- problem constants (from reference) ----
#define N_U   100000
#define N_I   50000
#define DD    64
#define NNZ_  1000000
#define LL    2
#define TEMP_ 0.2f
#define LAM1  0.2f
#define DROP_ 0.1f
#define EPS_  0.05f
#define BB    2048
#define KCH   320
#define NCH_I ((N_I + KCH - 1) / KCH)   /* 157 */
#define NCH_U ((N_U + KCH - 1) / KCH)   /* 313 */
#define REGION_SZ 2097152               /* floats, time-shared scratch */

__device__ __forceinline__ float leaky(float x) { return x >= 0.0f ? x : 0.5f * x; }

__device__ __forceinline__ float waveReduceSum(float v) {
#pragma unroll
  for (int m = 32; m >= 1; m >>= 1) v += __shfl_xor(v, m, 64);
  return v;
}

__device__ __forceinline__ int rlanei(int v, int l) {
  return __builtin_amdgcn_readlane(v, l);
}
__device__ __forceinline__ float rlanef(float v, int l) {
  return __int_as_float(__builtin_amdgcn_readlane(__float_as_int(v), l));
}

// async global->LDS, 16B per lane. LDS dest is wave-uniform base; HW adds lane*16.
__device__ __forceinline__ void gload_lds16(const float* g, float* l) {
  __builtin_amdgcn_global_load_lds(
      (const __attribute__((address_space(1))) void*)g,
      (__attribute__((address_space(3))) void*)l, 16, 0, 0);
}

// ===========================================================================
// CSR build: histogram -> scan (3-phase) -> scatter (+ packed edge payload)
// Payload per side per edge: float4 { bitcast(gather_id), k_layer1, k_layer2, 0 }
// ===========================================================================
__global__ void hist_kernel(const int* __restrict__ rows, const int* __restrict__ cols,
                            int* __restrict__ deg_u, int* __restrict__ deg_i, int nnz) {
  int e = blockIdx.x * blockDim.x + threadIdx.x;
  if (e >= nnz) return;
  atomicAdd(&deg_u[rows[e]], 1);
  atomicAdd(&deg_i[cols[e]], 1);
}

__global__ void scan1(const int* __restrict__ in, int* __restrict__ tmp,
                      int* __restrict__ partial, int n) {
  __shared__ int s[256];
  int t = threadIdx.x;
  int base = blockIdx.x * 1024;
  int v[4]; int tsum = 0;
#pragma unroll
  for (int k = 0; k < 4; ++k) {
    int idx = base + t * 4 + k;
    v[k] = (idx < n) ? in[idx] : 0;
    tsum += v[k];
  }
  s[t] = tsum;
  __syncthreads();
  for (int ofs = 1; ofs < 256; ofs <<= 1) {
    int x = (t >= ofs) ? s[t - ofs] : 0;
    __syncthreads();
    s[t] += x;
    __syncthreads();
  }
  if (t == 255) partial[blockIdx.x] = s[255];
  int run = (t == 0) ? 0 : s[t - 1];
#pragma unroll
  for (int k = 0; k < 4; ++k) {
    run += v[k];
    int idx = base + t * 4 + k;
    if (idx < n) tmp[idx] = run;
  }
}

__global__ void scan2(int* __restrict__ partial, int nb) {
  __shared__ int s[256];
  int t = threadIdx.x;
  s[t] = (t < nb) ? partial[t] : 0;
  __syncthreads();
  for (int ofs = 1; ofs < 256; ofs <<= 1) {
    int x = (t >= ofs) ? s[t - ofs] : 0;
    __syncthreads();
    s[t] += x;
    __syncthreads();
  }
  if (t < nb) partial[t] = (t == 0) ? 0 : s[t - 1];
}

__global__ void scan3(const int* __restrict__ tmp, const int* __restrict__ partial,
                      int* __restrict__ off, int n) {
  int i = blockIdx.x * blockDim.x + threadIdx.x;
  if (i == 0) off[0] = 0;
  if (i < n) off[i + 1] = tmp[i] + partial[i >> 10];
}

__global__ void scatter_build(const int* __restrict__ rows, const int* __restrict__ cols,
                              const float* __restrict__ vals, const float* __restrict__ dropr,
                              const int* __restrict__ off_u, const int* __restrict__ off_i,
                              int* __restrict__ cur_u, int* __restrict__ cur_i,
                              float4* __restrict__ pu, float4* __restrict__ pi,
                              int nnz) {
  int e = blockIdx.x * blockDim.x + threadIdx.x;
  if (e >= nnz) return;
  int r = rows[e], c = cols[e];
  float v = vals[e] * (1.0f / (1.0f - DROP_));
  float k0 = (dropr[e] >= DROP_) ? v : 0.0f;                      // layer1, u-side
  float k1 = (dropr[(size_t)NNZ_ + e] >= DROP_) ? v : 0.0f;       // layer1, i-side
  float k2 = (dropr[(size_t)2 * NNZ_ + e] >= DROP_) ? v : 0.0f;   // layer2, u-side
  float k3 = (dropr[(size_t)3 * NNZ_ + e] >= DROP_) ? v : 0.0f;   // layer2, i-side
  int p = off_u[r] + atomicAdd(&cur_u[r], 1);
  pu[p] = make_float4(__int_as_float(c), k0, k2, 0.0f);
  int q = off_i[c] + atomicAdd(&cur_i[c], 1);
  pi[q] = make_float4(__int_as_float(r), k1, k3, 0.0f);
}

// ===========================================================================
// Layer-1 SpMM, both sides in one launch. One wave per row; lane = dim.
// ===========================================================================
__global__ void spmm_all(const int* __restrict__ off_u, const float4* __restrict__ pu,
                         const int* __restrict__ off_i, const float4* __restrict__ pi,
                         const float* __restrict__ Eu0, const float* __restrict__ Ei0,
                         float* __restrict__ EU1, float* __restrict__ EI1) {
  int wid = threadIdx.x >> 6, lane = threadIdx.x & 63;
  int r = blockIdx.x * 4 + wid;
  const int* off; const float4* pay;
  const float* Esrc; const float* base; float* out;
  if (r < N_U) {
    off = off_u; pay = pu; Esrc = Ei0; base = Eu0; out = EU1;
  } else {
    r -= N_U;
    if (r >= N_I) return;
    off = off_i; pay = pi; Esrc = Eu0; base = Ei0; out = EI1;
  }
  int i0 = off[r], i1 = off[r + 1];
  float acc = 0.0f;
  for (int p = i0; p < i1; p += 64) {
    int cn = min(64, i1 - p);
    float dvl = 0.0f; int gl = 0;
    if (lane < cn) {
      float4 pl = pay[p + lane];
      gl = __float_as_int(pl.x);
      dvl = pl.y;
    }
    int j = 0;
    for (; j + 3 < cn; j += 4) {
      float d0 = rlanef(dvl, j), d1 = rlanef(dvl, j + 1),
            d2 = rlanef(dvl, j + 2), d3 = rlanef(dvl, j + 3);
      int g0 = rlanei(gl, j), g1 = rlanei(gl, j + 1),
          g2 = rlanei(gl, j + 2), g3 = rlanei(gl, j + 3);
      float e0 = Esrc[(size_t)g0 * DD + lane];
      float e1 = Esrc[(size_t)g1 * DD + lane];
      float e2 = Esrc[(size_t)g2 * DD + lane];
      float e3 = Esrc[(size_t)g3 * DD + lane];
      acc += d0 * e0; acc += d1 * e1; acc += d2 * e2; acc += d3 * e3;
    }
    for (; j < cn; ++j)
      acc += rlanef(dvl, j) * Esrc[(size_t)rlanei(gl, j) * DD + lane];
  }
  size_t o = (size_t)r * DD + lane;
  out[o] = base[o] + leaky(acc);
}

// Layer-2 SpMM only at gathered batch rows (uids | pos | neg via blockIdx.y).
__global__ void spmm_batch3(const int* __restrict__ uids, const int* __restrict__ pos,
                            const int* __restrict__ neg,
                            const int* __restrict__ off_u, const float4* __restrict__ pu,
                            const int* __restrict__ off_i, const float4* __restrict__ pi,
                            const float* __restrict__ EU1, const float* __restrict__ EI1,
                            float* __restrict__ bu, float* __restrict__ bpos,
                            float* __restrict__ bneg) {
  int z = blockIdx.y;
  const int* ids = (z == 0) ? uids : ((z == 1) ? pos : neg);
  const int* off = (z == 0) ? off_u : off_i;
  const float4* pay = (z == 0) ? pu : pi;
  const float* Esrc = (z == 0) ? EI1 : EU1;
  const float* base = (z == 0) ? EU1 : EI1;
  float* out = (z == 0) ? bu : ((z == 1) ? bpos : bneg);
  int wid = threadIdx.x >> 6, lane = threadIdx.x & 63;
  int i = blockIdx.x * 4 + wid;
  int r = ids[i];
  int i0 = off[r], i1 = off[r + 1];
  float acc = 0.0f;
  for (int p = i0; p < i1; p += 64) {
    int cn = min(64, i1 - p);
    float dvl = 0.0f; int gl = 0;
    if (lane < cn) {
      float4 pl = pay[p + lane];
      gl = __float_as_int(pl.x);
      dvl = pl.z;
    }
    int j = 0;
    for (; j + 3 < cn; j += 4) {
      float d0 = rlanef(dvl, j), d1 = rlanef(dvl, j + 1),
            d2 = rlanef(dvl, j + 2), d3 = rlanef(dvl, j + 3);
      int g0 = rlanei(gl, j), g1 = rlanei(gl, j + 1),
          g2 = rlanei(gl, j + 2), g3 = rlanei(gl, j + 3);
      acc += d0 * Esrc[(size_t)g0 * DD + lane];
      acc += d1 * Esrc[(size_t)g1 * DD + lane];
      acc += d2 * Esrc[(size_t)g2 * DD + lane];
      acc += d3 * Esrc[(size_t)g3 * DD + lane];
    }
    for (; j < cn; ++j)
      acc += rlanef(dvl, j) * Esrc[(size_t)rlanei(gl, j) * DD + lane];
  }
  out[(size_t)i * DD + lane] = base[(size_t)r * DD + lane] + leaky(acc);
}

// ===========================================================================
// Split-K dual GEMM with async global->LDS staging + LDS double-buffer.
// C[64][64] = A[64][N] @ B[N][64]; one KCH-chunk per block; partials to Cp.
// Staging: 8x global_load_lds(16B) per thread per 64-tile; linear LDS [64][64]
// (global_load_lds writes wave-uniform-base + lane*16 -> layout must be linear).
// Double-buffer: issue tile t+1's async loads, compute tile t, barrier (drains
// vmcnt) -> transfer overlaps compute.
// ===========================================================================
__global__ void gemm_tiled(const float* __restrict__ A0, const float* __restrict__ B0,
                           const float* __restrict__ A1, const float* __restrict__ B1,
                           float* __restrict__ Cp) {
  __shared__ __align__(16) float sA[2][4096];
  __shared__ __align__(16) float sB[2][4096];
  int bx = blockIdx.x;
  const float* A; const float* B; int N; int k0;
  if (bx < NCH_I) { A = A0; B = B0; N = N_I; k0 = bx * KCH; }
  else            { A = A1; B = B1; N = N_U; k0 = (bx - NCH_I) * KCH; }
  int t = threadIdx.x;
  int w = t >> 6, l = t & 63;
  int rseg = l >> 4;            // 0..3 row-within-segment
  int c4 = (l & 15) * 4;        // float4 column
  int ti = t >> 4, tj = t & 15;
  int ti4 = ti * 4, tj4 = tj * 4;

  int NT = min(KCH / 64, (N - k0 + 63) >> 6);   // tiles this block owns

  float acc[4][4];
#pragma unroll
  for (int x = 0; x < 4; ++x)
#pragma unroll
    for (int y = 0; y < 4; ++y) acc[x][y] = 0.0f;

  // ---- stage tile `tt` into buffer `b` ----
  auto stage = [&](int tt, int b) {
    int kb = k0 + tt * 64;
    if (kb + 64 <= N) {
      // fast path: 4 A-segments + 4 B-segments per thread, async 16B each
#pragma unroll
      for (int q = 0; q < 4; ++q) {
        int s = w * 4 + q;                       // segment 0..15, wave-uniform
        const float* ga = A + (size_t)(s * 4 + rseg) * N + kb + c4;
        gload_lds16(ga, &sA[b][s * 256]);
        const float* gb = B + (size_t)(kb + s * 4 + rseg) * DD + c4;
        gload_lds16(gb, &sB[b][s * 256]);
      }
    } else {
      // tail tile: guarded scalar path (block-uniform branch)
#pragma unroll
      for (int q = 0; q < 16; ++q) {
        int lin = t + q * 256;
        int r = lin >> 6, c = lin & 63;
        sA[b][lin] = (kb + c < N) ? A[(size_t)r * N + kb + c] : 0.0f;
        sB[b][lin] = (kb + r < N) ? B[(size_t)(kb + r) * DD + c] : 0.0f;
      }
    }
  };

  stage(0, 0);
  __syncthreads();                 // drains vmcnt -> buf0 ready
  int cur = 0;
  for (int tt = 0; tt < NT; ++tt) {
    if (tt + 1 < NT) stage(tt + 1, cur ^ 1);   // async loads fly during compute
    const float* cA = sA[cur];
    const float* cB = sB[cur];
#pragma unroll 8
    for (int k = 0; k < 64; ++k) {
      float4 b4 = *(const float4*)&cB[k * 64 + tj4];
      float a0 = cA[(ti4 + 0) * 64 + k];
      float a1 = cA[(ti4 + 1) * 64 + k];
      float a2 = cA[(ti4 + 2) * 64 + k];
      float a3 = cA[(ti4 + 3) * 64 + k];
      acc[0][0] += a0 * b4.x; acc[0][1] += a0 * b4.y; acc[0][2] += a0 * b4.z; acc[0][3] += a0 * b4.w;
      acc[1][0] += a1 * b4.x; acc[1][1] += a1 * b4.y; acc[1][2] += a1 * b4.z; acc[1][3] += a1 * b4.w;
      acc[2][0] += a2 * b4.x; acc[2][1] += a2 * b4.y; acc[2][2] += a2 * b4.z; acc[2][3] += a2 * b4.w;
      acc[3][0] += a3 * b4.x; acc[3][1] += a3 * b4.y; acc[3][2] += a3 * b4.z; acc[3][3] += a3 * b4.w;
    }
    __syncthreads();               // drains vmcnt -> next buffer ready; readers done
    cur ^= 1;
  }

  float* cp = Cp + (size_t)bx * 4096;
#pragma unroll
  for (int x = 0; x < 4; ++x)
#pragma unroll
    for (int y = 0; y < 4; ++y)
      cp[(ti4 + x) * DD + tj4 + y] = acc[x][y];
}

// fold partials, 2 stages for parallelism.
// stage1: grid (16, 2, 4): chunk-sums -> Cp2[(y*4+z)*4096 + idx]
__global__ void gemm_reduce_s1(const float* __restrict__ Cp, float* __restrict__ Cp2) {
  int y = blockIdx.y, z = blockIdx.z;
  const float* base = Cp + (y ? (size_t)NCH_I * 4096 : 0);
  int cnt = y ? NCH_U : NCH_I;
  int chunk = (cnt + 3) >> 2;
  int b0 = z * chunk, b1 = min(b0 + chunk, cnt);
  int idx = blockIdx.x * 256 + threadIdx.x;
  float s = 0.0f;
  for (int b = b0; b < b1; ++b) s += base[(size_t)b * 4096 + idx];
  Cp2[((size_t)(y * 4 + z)) * 4096 + idx] = s;
}

// stage2: grid (16, 2): C[idx] = sum_z Cp2
__global__ void gemm_reduce_s2(const float* __restrict__ Cp2,
                               float* __restrict__ C0, float* __restrict__ C1) {
  int y = blockIdx.y;
  float* C = y ? C1 : C0;
  int idx = blockIdx.x * 256 + threadIdx.x;
  float s = 0.0f;
#pragma unroll
  for (int z = 0; z < 4; ++z) s += Cp2[((size_t)(y * 4 + z)) * 4096 + idx];
  C[idx] = s;
}

// ===========================================================================
// h for both views and both layers of one side. hout [layer][view][BB][64].
// ===========================================================================
__global__ void h_kernel2(const float* __restrict__ svd,
                          const float* __restrict__ n1, const float* __restrict__ n2,
                          const float* __restrict__ sdiag,
                          const float* __restrict__ Mb,
                          const float* __restrict__ Wb,
                          const int*   __restrict__ ids,
                          float*       __restrict__ hout) {
  int layer = blockIdx.y;
  const float* M = Mb + layer * 4096;
  const float* W = Wb + layer * 4096;
  int wid  = threadIdx.x >> 6;
  int lane = threadIdx.x & 63;
  int i = blockIdx.x * 4 + wid;
  int id = ids[i];
  float sv = svd[(size_t)id * DD + lane];
  float sgn = (sv > 0.0f) ? 1.0f : ((sv < 0.0f) ? -1.0f : 0.0f);
  float sd = sdiag[lane];

  float z1 = n1[(size_t)id * DD + lane];
  float z2 = n2[(size_t)id * DD + lane];
  float d1 = fmaxf(sqrtf(waveReduceSum(z1 * z1)), 1e-12f);
  float d2 = fmaxf(sqrtf(waveReduceSum(z2 * z2)), 1e-12f);
  float g1 = (sv + sgn * (z1 / d1) * EPS_) * sd;
  float g2 = (sv + sgn * (z2 / d2) * EPS_) * sd;

  float a1 = 0.0f, a2 = 0.0f;
#pragma unroll
  for (int k = 0; k < 64; ++k) {
    float m = M[k * DD + lane];
    a1 += rlanef(g1, k) * m;
    a2 += rlanef(g2, k) * m;
  }
  a1 = leaky(a1); a2 = leaky(a2);
  float s1 = fmaxf(sqrtf(waveReduceSum(a1 * a1)), 1e-12f);
  float s2 = fmaxf(sqrtf(waveReduceSum(a2 * a2)), 1e-12f);
  float gn1 = a1 / s1, gn2 = a2 / s2;

  float h1 = 0.0f, h2 = 0.0f;
#pragma unroll
  for (int k = 0; k < 64; ++k) {
    float w = W[k * DD + lane];
    h1 += rlanef(gn1, k) * w;
    h2 += rlanef(gn2, k) * w;
  }
  size_t b0 = ((size_t)(layer * 2 + 0) * BB + i) * DD + lane;
  size_t b1 = ((size_t)(layer * 2 + 1) * BB + i) * DD + lane;
  hout[b0] = h1;
  hout[b1] = h2;
}

// ===========================================================================
// score tiles: 64x64 tile of exp(S/T), row-sum partials (non-atomic)
// ===========================================================================
__global__ void score_tiles(const float* __restrict__ hu, const float* __restrict__ hv,
                            float* __restrict__ negpart) {
  __shared__ float s1[64][65];
  __shared__ float s2[64][65];
  int z = blockIdx.z;
  int layer = z >> 1, side = z & 1;
  const float* hb = side ? hv : hu;
  const float* h1 = hb + (size_t)(layer * 2 + 0) * BB * DD;
  const float* h2 = hb + (size_t)(layer * 2 + 1) * BB * DD;
  int i0 = blockIdx.x * 64, j0 = blockIdx.y * 64;
  int t = threadIdx.x;
#pragma unroll
  for (int k = 0; k < 16; ++k) {
    int lin = t + k * 256;
    int r = lin >> 6, c = lin & 63;
    s1[r][c] = h1[(size_t)(i0 + r) * DD + c];
    s2[r][c] = h2[(size_t)(j0 + r) * DD + c];
  }
  __syncthreads();
  int ti = t >> 4, tj = t & 15;
  float acc[4][4];
#pragma unroll
  for (int x = 0; x < 4; ++x)
#pragma unroll
    for (int y = 0; y < 4; ++y) acc[x][y] = 0.0f;
  for (int d = 0; d < 64; ++d) {
    float a[4], b[4];
#pragma unroll
    for (int k = 0; k < 4; ++k) { a[k] = s1[ti * 4 + k][d]; b[k] = s2[tj * 4 + k][d]; }
#pragma unroll
    for (int x = 0; x < 4; ++x)
#pragma unroll
      for (int y = 0; y < 4; ++y) acc[x][y] += a[x] * b[y];
  }
  float rsum[4];
#pragma unroll
  for (int x = 0; x < 4; ++x) {
    float s = 0.0f;
#pragma unroll
    for (int y = 0; y < 4; ++y) s += expf(acc[x][y] * (1.0f / TEMP_));
    rsum[x] = s;
  }
  __syncthreads();
#pragma unroll
  for (int x = 0; x < 4; ++x) s1[ti * 4 + x][tj] = rsum[x];
  __syncthreads();
  if (t < 64) {
    float s = 0.0f;
#pragma unroll
    for (int c = 0; c < 16; ++c) s += s1[t][c];
    negpart[((size_t)z * 32 + blockIdx.y) * BB + i0 + t] = s;
  }
}

__global__ void score_loss(const float* __restrict__ hu, const float* __restrict__ hv,
                           const float* __restrict__ negpart,
                           const float* __restrict__ u_mask, const float* __restrict__ i_mask,
                           float* __restrict__ loss_acc) {
  __shared__ float red[256];
  int z = blockIdx.y;
  int layer = z >> 1, side = z & 1;
  const float* hb = side ? hv : hu;
  const float* h1 = hb + (size_t)(layer * 2 + 0) * BB * DD;
  const float* h2 = hb + (size_t)(layer * 2 + 1) * BB * DD;
  const float* mask = (side ? i_mask : u_mask) + layer * BB;
  int i = blockIdx.x * 256 + threadIdx.x;
  const float4* a = (const float4*)(h1 + (size_t)i * DD);
  const float4* b = (const float4*)(h2 + (size_t)i * DD);
  float pos = 0.0f;
#pragma unroll
  for (int k = 0; k < 16; ++k) {
    float4 av = a[k], bv = b[k];
    pos += av.x * bv.x + av.y * bv.y + av.z * bv.z + av.w * bv.w;
  }
  float ng = 0.0f;
  for (int jt = 0; jt < 32; ++jt) ng += negpart[((size_t)z * 32 + jt) * BB + i];
  float ps = expf(pos * (1.0f / TEMP_));
  float m = (mask[i] > 0.5f) ? 1.0f : 0.0f;
  float li = -logf(ps / (ng + 1e-8f) + 1e-8f) * m;
  red[threadIdx.x] = li;
  __syncthreads();
  for (int ofs = 128; ofs >= 1; ofs >>= 1) {
    if (threadIdx.x < ofs) red[threadIdx.x] += red[threadIdx.x + ofs];
    __syncthreads();
  }
  if (threadIdx.x == 0) unsafeAtomicAdd(loss_acc, red[0]);
}

// ===========================================================================
// BPR
// ===========================================================================
__global__ void bpr_kernel(const float* __restrict__ Eu0, const float* __restrict__ EU1,
                           const float* __restrict__ bu,
                           const float* __restrict__ Ei0, const float* __restrict__ EI1,
                           const float* __restrict__ bpos, const float* __restrict__ bneg,
                           const int* __restrict__ uids, const int* __restrict__ pos,
                           const int* __restrict__ neg,
                           float* __restrict__ acc_r) {
  __shared__ float red[256];
  int i = blockIdx.x * 256 + threadIdx.x;
  const float4* u0 = (const float4*)(Eu0 + (size_t)uids[i] * DD);
  const float4* u1 = (const float4*)(EU1 + (size_t)uids[i] * DD);
  const float4* u2 = (const float4*)(bu  + (size_t)i * DD);
  const float4* p0 = (const float4*)(Ei0 + (size_t)pos[i] * DD);
  const float4* p1 = (const float4*)(EI1 + (size_t)pos[i] * DD);
  const float4* p2 = (const float4*)(bpos + (size_t)i * DD);
  const float4* n0 = (const float4*)(Ei0 + (size_t)neg[i] * DD);
  const float4* n1 = (const float4*)(EI1 + (size_t)neg[i] * DD);
  const float4* n2 = (const float4*)(bneg + (size_t)i * DD);
  float ps = 0.0f, ns = 0.0f;
#pragma unroll
  for (int k = 0; k < 16; ++k) {
    float4 ua = u0[k], ub = u1[k], uc = u2[k];
    float4 pa = p0[k], pb = p1[k], pc = p2[k];
    float4 na = n0[k], nb = n1[k], nc = n2[k];
    float ux = ua.x + ub.x + uc.x, uy = ua.y + ub.y + uc.y,
          uz = ua.z + ub.z + uc.z, uw = ua.w + ub.w + uc.w;
    ps += ux * (pa.x + pb.x + pc.x) + uy * (pa.y + pb.y + pc.y)
        + uz * (pa.z + pb.z + pc.z) + uw * (pa.w + pb.w + pc.w);
    ns += ux * (na.x + nb.x + nc.x) + uy * (na.y + nb.y + nc.y)
        + uz * (na.z + nb.z + nc.z) + uw * (na.w + nb.w + nc.w);
  }
  red[threadIdx.x] = fmaxf(1.0f - ps + ns, 0.0f);
  __syncthreads();
  for (int ofs = 128; ofs >= 1; ofs >>= 1) {
    if (threadIdx.x < ofs) red[threadIdx.x] += red[threadIdx.x + ofs];
    __syncthreads();
  }
  if (threadIdx.x == 0) unsafeAtomicAdd(acc_r, red[0]);
}

__global__ void finalize_kernel(const float* __restrict__ acc, float* __restrict__ out) {
  float lr = acc[0] / (float)BB;
  float ls = acc[1];
  out[0] = lr + LAM1 * ls;
  out[1] = lr;
  out[2] = ls;
}

// ===========================================================================
extern "C" void kernel_launch(void* const* d_in, const int* in_sizes, int n_in,
                              void* d_out, int out_size, void* d_ws, size_t ws_size,
                              hipStream_t stream) {
  const float* E_u_0   = (const float*)d_in[0];
  const float* E_i_0   = (const float*)d_in[1];
  const float* svd_u   = (const float*)d_in[2];
  const float* svd_v   = (const float*)d_in[3];
  const float* sdiag   = (const float*)d_in[4];
  const float* ut      = (const float*)d_in[5];
  const float* vt      = (const float*)d_in[6];
  const float* W_u     = (const float*)d_in[7];
  const float* W_i     = (const float*)d_in[8];
  const float* adjv    = (const float*)d_in[9];
  const float* dropr   = (const float*)d_in[10];
  const float* noise_u1= (const float*)d_in[11];
  const float* noise_v1= (const float*)d_in[12];
  const float* noise_u2= (const float*)d_in[13];
  const float* noise_v2= (const float*)d_in[14];
  const float* u_mask  = (const float*)d_in[15];
  const float* i_mask  = (const float*)d_in[16];
  const int*   rows    = (const int*)d_in[17];
  const int*   cols    = (const int*)d_in[18];
  const int*   uids    = (const int*)d_in[19];
  const int*   iids    = (const int*)d_in[20];
  const int*   pos     = (const int*)d_in[21];
  const int*   neg     = (const int*)d_in[22];
  float* out = (float*)d_out;

  // ---- workspace layout (~80 MB, with aliasing) ----
  float* ws     = (float*)d_ws;
  float* EU1    = ws;                           // 6,400,000
  float* EI1    = EU1 + (size_t)N_U * DD;       // 3,200,000
  float* vtei   = EI1 + (size_t)N_I * DD;       // 2*4096
  float* uteu   = vtei + 2 * DD * DD;           // 2*4096
  float* accs   = uteu + 2 * DD * DD;           // 16
  float* region = accs + 16;                    // REGION_SZ floats (time-shared)
  // phase A (gemm partials): (NCH_I+NCH_U)*4096 + 8*4096 = 1,957,888 < REGION_SZ
  float* Cp   = region;
  float* Cp2  = Cp + (size_t)(NCH_I + NCH_U) * 4096;
  // phase B (post-gemm buffers):
  float* bu   = region;                          // 131072
  float* bpos = bu   + (size_t)BB * DD;          // 131072
  float* bneg = bpos + (size_t)BB * DD;          // 131072
  float* hu   = bneg + (size_t)BB * DD;          // 524288
  float* hv   = hu   + (size_t)4 * BB * DD;      // 524288
  float* negp = hv   + (size_t)4 * BB * DD;      // 262144 (sum 1,703,936 < REGION_SZ)
  // packed edge payloads (float4 per edge per side):
  float4* pu  = (float4*)(region + (size_t)REGION_SZ);  // NNZ_ float4 = 16 MB
  float4* pi  = pu + NNZ_;                              // NNZ_ float4 = 16 MB
  int* off_u = (int*)(pi + NNZ_);               // 100,001
  int* off_i = off_u + (N_U + 1);               // 50,001
  int* cur_u = off_i + (N_I + 1);               // 100,000
  int* cur_i = cur_u + N_U;                     // 50,000
  int* spart = cur_i + N_I;                     // 256
  // scan temps alias payload space (dead until scatter_build):
  int* stmp  = (int*)pu;                        // <= N_U
  int* deg_u = (int*)pi;                        // N_U
  int* deg_i = deg_u + N_U;                     // N_I

  const int TB = 256;
  dim3 blk(TB);
  int eg = (NNZ_ + TB - 1) / TB;
  int row_grid = BB / 4;

  hipMemsetAsync(deg_u, 0, (size_t)(N_U + N_I) * sizeof(int), stream);
  hipMemsetAsync(cur_u, 0, (size_t)(N_U + N_I) * sizeof(int), stream);
  hipMemsetAsync(accs, 0, 16 * sizeof(float), stream);

  // ---- CSR build + packed edge payloads ----
  hist_kernel<<<eg, blk, 0, stream>>>(rows, cols, deg_u, deg_i, NNZ_);
  {
    int nb_u = (N_U + 1023) / 1024, nb_i = (N_I + 1023) / 1024;
    scan1<<<nb_u, blk, 0, stream>>>(deg_u, stmp, spart, N_U);
    scan2<<<1, blk, 0, stream>>>(spart, nb_u);
    scan3<<<(N_U + TB - 1) / TB, blk, 0, stream>>>(stmp, spart, off_u, N_U);
    scan1<<<nb_i, blk, 0, stream>>>(deg_i, stmp, spart, N_I);
    scan2<<<1, blk, 0, stream>>>(spart, nb_i);
    scan3<<<(N_I + TB - 1) / TB, blk, 0, stream>>>(stmp, spart, off_i, N_I);
  }
  scatter_build<<<eg, blk, 0, stream>>>(rows, cols, adjv, dropr, off_u, off_i,
                                        cur_u, cur_i, pu, pi, NNZ_);

  // ---- layer-1 small GEMMs (async-staged split-K, 2-stage reduce) ----
  gemm_tiled<<<NCH_I + NCH_U, blk, 0, stream>>>(vt, E_i_0, ut, E_u_0, Cp);
  gemm_reduce_s1<<<dim3(16, 2, 4), blk, 0, stream>>>(Cp, Cp2);
  gemm_reduce_s2<<<dim3(16, 2), blk, 0, stream>>>(Cp2, vtei, uteu);

  // ---- layer-1 full SpMM, both sides fused ----
  spmm_all<<<(N_U + N_I + 3) / 4, blk, 0, stream>>>(off_u, pu, off_i, pi,
                                                    E_u_0, E_i_0, EU1, EI1);

  // ---- layer-2 small GEMMs ----
  gemm_tiled<<<NCH_I + NCH_U, blk, 0, stream>>>(vt, EI1, ut, EU1, Cp);
  gemm_reduce_s1<<<dim3(16, 2, 4), blk, 0, stream>>>(Cp, Cp2);
  gemm_reduce_s2<<<dim3(16, 2), blk, 0, stream>>>(Cp2, vtei + 4096, uteu + 4096);

  // ---- layer-2 SpMM at batch rows only (region now free for phase B) ----
  spmm_batch3<<<dim3(row_grid, 3), blk, 0, stream>>>(uids, pos, neg,
      off_u, pu, off_i, pi, EU1, EI1, bu, bpos, bneg);

  // ---- contrastive ----
  h_kernel2<<<dim3(row_grid, LL), blk, 0, stream>>>(svd_u, noise_u1, noise_u2, sdiag,
                                                    vtei, W_u, uids, hu);
  h_kernel2<<<dim3(row_grid, LL), blk, 0, stream>>>(svd_v, noise_v1, noise_v2, sdiag,
                                                    uteu, W_i, iids, hv);
  score_tiles<<<dim3(32, 32, 4), blk, 0, stream>>>(hu, hv, negp);
  score_loss<<<dim3(8, 4), blk, 0, stream>>>(hu, hv, negp, u_mask, i_mask, accs + 1);

  // ---- BPR ----
  bpr_kernel<<<8, blk, 0, stream>>>(E_u_0, EU1, bu, E_i_0, EI1, bpos, bneg,
                                    uids, pos, neg, accs);

  finalize_kernel<<<1, 1, 0, stream>>>(accs, out);
}

// Round 6
// 706.932 us; speedup vs baseline: 1.4722x; 1.0324x over previous
//
#include <hip/hip_runtime.h>
#include <cstddef>

// ---- problem constants (from reference) ----
#define N_U   100000
#define N_I   50000
#define DD    64
#define NNZ_  1000000
#define LL    2
#define TEMP_ 0.2f
#define LAM1  0.2f
#define DROP_ 0.1f
#define EPS_  0.05f
#define BB    2048
#define KCH   320
#define NCH_I ((N_I + KCH - 1) / KCH)   /* 157 */
#define NCH_U ((N_U + KCH - 1) / KCH)   /* 313 */
#define REGION_SZ 2097152               /* floats, time-shared scratch */

// CSR binning constants
#define NBK   196        /* buckets per side */
#define SH_U  9          /* 512 rows/bucket (u) */
#define SH_I  8          /* 256 rows/bucket (i) */
#define C1_CHUNK   3072  /* 48KB LDS staging + 5.9KB tables < 64KB limit */
#define C1_THREADS 512
#define C1_EPT     6     /* edges per thread = C1_CHUNK / C1_THREADS */

__device__ __forceinline__ float leaky(float x) { return x >= 0.0f ? x : 0.5f * x; }

__device__ __forceinline__ float waveReduceSum(float v) {
#pragma unroll
  for (int m = 32; m >= 1; m >>= 1) v += __shfl_xor(v, m, 64);
  return v;
}

__device__ __forceinline__ int rlanei(int v, int l) {
  return __builtin_amdgcn_readlane(v, l);
}
__device__ __forceinline__ float rlanef(float v, int l) {
  return __int_as_float(__builtin_amdgcn_readlane(__float_as_int(v), l));
}

// async global->LDS, 16B per lane. LDS dest is wave-uniform base; HW adds lane*16.
__device__ __forceinline__ void gload_lds16(const float* g, float* l) {
  __builtin_amdgcn_global_load_lds(
      (const __attribute__((address_space(1))) void*)g,
      (__attribute__((address_space(3))) void*)l, 16, 0, 0);
}

// ===========================================================================
// CSR build: histogram -> fused scans -> 2-phase binned scatter.
// Phase C1 (csr_bin): LDS-bin 3072 edges by coarse bucket (row-range), flush
//   per-bucket runs (~250B contiguous) into a bucket-grouped staging buffer
//   -> dense line-efficient writes (fixes the 1-line-per-16B-store floor).
// Phase C2 (csr_place): per bucket, read staged slab (dense) and scatter to
//   exact CSR position; destinations span only ~100KB -> L2-merged lines.
// Record: float4 { bitcast(gather_id), k_layer1, k_layer2, bitcast(row) }.
// ===========================================================================
__global__ void hist_kernel(const int* __restrict__ rows, const int* __restrict__ cols,
                            int* __restrict__ deg_u, int* __restrict__ deg_i, int nnz) {
  int e = blockIdx.x * blockDim.x + threadIdx.x;
  if (e >= nnz) return;
  atomicAdd(&deg_u[rows[e]], 1);
  atomicAdd(&deg_i[cols[e]], 1);
}

// fused per-side scans: y=0 -> u, y=1 -> i
__global__ void scan1b(const int* __restrict__ deg_u, const int* __restrict__ deg_i,
                       int* __restrict__ tmp_u, int* __restrict__ tmp_i,
                       int* __restrict__ part_u, int* __restrict__ part_i) {
  int y = blockIdx.y;
  const int* in = y ? deg_i : deg_u;
  int n = y ? N_I : N_U;
  int* tmp = y ? tmp_i : tmp_u;
  int* partial = y ? part_i : part_u;
  if (blockIdx.x * 1024 >= n) return;   // whole-block uniform
  __shared__ int s[256];
  int t = threadIdx.x;
  int base = blockIdx.x * 1024;
  int v[4]; int tsum = 0;
#pragma unroll
  for (int k = 0; k < 4; ++k) {
    int idx = base + t * 4 + k;
    v[k] = (idx < n) ? in[idx] : 0;
    tsum += v[k];
  }
  s[t] = tsum;
  __syncthreads();
  for (int ofs = 1; ofs < 256; ofs <<= 1) {
    int x = (t >= ofs) ? s[t - ofs] : 0;
    __syncthreads();
    s[t] += x;
    __syncthreads();
  }
  if (t == 255) partial[blockIdx.x] = s[255];
  int run = (t == 0) ? 0 : s[t - 1];
#pragma unroll
  for (int k = 0; k < 4; ++k) {
    run += v[k];
    int idx = base + t * 4 + k;
    if (idx < n) tmp[idx] = run;
  }
}

__global__ void scan2b(int* __restrict__ part_u, int* __restrict__ part_i) {
  int y = blockIdx.y;
  int* partial = y ? part_i : part_u;
  int nb = y ? (N_I + 1023) / 1024 : (N_U + 1023) / 1024;
  __shared__ int s[256];
  int t = threadIdx.x;
  s[t] = (t < nb) ? partial[t] : 0;
  __syncthreads();
  for (int ofs = 1; ofs < 256; ofs <<= 1) {
    int x = (t >= ofs) ? s[t - ofs] : 0;
    __syncthreads();
    s[t] += x;
    __syncthreads();
  }
  if (t < nb) partial[t] = (t == 0) ? 0 : s[t - 1];
}

__global__ void scan3b(const int* __restrict__ tmp_u, const int* __restrict__ tmp_i,
                       const int* __restrict__ part_u, const int* __restrict__ part_i,
                       int* __restrict__ off_u, int* __restrict__ off_i) {
  int y = blockIdx.y;
  const int* tmp = y ? tmp_i : tmp_u;
  const int* partial = y ? part_i : part_u;
  int* off = y ? off_i : off_u;
  int n = y ? N_I : N_U;
  int i = blockIdx.x * blockDim.x + threadIdx.x;
  if (i == 0) off[0] = 0;
  if (i < n) off[i + 1] = tmp[i] + partial[i >> 10];
}

// Phase C1: bucket-binned staging. One launch per side.
__global__ __launch_bounds__(C1_THREADS)
void csr_bin(const int* __restrict__ rws,   // this side's row endpoint per edge
             const int* __restrict__ oth,   // other endpoint (gather id)
             const float* __restrict__ vals,
             const float* __restrict__ dA, const float* __restrict__ dB,
             const int* __restrict__ off,   // CSR row offsets
             int* __restrict__ bcur,        // bucket cursors [NBK], zeroed
             float4* __restrict__ stg,      // bucket-grouped staging
             int shift) {
  __shared__ float4 st[C1_CHUNK];                       // 48 KB
  __shared__ int hist[NBK], lbase[NBK], cur2[NBK], slab[NBK], lboff[NBK];
  __shared__ int sc[256];
  int t = threadIdx.x;
  int e0 = blockIdx.x * C1_CHUNK;
  int n = min(C1_CHUNK, NNZ_ - e0);
  for (int b = t; b < NBK; b += C1_THREADS) { hist[b] = 0; cur2[b] = 0; }
  __syncthreads();
  // pass 1: load edge data to regs, count buckets
  int myr[C1_EPT], myo[C1_EPT];
  float mk1[C1_EPT], mk2[C1_EPT];
#pragma unroll
  for (int k = 0; k < C1_EPT; ++k) {
    int li = t + k * C1_THREADS;
    if (li < n) {
      int e = e0 + li;
      int r = rws[e];
      myr[k] = r;
      myo[k] = oth[e];
      float v = vals[e] * (1.0f / (1.0f - DROP_));
      mk1[k] = (dA[e] >= DROP_) ? v : 0.0f;
      mk2[k] = (dB[e] >= DROP_) ? v : 0.0f;
      atomicAdd(&hist[r >> shift], 1);
    } else {
      myr[k] = -1;
    }
  }
  __syncthreads();
  // exclusive scan over NBK (padded to 256)
  if (t < 256) sc[t] = (t < NBK) ? hist[t] : 0;
  __syncthreads();
  for (int ofs = 1; ofs < 256; ofs <<= 1) {
    int x = (t < 256 && t >= ofs) ? sc[t - ofs] : 0;
    __syncthreads();
    if (t < 256) sc[t] += x;
    __syncthreads();
  }
  if (t < NBK) {
    lbase[t] = (t == 0) ? 0 : sc[t - 1];
    lboff[t] = off[t << shift];            // bucket base in CSR coords
    if (hist[t] > 0) slab[t] = atomicAdd(&bcur[t], hist[t]);
  }
  __syncthreads();
  // pass 2: place records bucket-sorted in LDS
#pragma unroll
  for (int k = 0; k < C1_EPT; ++k) {
    if (myr[k] >= 0) {
      int b = myr[k] >> shift;
      int pos = lbase[b] + atomicAdd(&cur2[b], 1);
      st[pos] = make_float4(__int_as_float(myo[k]), mk1[k], mk2[k],
                            __int_as_float(myr[k]));
    }
  }
  __syncthreads();
  // flush: contiguous runs per bucket -> global slabs (line-dense)
  for (int s = t; s < n; s += C1_THREADS) {
    float4 rec = st[s];
    int r = __float_as_int(rec.w);
    int b = r >> shift;
    stg[(size_t)lboff[b] + slab[b] + (s - lbase[b])] = rec;
  }
}

// Phase C2: exact-position scatter within one bucket (L2-local destinations).
__global__ void csr_place(const float4* __restrict__ stg, const int* __restrict__ off,
                          int* __restrict__ cur, float4* __restrict__ out,
                          int N, int shift) {
  int b = blockIdx.x;
  int lo = off[b << shift];
  int hiRow = (b + 1) << shift; if (hiRow > N) hiRow = N;
  int hi = off[hiRow];
  int cnt = hi - lo;
  int part = blockIdx.y;
  int c0 = lo + (int)(((long long)cnt * part) >> 2);
  int c1 = lo + (int)(((long long)cnt * (part + 1)) >> 2);
  for (int i = c0 + threadIdx.x; i < c1; i += blockDim.x) {
    float4 rec = stg[i];
    int r = __float_as_int(rec.w);
    int pos = off[r] + atomicAdd(&cur[r], 1);
    out[pos] = rec;
  }
}

// ===========================================================================
// Layer-1 SpMM, both sides in one launch. One wave per row; lane = dim.
// ===========================================================================
__global__ void spmm_all(const int* __restrict__ off_u, const float4* __restrict__ pu,
                         const int* __restrict__ off_i, const float4* __restrict__ pi,
                         const float* __restrict__ Eu0, const float* __restrict__ Ei0,
                         float* __restrict__ EU1, float* __restrict__ EI1) {
  int wid = threadIdx.x >> 6, lane = threadIdx.x & 63;
  int r = blockIdx.x * 4 + wid;
  const int* off; const float4* pay;
  const float* Esrc; const float* base; float* out;
  if (r < N_U) {
    off = off_u; pay = pu; Esrc = Ei0; base = Eu0; out = EU1;
  } else {
    r -= N_U;
    if (r >= N_I) return;
    off = off_i; pay = pi; Esrc = Eu0; base = Ei0; out = EI1;
  }
  int i0 = off[r], i1 = off[r + 1];
  float acc = 0.0f;
  for (int p = i0; p < i1; p += 64) {
    int cn = min(64, i1 - p);
    float dvl = 0.0f; int gl = 0;
    if (lane < cn) {
      float4 pl = pay[p + lane];
      gl = __float_as_int(pl.x);
      dvl = pl.y;
    }
    int j = 0;
    for (; j + 3 < cn; j += 4) {
      float d0 = rlanef(dvl, j), d1 = rlanef(dvl, j + 1),
            d2 = rlanef(dvl, j + 2), d3 = rlanef(dvl, j + 3);
      int g0 = rlanei(gl, j), g1 = rlanei(gl, j + 1),
          g2 = rlanei(gl, j + 2), g3 = rlanei(gl, j + 3);
      float e0 = Esrc[(size_t)g0 * DD + lane];
      float e1 = Esrc[(size_t)g1 * DD + lane];
      float e2 = Esrc[(size_t)g2 * DD + lane];
      float e3 = Esrc[(size_t)g3 * DD + lane];
      acc += d0 * e0; acc += d1 * e1; acc += d2 * e2; acc += d3 * e3;
    }
    for (; j < cn; ++j)
      acc += rlanef(dvl, j) * Esrc[(size_t)rlanei(gl, j) * DD + lane];
  }
  size_t o = (size_t)r * DD + lane;
  out[o] = base[o] + leaky(acc);
}

// Layer-2 SpMM only at gathered batch rows (uids | pos | neg via blockIdx.y).
__global__ void spmm_batch3(const int* __restrict__ uids, const int* __restrict__ pos,
                            const int* __restrict__ neg,
                            const int* __restrict__ off_u, const float4* __restrict__ pu,
                            const int* __restrict__ off_i, const float4* __restrict__ pi,
                            const float* __restrict__ EU1, const float* __restrict__ EI1,
                            float* __restrict__ bu, float* __restrict__ bpos,
                            float* __restrict__ bneg) {
  int z = blockIdx.y;
  const int* ids = (z == 0) ? uids : ((z == 1) ? pos : neg);
  const int* off = (z == 0) ? off_u : off_i;
  const float4* pay = (z == 0) ? pu : pi;
  const float* Esrc = (z == 0) ? EI1 : EU1;
  const float* base = (z == 0) ? EU1 : EI1;
  float* out = (z == 0) ? bu : ((z == 1) ? bpos : bneg);
  int wid = threadIdx.x >> 6, lane = threadIdx.x & 63;
  int i = blockIdx.x * 4 + wid;
  int r = ids[i];
  int i0 = off[r], i1 = off[r + 1];
  float acc = 0.0f;
  for (int p = i0; p < i1; p += 64) {
    int cn = min(64, i1 - p);
    float dvl = 0.0f; int gl = 0;
    if (lane < cn) {
      float4 pl = pay[p + lane];
      gl = __float_as_int(pl.x);
      dvl = pl.z;
    }
    int j = 0;
    for (; j + 3 < cn; j += 4) {
      float d0 = rlanef(dvl, j), d1 = rlanef(dvl, j + 1),
            d2 = rlanef(dvl, j + 2), d3 = rlanef(dvl, j + 3);
      int g0 = rlanei(gl, j), g1 = rlanei(gl, j + 1),
          g2 = rlanei(gl, j + 2), g3 = rlanei(gl, j + 3);
      acc += d0 * Esrc[(size_t)g0 * DD + lane];
      acc += d1 * Esrc[(size_t)g1 * DD + lane];
      acc += d2 * Esrc[(size_t)g2 * DD + lane];
      acc += d3 * Esrc[(size_t)g3 * DD + lane];
    }
    for (; j < cn; ++j)
      acc += rlanef(dvl, j) * Esrc[(size_t)rlanei(gl, j) * DD + lane];
  }
  out[(size_t)i * DD + lane] = base[(size_t)r * DD + lane] + leaky(acc);
}

// ===========================================================================
// Split-K dual GEMM with async global->LDS staging + LDS double-buffer.
// ===========================================================================
__global__ void gemm_tiled(const float* __restrict__ A0, const float* __restrict__ B0,
                           const float* __restrict__ A1, const float* __restrict__ B1,
                           float* __restrict__ Cp) {
  __shared__ __align__(16) float sA[2][4096];
  __shared__ __align__(16) float sB[2][4096];
  int bx = blockIdx.x;
  const float* A; const float* B; int N; int k0;
  if (bx < NCH_I) { A = A0; B = B0; N = N_I; k0 = bx * KCH; }
  else            { A = A1; B = B1; N = N_U; k0 = (bx - NCH_I) * KCH; }
  int t = threadIdx.x;
  int w = t >> 6, l = t & 63;
  int rseg = l >> 4;            // 0..3 row-within-segment
  int c4 = (l & 15) * 4;        // float4 column
  int ti = t >> 4, tj = t & 15;
  int ti4 = ti * 4, tj4 = tj * 4;

  int NT = min(KCH / 64, (N - k0 + 63) >> 6);   // tiles this block owns

  float acc[4][4];
#pragma unroll
  for (int x = 0; x < 4; ++x)
#pragma unroll
    for (int y = 0; y < 4; ++y) acc[x][y] = 0.0f;

  auto stage = [&](int tt, int b) {
    int kb = k0 + tt * 64;
    if (kb + 64 <= N) {
#pragma unroll
      for (int q = 0; q < 4; ++q) {
        int s = w * 4 + q;                       // segment 0..15, wave-uniform
        const float* ga = A + (size_t)(s * 4 + rseg) * N + kb + c4;
        gload_lds16(ga, &sA[b][s * 256]);
        const float* gb = B + (size_t)(kb + s * 4 + rseg) * DD + c4;
        gload_lds16(gb, &sB[b][s * 256]);
      }
    } else {
#pragma unroll
      for (int q = 0; q < 16; ++q) {
        int lin = t + q * 256;
        int r = lin >> 6, c = lin & 63;
        sA[b][lin] = (kb + c < N) ? A[(size_t)r * N + kb + c] : 0.0f;
        sB[b][lin] = (kb + r < N) ? B[(size_t)(kb + r) * DD + c] : 0.0f;
      }
    }
  };

  stage(0, 0);
  __syncthreads();
  int cur = 0;
  for (int tt = 0; tt < NT; ++tt) {
    if (tt + 1 < NT) stage(tt + 1, cur ^ 1);
    const float* cA = sA[cur];
    const float* cB = sB[cur];
#pragma unroll 8
    for (int k = 0; k < 64; ++k) {
      float4 b4 = *(const float4*)&cB[k * 64 + tj4];
      float a0 = cA[(ti4 + 0) * 64 + k];
      float a1 = cA[(ti4 + 1) * 64 + k];
      float a2 = cA[(ti4 + 2) * 64 + k];
      float a3 = cA[(ti4 + 3) * 64 + k];
      acc[0][0] += a0 * b4.x; acc[0][1] += a0 * b4.y; acc[0][2] += a0 * b4.z; acc[0][3] += a0 * b4.w;
      acc[1][0] += a1 * b4.x; acc[1][1] += a1 * b4.y; acc[1][2] += a1 * b4.z; acc[1][3] += a1 * b4.w;
      acc[2][0] += a2 * b4.x; acc[2][1] += a2 * b4.y; acc[2][2] += a2 * b4.z; acc[2][3] += a2 * b4.w;
      acc[3][0] += a3 * b4.x; acc[3][1] += a3 * b4.y; acc[3][2] += a3 * b4.z; acc[3][3] += a3 * b4.w;
    }
    __syncthreads();
    cur ^= 1;
  }

  float* cp = Cp + (size_t)bx * 4096;
#pragma unroll
  for (int x = 0; x < 4; ++x)
#pragma unroll
    for (int y = 0; y < 4; ++y)
      cp[(ti4 + x) * DD + tj4 + y] = acc[x][y];
}

// fold partials, 2 stages for parallelism.
__global__ void gemm_reduce_s1(const float* __restrict__ Cp, float* __restrict__ Cp2) {
  int y = blockIdx.y, z = blockIdx.z;
  const float* base = Cp + (y ? (size_t)NCH_I * 4096 : 0);
  int cnt = y ? NCH_U : NCH_I;
  int chunk = (cnt + 3) >> 2;
  int b0 = z * chunk, b1 = min(b0 + chunk, cnt);
  int idx = blockIdx.x * 256 + threadIdx.x;
  float s = 0.0f;
  for (int b = b0; b < b1; ++b) s += base[(size_t)b * 4096 + idx];
  Cp2[((size_t)(y * 4 + z)) * 4096 + idx] = s;
}

__global__ void gemm_reduce_s2(const float* __restrict__ Cp2,
                               float* __restrict__ C0, float* __restrict__ C1) {
  int y = blockIdx.y;
  float* C = y ? C1 : C0;
  int idx = blockIdx.x * 256 + threadIdx.x;
  float s = 0.0f;
#pragma unroll
  for (int z = 0; z < 4; ++z) s += Cp2[((size_t)(y * 4 + z)) * 4096 + idx];
  C[idx] = s;
}

// ===========================================================================
// h for both views and both layers of one side. hout [layer][view][BB][64].
// ===========================================================================
__global__ void h_kernel2(const float* __restrict__ svd,
                          const float* __restrict__ n1, const float* __restrict__ n2,
                          const float* __restrict__ sdiag,
                          const float* __restrict__ Mb,
                          const float* __restrict__ Wb,
                          const int*   __restrict__ ids,
                          float*       __restrict__ hout) {
  int layer = blockIdx.y;
  const float* M = Mb + layer * 4096;
  const float* W = Wb + layer * 4096;
  int wid  = threadIdx.x >> 6;
  int lane = threadIdx.x & 63;
  int i = blockIdx.x * 4 + wid;
  int id = ids[i];
  float sv = svd[(size_t)id * DD + lane];
  float sgn = (sv > 0.0f) ? 1.0f : ((sv < 0.0f) ? -1.0f : 0.0f);
  float sd = sdiag[lane];

  float z1 = n1[(size_t)id * DD + lane];
  float z2 = n2[(size_t)id * DD + lane];
  float d1 = fmaxf(sqrtf(waveReduceSum(z1 * z1)), 1e-12f);
  float d2 = fmaxf(sqrtf(waveReduceSum(z2 * z2)), 1e-12f);
  float g1 = (sv + sgn * (z1 / d1) * EPS_) * sd;
  float g2 = (sv + sgn * (z2 / d2) * EPS_) * sd;

  float a1 = 0.0f, a2 = 0.0f;
#pragma unroll
  for (int k = 0; k < 64; ++k) {
    float m = M[k * DD + lane];
    a1 += rlanef(g1, k) * m;
    a2 += rlanef(g2, k) * m;
  }
  a1 = leaky(a1); a2 = leaky(a2);
  float s1 = fmaxf(sqrtf(waveReduceSum(a1 * a1)), 1e-12f);
  float s2 = fmaxf(sqrtf(waveReduceSum(a2 * a2)), 1e-12f);
  float gn1 = a1 / s1, gn2 = a2 / s2;

  float h1 = 0.0f, h2 = 0.0f;
#pragma unroll
  for (int k = 0; k < 64; ++k) {
    float w = W[k * DD + lane];
    h1 += rlanef(gn1, k) * w;
    h2 += rlanef(gn2, k) * w;
  }
  size_t b0 = ((size_t)(layer * 2 + 0) * BB + i) * DD + lane;
  size_t b1 = ((size_t)(layer * 2 + 1) * BB + i) * DD + lane;
  hout[b0] = h1;
  hout[b1] = h2;
}

// ===========================================================================
// score tiles: 64x64 tile of exp(S/T), row-sum partials (non-atomic)
// ===========================================================================
__global__ void score_tiles(const float* __restrict__ hu, const float* __restrict__ hv,
                            float* __restrict__ negpart) {
  __shared__ float s1[64][65];
  __shared__ float s2[64][65];
  int z = blockIdx.z;
  int layer = z >> 1, side = z & 1;
  const float* hb = side ? hv : hu;
  const float* h1 = hb + (size_t)(layer * 2 + 0) * BB * DD;
  const float* h2 = hb + (size_t)(layer * 2 + 1) * BB * DD;
  int i0 = blockIdx.x * 64, j0 = blockIdx.y * 64;
  int t = threadIdx.x;
#pragma unroll
  for (int k = 0; k < 16; ++k) {
    int lin = t + k * 256;
    int r = lin >> 6, c = lin & 63;
    s1[r][c] = h1[(size_t)(i0 + r) * DD + c];
    s2[r][c] = h2[(size_t)(j0 + r) * DD + c];
  }
  __syncthreads();
  int ti = t >> 4, tj = t & 15;
  float acc[4][4];
#pragma unroll
  for (int x = 0; x < 4; ++x)
#pragma unroll
    for (int y = 0; y < 4; ++y) acc[x][y] = 0.0f;
  for (int d = 0; d < 64; ++d) {
    float a[4], b[4];
#pragma unroll
    for (int k = 0; k < 4; ++k) { a[k] = s1[ti * 4 + k][d]; b[k] = s2[tj * 4 + k][d]; }
#pragma unroll
    for (int x = 0; x < 4; ++x)
#pragma unroll
      for (int y = 0; y < 4; ++y) acc[x][y] += a[x] * b[y];
  }
  float rsum[4];
#pragma unroll
  for (int x = 0; x < 4; ++x) {
    float s = 0.0f;
#pragma unroll
    for (int y = 0; y < 4; ++y) s += expf(acc[x][y] * (1.0f / TEMP_));
    rsum[x] = s;
  }
  __syncthreads();
#pragma unroll
  for (int x = 0; x < 4; ++x) s1[ti * 4 + x][tj] = rsum[x];
  __syncthreads();
  if (t < 64) {
    float s = 0.0f;
#pragma unroll
    for (int c = 0; c < 16; ++c) s += s1[t][c];
    negpart[((size_t)z * 32 + blockIdx.y) * BB + i0 + t] = s;
  }
}

__global__ void score_loss(const float* __restrict__ hu, const float* __restrict__ hv,
                           const float* __restrict__ negpart,
                           const float* __restrict__ u_mask, const float* __restrict__ i_mask,
                           float* __restrict__ loss_acc) {
  __shared__ float red[256];
  int z = blockIdx.y;
  int layer = z >> 1, side = z & 1;
  const float* hb = side ? hv : hu;
  const float* h1 = hb + (size_t)(layer * 2 + 0) * BB * DD;
  const float* h2 = hb + (size_t)(layer * 2 + 1) * BB * DD;
  const float* mask = (side ? i_mask : u_mask) + layer * BB;
  int i = blockIdx.x * 256 + threadIdx.x;
  const float4* a = (const float4*)(h1 + (size_t)i * DD);
  const float4* b = (const float4*)(h2 + (size_t)i * DD);
  float pos = 0.0f;
#pragma unroll
  for (int k = 0; k < 16; ++k) {
    float4 av = a[k], bv = b[k];
    pos += av.x * bv.x + av.y * bv.y + av.z * bv.z + av.w * bv.w;
  }
  float ng = 0.0f;
  for (int jt = 0; jt < 32; ++jt) ng += negpart[((size_t)z * 32 + jt) * BB + i];
  float ps = expf(pos * (1.0f / TEMP_));
  float m = (mask[i] > 0.5f) ? 1.0f : 0.0f;
  float li = -logf(ps / (ng + 1e-8f) + 1e-8f) * m;
  red[threadIdx.x] = li;
  __syncthreads();
  for (int ofs = 128; ofs >= 1; ofs >>= 1) {
    if (threadIdx.x < ofs) red[threadIdx.x] += red[threadIdx.x + ofs];
    __syncthreads();
  }
  if (threadIdx.x == 0) unsafeAtomicAdd(loss_acc, red[0]);
}

// ===========================================================================
// BPR
// ===========================================================================
__global__ void bpr_kernel(const float* __restrict__ Eu0, const float* __restrict__ EU1,
                           const float* __restrict__ bu,
                           const float* __restrict__ Ei0, const float* __restrict__ EI1,
                           const float* __restrict__ bpos, const float* __restrict__ bneg,
                           const int* __restrict__ uids, const int* __restrict__ pos,
                           const int* __restrict__ neg,
                           float* __restrict__ acc_r) {
  __shared__ float red[256];
  int i = blockIdx.x * 256 + threadIdx.x;
  const float4* u0 = (const float4*)(Eu0 + (size_t)uids[i] * DD);
  const float4* u1 = (const float4*)(EU1 + (size_t)uids[i] * DD);
  const float4* u2 = (const float4*)(bu  + (size_t)i * DD);
  const float4* p0 = (const float4*)(Ei0 + (size_t)pos[i] * DD);
  const float4* p1 = (const float4*)(EI1 + (size_t)pos[i] * DD);
  const float4* p2 = (const float4*)(bpos + (size_t)i * DD);
  const float4* n0 = (const float4*)(Ei0 + (size_t)neg[i] * DD);
  const float4* n1 = (const float4*)(EI1 + (size_t)neg[i] * DD);
  const float4* n2 = (const float4*)(bneg + (size_t)i * DD);
  float ps = 0.0f, ns = 0.0f;
#pragma unroll
  for (int k = 0; k < 16; ++k) {
    float4 ua = u0[k], ub = u1[k], uc = u2[k];
    float4 pa = p0[k], pb = p1[k], pc = p2[k];
    float4 na = n0[k], nb = n1[k], nc = n2[k];
    float ux = ua.x + ub.x + uc.x, uy = ua.y + ub.y + uc.y,
          uz = ua.z + ub.z + uc.z, uw = ua.w + ub.w + uc.w;
    ps += ux * (pa.x + pb.x + pc.x) + uy * (pa.y + pb.y + pc.y)
        + uz * (pa.z + pb.z + pc.z) + uw * (pa.w + pb.w + pc.w);
    ns += ux * (na.x + nb.x + nc.x) + uy * (na.y + nb.y + nc.y)
        + uz * (na.z + nb.z + nc.z) + uw * (na.w + nb.w + nc.w);
  }
  red[threadIdx.x] = fmaxf(1.0f - ps + ns, 0.0f);
  __syncthreads();
  for (int ofs = 128; ofs >= 1; ofs >>= 1) {
    if (threadIdx.x < ofs) red[threadIdx.x] += red[threadIdx.x + ofs];
    __syncthreads();
  }
  if (threadIdx.x == 0) unsafeAtomicAdd(acc_r, red[0]);
}

__global__ void finalize_kernel(const float* __restrict__ acc, float* __restrict__ out) {
  float lr = acc[0] / (float)BB;
  float ls = acc[1];
  out[0] = lr + LAM1 * ls;
  out[1] = lr;
  out[2] = ls;
}

// ===========================================================================
extern "C" void kernel_launch(void* const* d_in, const int* in_sizes, int n_in,
                              void* d_out, int out_size, void* d_ws, size_t ws_size,
                              hipStream_t stream) {
  const float* E_u_0   = (const float*)d_in[0];
  const float* E_i_0   = (const float*)d_in[1];
  const float* svd_u   = (const float*)d_in[2];
  const float* svd_v   = (const float*)d_in[3];
  const float* sdiag   = (const float*)d_in[4];
  const float* ut      = (const float*)d_in[5];
  const float* vt      = (const float*)d_in[6];
  const float* W_u     = (const float*)d_in[7];
  const float* W_i     = (const float*)d_in[8];
  const float* adjv    = (const float*)d_in[9];
  const float* dropr   = (const float*)d_in[10];
  const float* noise_u1= (const float*)d_in[11];
  const float* noise_v1= (const float*)d_in[12];
  const float* noise_u2= (const float*)d_in[13];
  const float* noise_v2= (const float*)d_in[14];
  const float* u_mask  = (const float*)d_in[15];
  const float* i_mask  = (const float*)d_in[16];
  const int*   rows    = (const int*)d_in[17];
  const int*   cols    = (const int*)d_in[18];
  const int*   uids    = (const int*)d_in[19];
  const int*   iids    = (const int*)d_in[20];
  const int*   pos     = (const int*)d_in[21];
  const int*   neg     = (const int*)d_in[22];
  float* out = (float*)d_out;

  // ---- workspace layout (~80 MB, with aliasing) ----
  float* ws     = (float*)d_ws;
  float* EU1    = ws;                           // 6,400,000
  float* EI1    = EU1 + (size_t)N_U * DD;       // 3,200,000
  float* vtei   = EI1 + (size_t)N_I * DD;       // 2*4096
  float* uteu   = vtei + 2 * DD * DD;           // 2*4096
  float* accs   = uteu + 2 * DD * DD;           // 16
  float* region = accs + 16;                    // REGION_SZ floats (time-shared)
  // phase A (gemm partials): (NCH_I+NCH_U)*4096 + 8*4096 = 1,957,888 < REGION_SZ
  float* Cp   = region;
  float* Cp2  = Cp + (size_t)(NCH_I + NCH_U) * 4096;
  // phase B (post-gemm buffers):
  float* bu   = region;                          // 131072
  float* bpos = bu   + (size_t)BB * DD;          // 131072
  float* bneg = bpos + (size_t)BB * DD;          // 131072
  float* hu   = bneg + (size_t)BB * DD;          // 524288
  float* hv   = hu   + (size_t)4 * BB * DD;      // 524288
  float* negp = hv   + (size_t)4 * BB * DD;      // 262144 (sum 1,703,936 < REGION_SZ)
  // packed edge payloads (float4 per edge per side):
  float4* pu  = (float4*)(region + (size_t)REGION_SZ);  // NNZ_ float4 = 16 MB
  float4* pi  = pu + NNZ_;                              // NNZ_ float4 = 16 MB
  int* off_u = (int*)(pi + NNZ_);               // 100,001
  int* off_i = off_u + (N_U + 1);               // 50,001
  int* cur_u = off_i + (N_I + 1);               // 100,000
  int* cur_i = cur_u + N_U;                     // 50,000
  int* bcur_u = cur_i + N_I;                    // 196
  int* bcur_i = bcur_u + NBK;                   // 196
  int* spart_u = bcur_i + NBK;                  // 256
  int* spart_i = spart_u + 256;                 // 256
  // staging buffers alias EU1/EI1 (dead until spmm_all): 2M float4 = 8M floats
  // EU1+EI1 = 9.6M floats >= 8M; vtei/uteu/accs start at 9.6M+ -> untouched.
  float4* stg_u = (float4*)ws;                  // NNZ_ float4
  float4* stg_i = stg_u + NNZ_;                 // NNZ_ float4
  // scan temps alias payload space (dead until csr_place):
  int* stmp_u = (int*)pu;                       // N_U
  int* stmp_i = stmp_u + N_U;                   // N_I
  int* deg_u = (int*)pi;                        // N_U
  int* deg_i = deg_u + N_U;                     // N_I

  const int TB = 256;
  dim3 blk(TB);
  int eg = (NNZ_ + TB - 1) / TB;
  int row_grid = BB / 4;

  hipMemsetAsync(deg_u, 0, (size_t)(N_U + N_I) * sizeof(int), stream);
  hipMemsetAsync(cur_u, 0, (size_t)(N_U + N_I + 2 * NBK) * sizeof(int), stream);
  hipMemsetAsync(accs, 0, 16 * sizeof(float), stream);

  // ---- CSR build: hist -> fused scans -> binned 2-phase scatter ----
  hist_kernel<<<eg, blk, 0, stream>>>(rows, cols, deg_u, deg_i, NNZ_);
  {
    int nb_u = (N_U + 1023) / 1024;   // 98 (covers i side's 49 via guard)
    scan1b<<<dim3(nb_u, 2), blk, 0, stream>>>(deg_u, deg_i, stmp_u, stmp_i,
                                              spart_u, spart_i);
    scan2b<<<dim3(1, 2), blk, 0, stream>>>(spart_u, spart_i);
    scan3b<<<dim3((N_U + TB - 1) / TB, 2), blk, 0, stream>>>(stmp_u, stmp_i,
                                                             spart_u, spart_i,
                                                             off_u, off_i);
  }
  {
    int c1g = (NNZ_ + C1_CHUNK - 1) / C1_CHUNK;   // 326
    csr_bin<<<c1g, C1_THREADS, 0, stream>>>(rows, cols, adjv,
        dropr, dropr + (size_t)2 * NNZ_, off_u, bcur_u, stg_u, SH_U);
    csr_bin<<<c1g, C1_THREADS, 0, stream>>>(cols, rows, adjv,
        dropr + (size_t)NNZ_, dropr + (size_t)3 * NNZ_, off_i, bcur_i, stg_i, SH_I);
    csr_place<<<dim3(NBK, 4), blk, 0, stream>>>(stg_u, off_u, cur_u, pu, N_U, SH_U);
    csr_place<<<dim3(NBK, 4), blk, 0, stream>>>(stg_i, off_i, cur_i, pi, N_I, SH_I);
  }

  // ---- layer-1 small GEMMs (async-staged split-K, 2-stage reduce) ----
  gemm_tiled<<<NCH_I + NCH_U, blk, 0, stream>>>(vt, E_i_0, ut, E_u_0, Cp);
  gemm_reduce_s1<<<dim3(16, 2, 4), blk, 0, stream>>>(Cp, Cp2);
  gemm_reduce_s2<<<dim3(16, 2), blk, 0, stream>>>(Cp2, vtei, uteu);

  // ---- layer-1 full SpMM, both sides fused ----
  spmm_all<<<(N_U + N_I + 3) / 4, blk, 0, stream>>>(off_u, pu, off_i, pi,
                                                    E_u_0, E_i_0, EU1, EI1);

  // ---- layer-2 small GEMMs ----
  gemm_tiled<<<NCH_I + NCH_U, blk, 0, stream>>>(vt, EI1, ut, EU1, Cp);
  gemm_reduce_s1<<<dim3(16, 2, 4), blk, 0, stream>>>(Cp, Cp2);
  gemm_reduce_s2<<<dim3(16, 2), blk, 0, stream>>>(Cp2, vtei + 4096, uteu + 4096);

  // ---- layer-2 SpMM at batch rows only (region now free for phase B) ----
  spmm_batch3<<<dim3(row_grid, 3), blk, 0, stream>>>(uids, pos, neg,
      off_u, pu, off_i, pi, EU1, EI1, bu, bpos, bneg);

  // ---- contrastive ----
  h_kernel2<<<dim3(row_grid, LL), blk, 0, stream>>>(svd_u, noise_u1, noise_u2, sdiag,
                                                    vtei, W_u, uids, hu);
  h_kernel2<<<dim3(row_grid, LL), blk, 0, stream>>>(svd_v, noise_v1, noise_v2, sdiag,
                                                    uteu, W_i, iids, hv);
  score_tiles<<<dim3(32, 32, 4), blk, 0, stream>>>(hu, hv, negp);
  score_loss<<<dim3(8, 4), blk, 0, stream>>>(hu, hv, negp, u_mask, i_mask, accs + 1);

  // ---- BPR ----
  bpr_kernel<<<8, blk, 0, stream>>>(E_u_0, EU1, bu, E_i_0, EI1, bpos, bneg,
                                    uids, pos, neg, accs);

  finalize_kernel<<<1, 1, 0, stream>>>(accs, out);
}

// Round 7
// 624.668 us; speedup vs baseline: 1.6661x; 1.1317x over previous
//
#include <hip/hip_runtime.h>
#include <cstddef>

// ---- problem constants (from reference) ----
#define N_U   100000
#define N_I   50000
#define DD    64
#define NNZ_  1000000
#define LL    2
#define TEMP_ 0.2f
#define LAM1  0.2f
#define DROP_ 0.1f
#define EPS_  0.05f
#define BB    2048
#define KCH   320
#define NCH_I ((N_I + KCH - 1) / KCH)   /* 157 */
#define NCH_U ((N_U + KCH - 1) / KCH)   /* 313 */
#define REGION_SZ 2097152               /* floats, time-shared scratch */

// CSR binning constants
#define NBK   391        /* buckets per side: u 256 rows (shift 8), i 128 rows (shift 7) */
#define SH_U  8
#define SH_I  7
#define C1_CHUNK   3072  /* 48KB LDS staging */
#define C1_THREADS 512
#define C1_EPT     6     /* edges per thread = C1_CHUNK / C1_THREADS */
#define BH_BLOCKS  256

__device__ __forceinline__ float leaky(float x) { return x >= 0.0f ? x : 0.5f * x; }

__device__ __forceinline__ float waveReduceSum(float v) {
#pragma unroll
  for (int m = 32; m >= 1; m >>= 1) v += __shfl_xor(v, m, 64);
  return v;
}

__device__ __forceinline__ int rlanei(int v, int l) {
  return __builtin_amdgcn_readlane(v, l);
}
__device__ __forceinline__ float rlanef(float v, int l) {
  return __int_as_float(__builtin_amdgcn_readlane(__float_as_int(v), l));
}

// async global->LDS, 16B per lane. LDS dest is wave-uniform base; HW adds lane*16.
__device__ __forceinline__ void gload_lds16(const float* g, float* l) {
  __builtin_amdgcn_global_load_lds(
      (const __attribute__((address_space(1))) void*)g,
      (__attribute__((address_space(3))) void*)l, 16, 0, 0);
}

// ===========================================================================
// CSR build v3 — NO global row-histogram (the old hist_kernel was 82us of
// random device-scope atomics, WRITE_SIZE 62MB for 600KB of counters).
//   bhist:    bucket-level histogram only (782 counters) via LDS, partials.
//   bscan:    1 block: fold partials, scan buckets -> bbase (CSR bucket bases).
//   csr_bin:  LDS-bin 3072 edges -> bucket-grouped staging slabs (line-dense).
//   csr_final:per bucket: LDS row-hist (<=256 rows) + LDS scan -> off[] +
//             exact-position place (LDS atomics, L2-local dests) ->
//             pay1=(id,k_l1), pay2=(id,k_l2) float2 arrays (split: spmm_all
//             only needs 8B/edge, not 16B).
// Staging record: float4 { bitcast(gather_id), k_l1, k_l2, bitcast(row) }.
// ===========================================================================
__global__ void bhist(const int* __restrict__ rows, const int* __restrict__ cols,
                      int* __restrict__ bh) {
  __shared__ int lh[2 * NBK];
  int t = threadIdx.x;
  for (int j = t; j < 2 * NBK; j += 256) lh[j] = 0;
  __syncthreads();
  for (int e = blockIdx.x * 256 + t; e < NNZ_; e += BH_BLOCKS * 256) {
    atomicAdd(&lh[rows[e] >> SH_U], 1);
    atomicAdd(&lh[NBK + (cols[e] >> SH_I)], 1);
  }
  __syncthreads();
  for (int j = t; j < 2 * NBK; j += 256) bh[blockIdx.x * (2 * NBK) + j] = lh[j];
}

__global__ void bscan(const int* __restrict__ bh,
                      int* __restrict__ bbase_u, int* __restrict__ bbase_i,
                      int* __restrict__ bcur_u, int* __restrict__ bcur_i) {
  __shared__ int tot[2 * NBK];
  __shared__ int sc[512];
  int t = threadIdx.x;   // 256
  for (int j = t; j < 2 * NBK; j += 256) {
    int s = 0;
    for (int k = 0; k < BH_BLOCKS; ++k) s += bh[k * (2 * NBK) + j];
    tot[j] = s;
  }
  __syncthreads();
  // ---- side u ----
  sc[t] = (t < NBK) ? tot[t] : 0;
  sc[t + 256] = (t + 256 < NBK) ? tot[t + 256] : 0;
  __syncthreads();
  for (int ofs = 1; ofs < 512; ofs <<= 1) {
    int a = (t >= ofs) ? sc[t - ofs] : 0;
    int b = (t + 256 >= ofs) ? sc[t + 256 - ofs] : 0;
    __syncthreads();
    sc[t] += a; sc[t + 256] += b;
    __syncthreads();
  }
  if (t == 0) bbase_u[0] = 0;
  for (int j = t; j < NBK; j += 256) bbase_u[j + 1] = sc[j];
  __syncthreads();
  // ---- side i ----
  sc[t] = (t < NBK) ? tot[NBK + t] : 0;
  sc[t + 256] = (t + 256 < NBK) ? tot[NBK + t + 256] : 0;
  __syncthreads();
  for (int ofs = 1; ofs < 512; ofs <<= 1) {
    int a = (t >= ofs) ? sc[t - ofs] : 0;
    int b = (t + 256 >= ofs) ? sc[t + 256 - ofs] : 0;
    __syncthreads();
    sc[t] += a; sc[t + 256] += b;
    __syncthreads();
  }
  if (t == 0) bbase_i[0] = 0;
  for (int j = t; j < NBK; j += 256) bbase_i[j + 1] = sc[j];
  for (int j = t; j < NBK; j += 256) { bcur_u[j] = 0; bcur_i[j] = 0; }
}

// bucket-binned staging. One launch per side.
__global__ __launch_bounds__(C1_THREADS)
void csr_bin(const int* __restrict__ rws, const int* __restrict__ oth,
             const float* __restrict__ vals,
             const float* __restrict__ dA, const float* __restrict__ dB,
             const int* __restrict__ bbase,   // bucket bases (edge coords)
             int* __restrict__ bcur,          // bucket cursors, zeroed
             float4* __restrict__ stg, int shift) {
  __shared__ float4 st[C1_CHUNK];                       // 48 KB
  __shared__ int hist[NBK], lbase[NBK], cur2[NBK], slab[NBK], lboff[NBK];
  __shared__ int sc[512];
  int t = threadIdx.x;
  int e0 = blockIdx.x * C1_CHUNK;
  int n = min(C1_CHUNK, NNZ_ - e0);
  for (int b = t; b < NBK; b += C1_THREADS) { hist[b] = 0; cur2[b] = 0; }
  __syncthreads();
  int myr[C1_EPT], myo[C1_EPT];
  float mk1[C1_EPT], mk2[C1_EPT];
#pragma unroll
  for (int k = 0; k < C1_EPT; ++k) {
    int li = t + k * C1_THREADS;
    if (li < n) {
      int e = e0 + li;
      int r = rws[e];
      myr[k] = r;
      myo[k] = oth[e];
      float v = vals[e] * (1.0f / (1.0f - DROP_));
      mk1[k] = (dA[e] >= DROP_) ? v : 0.0f;
      mk2[k] = (dB[e] >= DROP_) ? v : 0.0f;
      atomicAdd(&hist[r >> shift], 1);
    } else {
      myr[k] = -1;
    }
  }
  __syncthreads();
  sc[t] = (t < NBK) ? hist[t] : 0;
  __syncthreads();
  for (int ofs = 1; ofs < 512; ofs <<= 1) {
    int x = (t >= ofs) ? sc[t - ofs] : 0;
    __syncthreads();
    sc[t] += x;
    __syncthreads();
  }
  if (t < NBK) {
    lbase[t] = (t == 0) ? 0 : sc[t - 1];
    lboff[t] = bbase[t];
    if (hist[t] > 0) slab[t] = atomicAdd(&bcur[t], hist[t]);
  }
  __syncthreads();
#pragma unroll
  for (int k = 0; k < C1_EPT; ++k) {
    if (myr[k] >= 0) {
      int b = myr[k] >> shift;
      int pos = lbase[b] + atomicAdd(&cur2[b], 1);
      st[pos] = make_float4(__int_as_float(myo[k]), mk1[k], mk2[k],
                            __int_as_float(myr[k]));
    }
  }
  __syncthreads();
  for (int s = t; s < n; s += C1_THREADS) {
    float4 rec = st[s];
    int r = __float_as_int(rec.w);
    int b = r >> shift;
    stg[(size_t)lboff[b] + slab[b] + (s - lbase[b])] = rec;
  }
}

// per-bucket: LDS row-hist + scan -> off[]; place records at exact CSR pos.
__global__ void csr_final(const float4* __restrict__ stg, const int* __restrict__ bbase,
                          float2* __restrict__ pay1, float2* __restrict__ pay2,
                          int* __restrict__ off, int N, int shift) {
  __shared__ int h[256], incl[256], cur[256];
  int b = blockIdx.x;
  int t = threadIdx.x;
  int r0 = b << shift;
  int nrows = min(1 << shift, N - r0);
  int lo = bbase[b], hi = bbase[b + 1];
  h[t] = 0; cur[t] = 0;
  __syncthreads();
  for (int i = lo + t; i < hi; i += 256)
    atomicAdd(&h[__float_as_int(stg[i].w) - r0], 1);
  __syncthreads();
  incl[t] = h[t];
  __syncthreads();
  for (int ofs = 1; ofs < 256; ofs <<= 1) {
    int a = (t >= ofs) ? incl[t - ofs] : 0;
    __syncthreads();
    incl[t] += a;
    __syncthreads();
  }
  if (b == 0 && t == 0) off[0] = 0;
  if (t < nrows) off[r0 + t + 1] = lo + incl[t];
  for (int i = lo + t; i < hi; i += 256) {
    float4 rec = stg[i];
    int L = __float_as_int(rec.w) - r0;
    int pos = lo + (incl[L] - h[L]) + atomicAdd(&cur[L], 1);
    pay1[pos] = make_float2(rec.x, rec.y);
    pay2[pos] = make_float2(rec.x, rec.z);
  }
}

// ===========================================================================
// Layer-1 SpMM, both sides in one launch. One wave per row; lane = dim.
// 8-deep gather ILP; payload 8B/edge.
// ===========================================================================
__global__ void spmm_all(const int* __restrict__ off_u, const float2* __restrict__ pu,
                         const int* __restrict__ off_i, const float2* __restrict__ pi,
                         const float* __restrict__ Eu0, const float* __restrict__ Ei0,
                         float* __restrict__ EU1, float* __restrict__ EI1) {
  int wid = threadIdx.x >> 6, lane = threadIdx.x & 63;
  int r = blockIdx.x * 4 + wid;
  const int* off; const float2* pay;
  const float* Esrc; const float* base; float* out;
  if (r < N_U) {
    off = off_u; pay = pu; Esrc = Ei0; base = Eu0; out = EU1;
  } else {
    r -= N_U;
    if (r >= N_I) return;
    off = off_i; pay = pi; Esrc = Eu0; base = Ei0; out = EI1;
  }
  int i0 = off[r], i1 = off[r + 1];
  float acc = 0.0f;
  for (int p = i0; p < i1; p += 64) {
    int cn = min(64, i1 - p);
    float dvl = 0.0f; int gl = 0;
    if (lane < cn) {
      float2 pl = pay[p + lane];
      gl = __float_as_int(pl.x);
      dvl = pl.y;
    }
    int j = 0;
    for (; j + 7 < cn; j += 8) {
      float d[8]; int g[8]; float e[8];
#pragma unroll
      for (int q = 0; q < 8; ++q) { d[q] = rlanef(dvl, j + q); g[q] = rlanei(gl, j + q); }
#pragma unroll
      for (int q = 0; q < 8; ++q) e[q] = Esrc[(size_t)g[q] * DD + lane];
#pragma unroll
      for (int q = 0; q < 8; ++q) acc += d[q] * e[q];
    }
    for (; j + 3 < cn; j += 4) {
      float d[4]; int g[4]; float e[4];
#pragma unroll
      for (int q = 0; q < 4; ++q) { d[q] = rlanef(dvl, j + q); g[q] = rlanei(gl, j + q); }
#pragma unroll
      for (int q = 0; q < 4; ++q) e[q] = Esrc[(size_t)g[q] * DD + lane];
#pragma unroll
      for (int q = 0; q < 4; ++q) acc += d[q] * e[q];
    }
    for (; j < cn; ++j)
      acc += rlanef(dvl, j) * Esrc[(size_t)rlanei(gl, j) * DD + lane];
  }
  size_t o = (size_t)r * DD + lane;
  out[o] = base[o] + leaky(acc);
}

// Layer-2 SpMM only at gathered batch rows (uids | pos | neg via blockIdx.y).
__global__ void spmm_batch3(const int* __restrict__ uids, const int* __restrict__ pos,
                            const int* __restrict__ neg,
                            const int* __restrict__ off_u, const float2* __restrict__ pu2,
                            const int* __restrict__ off_i, const float2* __restrict__ pi2,
                            const float* __restrict__ EU1, const float* __restrict__ EI1,
                            float* __restrict__ bu, float* __restrict__ bpos,
                            float* __restrict__ bneg) {
  int z = blockIdx.y;
  const int* ids = (z == 0) ? uids : ((z == 1) ? pos : neg);
  const int* off = (z == 0) ? off_u : off_i;
  const float2* pay = (z == 0) ? pu2 : pi2;
  const float* Esrc = (z == 0) ? EI1 : EU1;
  const float* base = (z == 0) ? EU1 : EI1;
  float* out = (z == 0) ? bu : ((z == 1) ? bpos : bneg);
  int wid = threadIdx.x >> 6, lane = threadIdx.x & 63;
  int i = blockIdx.x * 4 + wid;
  int r = ids[i];
  int i0 = off[r], i1 = off[r + 1];
  float acc = 0.0f;
  for (int p = i0; p < i1; p += 64) {
    int cn = min(64, i1 - p);
    float dvl = 0.0f; int gl = 0;
    if (lane < cn) {
      float2 pl = pay[p + lane];
      gl = __float_as_int(pl.x);
      dvl = pl.y;
    }
    int j = 0;
    for (; j + 7 < cn; j += 8) {
      float d[8]; int g[8]; float e[8];
#pragma unroll
      for (int q = 0; q < 8; ++q) { d[q] = rlanef(dvl, j + q); g[q] = rlanei(gl, j + q); }
#pragma unroll
      for (int q = 0; q < 8; ++q) e[q] = Esrc[(size_t)g[q] * DD + lane];
#pragma unroll
      for (int q = 0; q < 8; ++q) acc += d[q] * e[q];
    }
    for (; j + 3 < cn; j += 4) {
      float d[4]; int g[4]; float e[4];
#pragma unroll
      for (int q = 0; q < 4; ++q) { d[q] = rlanef(dvl, j + q); g[q] = rlanei(gl, j + q); }
#pragma unroll
      for (int q = 0; q < 4; ++q) e[q] = Esrc[(size_t)g[q] * DD + lane];
#pragma unroll
      for (int q = 0; q < 4; ++q) acc += d[q] * e[q];
    }
    for (; j < cn; ++j)
      acc += rlanef(dvl, j) * Esrc[(size_t)rlanei(gl, j) * DD + lane];
  }
  out[(size_t)i * DD + lane] = base[(size_t)r * DD + lane] + leaky(acc);
}

// ===========================================================================
// Split-K dual GEMM with async global->LDS staging + LDS double-buffer.
// ===========================================================================
__global__ void gemm_tiled(const float* __restrict__ A0, const float* __restrict__ B0,
                           const float* __restrict__ A1, const float* __restrict__ B1,
                           float* __restrict__ Cp) {
  __shared__ __align__(16) float sA[2][4096];
  __shared__ __align__(16) float sB[2][4096];
  int bx = blockIdx.x;
  const float* A; const float* B; int N; int k0;
  if (bx < NCH_I) { A = A0; B = B0; N = N_I; k0 = bx * KCH; }
  else            { A = A1; B = B1; N = N_U; k0 = (bx - NCH_I) * KCH; }
  int t = threadIdx.x;
  int w = t >> 6, l = t & 63;
  int rseg = l >> 4;
  int c4 = (l & 15) * 4;
  int ti = t >> 4, tj = t & 15;
  int ti4 = ti * 4, tj4 = tj * 4;

  int NT = min(KCH / 64, (N - k0 + 63) >> 6);

  float acc[4][4];
#pragma unroll
  for (int x = 0; x < 4; ++x)
#pragma unroll
    for (int y = 0; y < 4; ++y) acc[x][y] = 0.0f;

  auto stage = [&](int tt, int b) {
    int kb = k0 + tt * 64;
    if (kb + 64 <= N) {
#pragma unroll
      for (int q = 0; q < 4; ++q) {
        int s = w * 4 + q;
        const float* ga = A + (size_t)(s * 4 + rseg) * N + kb + c4;
        gload_lds16(ga, &sA[b][s * 256]);
        const float* gb = B + (size_t)(kb + s * 4 + rseg) * DD + c4;
        gload_lds16(gb, &sB[b][s * 256]);
      }
    } else {
#pragma unroll
      for (int q = 0; q < 16; ++q) {
        int lin = t + q * 256;
        int r = lin >> 6, c = lin & 63;
        sA[b][lin] = (kb + c < N) ? A[(size_t)r * N + kb + c] : 0.0f;
        sB[b][lin] = (kb + r < N) ? B[(size_t)(kb + r) * DD + c] : 0.0f;
      }
    }
  };

  stage(0, 0);
  __syncthreads();
  int cur = 0;
  for (int tt = 0; tt < NT; ++tt) {
    if (tt + 1 < NT) stage(tt + 1, cur ^ 1);
    const float* cA = sA[cur];
    const float* cB = sB[cur];
#pragma unroll 8
    for (int k = 0; k < 64; ++k) {
      float4 b4 = *(const float4*)&cB[k * 64 + tj4];
      float a0 = cA[(ti4 + 0) * 64 + k];
      float a1 = cA[(ti4 + 1) * 64 + k];
      float a2 = cA[(ti4 + 2) * 64 + k];
      float a3 = cA[(ti4 + 3) * 64 + k];
      acc[0][0] += a0 * b4.x; acc[0][1] += a0 * b4.y; acc[0][2] += a0 * b4.z; acc[0][3] += a0 * b4.w;
      acc[1][0] += a1 * b4.x; acc[1][1] += a1 * b4.y; acc[1][2] += a1 * b4.z; acc[1][3] += a1 * b4.w;
      acc[2][0] += a2 * b4.x; acc[2][1] += a2 * b4.y; acc[2][2] += a2 * b4.z; acc[2][3] += a2 * b4.w;
      acc[3][0] += a3 * b4.x; acc[3][1] += a3 * b4.y; acc[3][2] += a3 * b4.z; acc[3][3] += a3 * b4.w;
    }
    __syncthreads();
    cur ^= 1;
  }

  float* cp = Cp + (size_t)bx * 4096;
#pragma unroll
  for (int x = 0; x < 4; ++x)
#pragma unroll
    for (int y = 0; y < 4; ++y)
      cp[(ti4 + x) * DD + tj4 + y] = acc[x][y];
}

__global__ void gemm_reduce_s1(const float* __restrict__ Cp, float* __restrict__ Cp2) {
  int y = blockIdx.y, z = blockIdx.z;
  const float* base = Cp + (y ? (size_t)NCH_I * 4096 : 0);
  int cnt = y ? NCH_U : NCH_I;
  int chunk = (cnt + 3) >> 2;
  int b0 = z * chunk, b1 = min(b0 + chunk, cnt);
  int idx = blockIdx.x * 256 + threadIdx.x;
  float s = 0.0f;
  for (int b = b0; b < b1; ++b) s += base[(size_t)b * 4096 + idx];
  Cp2[((size_t)(y * 4 + z)) * 4096 + idx] = s;
}

__global__ void gemm_reduce_s2(const float* __restrict__ Cp2,
                               float* __restrict__ C0, float* __restrict__ C1) {
  int y = blockIdx.y;
  float* C = y ? C1 : C0;
  int idx = blockIdx.x * 256 + threadIdx.x;
  float s = 0.0f;
#pragma unroll
  for (int z = 0; z < 4; ++z) s += Cp2[((size_t)(y * 4 + z)) * 4096 + idx];
  C[idx] = s;
}

// ===========================================================================
// h for both views and both layers of one side. hout [layer][view][BB][64].
// ===========================================================================
__global__ void h_kernel2(const float* __restrict__ svd,
                          const float* __restrict__ n1, const float* __restrict__ n2,
                          const float* __restrict__ sdiag,
                          const float* __restrict__ Mb,
                          const float* __restrict__ Wb,
                          const int*   __restrict__ ids,
                          float*       __restrict__ hout) {
  int layer = blockIdx.y;
  const float* M = Mb + layer * 4096;
  const float* W = Wb + layer * 4096;
  int wid  = threadIdx.x >> 6;
  int lane = threadIdx.x & 63;
  int i = blockIdx.x * 4 + wid;
  int id = ids[i];
  float sv = svd[(size_t)id * DD + lane];
  float sgn = (sv > 0.0f) ? 1.0f : ((sv < 0.0f) ? -1.0f : 0.0f);
  float sd = sdiag[lane];

  float z1 = n1[(size_t)id * DD + lane];
  float z2 = n2[(size_t)id * DD + lane];
  float d1 = fmaxf(sqrtf(waveReduceSum(z1 * z1)), 1e-12f);
  float d2 = fmaxf(sqrtf(waveReduceSum(z2 * z2)), 1e-12f);
  float g1 = (sv + sgn * (z1 / d1) * EPS_) * sd;
  float g2 = (sv + sgn * (z2 / d2) * EPS_) * sd;

  float a1 = 0.0f, a2 = 0.0f;
#pragma unroll
  for (int k = 0; k < 64; ++k) {
    float m = M[k * DD + lane];
    a1 += rlanef(g1, k) * m;
    a2 += rlanef(g2, k) * m;
  }
  a1 = leaky(a1); a2 = leaky(a2);
  float s1 = fmaxf(sqrtf(waveReduceSum(a1 * a1)), 1e-12f);
  float s2 = fmaxf(sqrtf(waveReduceSum(a2 * a2)), 1e-12f);
  float gn1 = a1 / s1, gn2 = a2 / s2;

  float h1 = 0.0f, h2 = 0.0f;
#pragma unroll
  for (int k = 0; k < 64; ++k) {
    float w = W[k * DD + lane];
    h1 += rlanef(gn1, k) * w;
    h2 += rlanef(gn2, k) * w;
  }
  size_t b0 = ((size_t)(layer * 2 + 0) * BB + i) * DD + lane;
  size_t b1 = ((size_t)(layer * 2 + 1) * BB + i) * DD + lane;
  hout[b0] = h1;
  hout[b1] = h2;
}

// ===========================================================================
// score tiles: 64x64 tile of exp(S/T), row-sum partials (non-atomic)
// ===========================================================================
__global__ void score_tiles(const float* __restrict__ hu, const float* __restrict__ hv,
                            float* __restrict__ negpart) {
  __shared__ float s1[64][65];
  __shared__ float s2[64][65];
  int z = blockIdx.z;
  int layer = z >> 1, side = z & 1;
  const float* hb = side ? hv : hu;
  const float* h1 = hb + (size_t)(layer * 2 + 0) * BB * DD;
  const float* h2 = hb + (size_t)(layer * 2 + 1) * BB * DD;
  int i0 = blockIdx.x * 64, j0 = blockIdx.y * 64;
  int t = threadIdx.x;
#pragma unroll
  for (int k = 0; k < 16; ++k) {
    int lin = t + k * 256;
    int r = lin >> 6, c = lin & 63;
    s1[r][c] = h1[(size_t)(i0 + r) * DD + c];
    s2[r][c] = h2[(size_t)(j0 + r) * DD + c];
  }
  __syncthreads();
  int ti = t >> 4, tj = t & 15;
  float acc[4][4];
#pragma unroll
  for (int x = 0; x < 4; ++x)
#pragma unroll
    for (int y = 0; y < 4; ++y) acc[x][y] = 0.0f;
  for (int d = 0; d < 64; ++d) {
    float a[4], b[4];
#pragma unroll
    for (int k = 0; k < 4; ++k) { a[k] = s1[ti * 4 + k][d]; b[k] = s2[tj * 4 + k][d]; }
#pragma unroll
    for (int x = 0; x < 4; ++x)
#pragma unroll
      for (int y = 0; y < 4; ++y) acc[x][y] += a[x] * b[y];
  }
  float rsum[4];
#pragma unroll
  for (int x = 0; x < 4; ++x) {
    float s = 0.0f;
#pragma unroll
    for (int y = 0; y < 4; ++y) s += expf(acc[x][y] * (1.0f / TEMP_));
    rsum[x] = s;
  }
  __syncthreads();
#pragma unroll
  for (int x = 0; x < 4; ++x) s1[ti * 4 + x][tj] = rsum[x];
  __syncthreads();
  if (t < 64) {
    float s = 0.0f;
#pragma unroll
    for (int c = 0; c < 16; ++c) s += s1[t][c];
    negpart[((size_t)z * 32 + blockIdx.y) * BB + i0 + t] = s;
  }
}

__global__ void score_loss(const float* __restrict__ hu, const float* __restrict__ hv,
                           const float* __restrict__ negpart,
                           const float* __restrict__ u_mask, const float* __restrict__ i_mask,
                           float* __restrict__ loss_acc) {
  __shared__ float red[256];
  int z = blockIdx.y;
  int layer = z >> 1, side = z & 1;
  const float* hb = side ? hv : hu;
  const float* h1 = hb + (size_t)(layer * 2 + 0) * BB * DD;
  const float* h2 = hb + (size_t)(layer * 2 + 1) * BB * DD;
  const float* mask = (side ? i_mask : u_mask) + layer * BB;
  int i = blockIdx.x * 256 + threadIdx.x;
  const float4* a = (const float4*)(h1 + (size_t)i * DD);
  const float4* b = (const float4*)(h2 + (size_t)i * DD);
  float pos = 0.0f;
#pragma unroll
  for (int k = 0; k < 16; ++k) {
    float4 av = a[k], bv = b[k];
    pos += av.x * bv.x + av.y * bv.y + av.z * bv.z + av.w * bv.w;
  }
  float ng = 0.0f;
  for (int jt = 0; jt < 32; ++jt) ng += negpart[((size_t)z * 32 + jt) * BB + i];
  float ps = expf(pos * (1.0f / TEMP_));
  float m = (mask[i] > 0.5f) ? 1.0f : 0.0f;
  float li = -logf(ps / (ng + 1e-8f) + 1e-8f) * m;
  red[threadIdx.x] = li;
  __syncthreads();
  for (int ofs = 128; ofs >= 1; ofs >>= 1) {
    if (threadIdx.x < ofs) red[threadIdx.x] += red[threadIdx.x + ofs];
    __syncthreads();
  }
  if (threadIdx.x == 0) unsafeAtomicAdd(loss_acc, red[0]);
}

// ===========================================================================
// BPR
// ===========================================================================
__global__ void bpr_kernel(const float* __restrict__ Eu0, const float* __restrict__ EU1,
                           const float* __restrict__ bu,
                           const float* __restrict__ Ei0, const float* __restrict__ EI1,
                           const float* __restrict__ bpos, const float* __restrict__ bneg,
                           const int* __restrict__ uids, const int* __restrict__ pos,
                           const int* __restrict__ neg,
                           float* __restrict__ acc_r) {
  __shared__ float red[256];
  int i = blockIdx.x * 256 + threadIdx.x;
  const float4* u0 = (const float4*)(Eu0 + (size_t)uids[i] * DD);
  const float4* u1 = (const float4*)(EU1 + (size_t)uids[i] * DD);
  const float4* u2 = (const float4*)(bu  + (size_t)i * DD);
  const float4* p0 = (const float4*)(Ei0 + (size_t)pos[i] * DD);
  const float4* p1 = (const float4*)(EI1 + (size_t)pos[i] * DD);
  const float4* p2 = (const float4*)(bpos + (size_t)i * DD);
  const float4* n0 = (const float4*)(Ei0 + (size_t)neg[i] * DD);
  const float4* n1 = (const float4*)(EI1 + (size_t)neg[i] * DD);
  const float4* n2 = (const float4*)(bneg + (size_t)i * DD);
  float ps = 0.0f, ns = 0.0f;
#pragma unroll
  for (int k = 0; k < 16; ++k) {
    float4 ua = u0[k], ub = u1[k], uc = u2[k];
    float4 pa = p0[k], pb = p1[k], pc = p2[k];
    float4 na = n0[k], nb = n1[k], nc = n2[k];
    float ux = ua.x + ub.x + uc.x, uy = ua.y + ub.y + uc.y,
          uz = ua.z + ub.z + uc.z, uw = ua.w + ub.w + uc.w;
    ps += ux * (pa.x + pb.x + pc.x) + uy * (pa.y + pb.y + pc.y)
        + uz * (pa.z + pb.z + pc.z) + uw * (pa.w + pb.w + pc.w);
    ns += ux * (na.x + nb.x + nc.x) + uy * (na.y + nb.y + nc.y)
        + uz * (na.z + nb.z + nc.z) + uw * (na.w + nb.w + nc.w);
  }
  red[threadIdx.x] = fmaxf(1.0f - ps + ns, 0.0f);
  __syncthreads();
  for (int ofs = 128; ofs >= 1; ofs >>= 1) {
    if (threadIdx.x < ofs) red[threadIdx.x] += red[threadIdx.x + ofs];
    __syncthreads();
  }
  if (threadIdx.x == 0) unsafeAtomicAdd(acc_r, red[0]);
}

__global__ void finalize_kernel(const float* __restrict__ acc, float* __restrict__ out) {
  float lr = acc[0] / (float)BB;
  float ls = acc[1];
  out[0] = lr + LAM1 * ls;
  out[1] = lr;
  out[2] = ls;
}

// ===========================================================================
extern "C" void kernel_launch(void* const* d_in, const int* in_sizes, int n_in,
                              void* d_out, int out_size, void* d_ws, size_t ws_size,
                              hipStream_t stream) {
  const float* E_u_0   = (const float*)d_in[0];
  const float* E_i_0   = (const float*)d_in[1];
  const float* svd_u   = (const float*)d_in[2];
  const float* svd_v   = (const float*)d_in[3];
  const float* sdiag   = (const float*)d_in[4];
  const float* ut      = (const float*)d_in[5];
  const float* vt      = (const float*)d_in[6];
  const float* W_u     = (const float*)d_in[7];
  const float* W_i     = (const float*)d_in[8];
  const float* adjv    = (const float*)d_in[9];
  const float* dropr   = (const float*)d_in[10];
  const float* noise_u1= (const float*)d_in[11];
  const float* noise_v1= (const float*)d_in[12];
  const float* noise_u2= (const float*)d_in[13];
  const float* noise_v2= (const float*)d_in[14];
  const float* u_mask  = (const float*)d_in[15];
  const float* i_mask  = (const float*)d_in[16];
  const int*   rows    = (const int*)d_in[17];
  const int*   cols    = (const int*)d_in[18];
  const int*   uids    = (const int*)d_in[19];
  const int*   iids    = (const int*)d_in[20];
  const int*   pos     = (const int*)d_in[21];
  const int*   neg     = (const int*)d_in[22];
  float* out = (float*)d_out;

  // ---- workspace layout (~80 MB, with aliasing) ----
  float* ws     = (float*)d_ws;
  float* EU1    = ws;                           // 6,400,000
  float* EI1    = EU1 + (size_t)N_U * DD;       // 3,200,000
  float* vtei   = EI1 + (size_t)N_I * DD;       // 2*4096
  float* uteu   = vtei + 2 * DD * DD;           // 2*4096
  float* accs   = uteu + 2 * DD * DD;           // 16
  float* region = accs + 16;                    // REGION_SZ floats (time-shared)
  // phase A (gemm partials): (NCH_I+NCH_U)*4096 + 8*4096 = 1,957,888 < REGION_SZ
  float* Cp   = region;
  float* Cp2  = Cp + (size_t)(NCH_I + NCH_U) * 4096;
  // phase B (post-gemm buffers):
  float* bu   = region;                          // 131072
  float* bpos = bu   + (size_t)BB * DD;          // 131072
  float* bneg = bpos + (size_t)BB * DD;          // 131072
  float* hu   = bneg + (size_t)BB * DD;          // 524288
  float* hv   = hu   + (size_t)4 * BB * DD;      // 524288
  float* negp = hv   + (size_t)4 * BB * DD;      // 262144 (sum 1,703,936 < REGION_SZ)
  // split edge payloads (float2 per edge per side per layer): 8M floats total
  float2* pay1_u = (float2*)(region + (size_t)REGION_SZ);  // NNZ_
  float2* pay2_u = pay1_u + NNZ_;
  float2* pay1_i = pay2_u + NNZ_;
  float2* pay2_i = pay1_i + NNZ_;
  int* off_u   = (int*)(pay2_i + NNZ_);          // 100,001
  int* off_i   = off_u + (N_U + 1);              // 50,001
  int* bcur_u  = off_i + (N_I + 1);              // 391
  int* bcur_i  = bcur_u + NBK;                   // 391
  int* bbase_u = bcur_i + NBK;                   // 392
  int* bbase_i = bbase_u + (NBK + 1);            // 392
  // staging buffers alias EU1/EI1 (dead until spmm_all): 2M float4 = 8M floats
  float4* stg_u = (float4*)ws;
  float4* stg_i = stg_u + NNZ_;
  // bucket-hist partials alias region (dead before gemm): 256*782 ints = 800KB
  int* bh = (int*)region;

  const int TB = 256;
  dim3 blk(TB);
  int row_grid = BB / 4;

  hipMemsetAsync(accs, 0, 16 * sizeof(float), stream);

  // ---- CSR build v3: bucket hist -> bucket scan -> bin -> final ----
  bhist<<<BH_BLOCKS, blk, 0, stream>>>(rows, cols, bh);
  bscan<<<1, blk, 0, stream>>>(bh, bbase_u, bbase_i, bcur_u, bcur_i);
  {
    int c1g = (NNZ_ + C1_CHUNK - 1) / C1_CHUNK;   // 326
    csr_bin<<<c1g, C1_THREADS, 0, stream>>>(rows, cols, adjv,
        dropr, dropr + (size_t)2 * NNZ_, bbase_u, bcur_u, stg_u, SH_U);
    csr_bin<<<c1g, C1_THREADS, 0, stream>>>(cols, rows, adjv,
        dropr + (size_t)NNZ_, dropr + (size_t)3 * NNZ_, bbase_i, bcur_i, stg_i, SH_I);
    csr_final<<<NBK, blk, 0, stream>>>(stg_u, bbase_u, pay1_u, pay2_u, off_u, N_U, SH_U);
    csr_final<<<NBK, blk, 0, stream>>>(stg_i, bbase_i, pay1_i, pay2_i, off_i, N_I, SH_I);
  }

  // ---- layer-1 small GEMMs (async-staged split-K, 2-stage reduce) ----
  gemm_tiled<<<NCH_I + NCH_U, blk, 0, stream>>>(vt, E_i_0, ut, E_u_0, Cp);
  gemm_reduce_s1<<<dim3(16, 2, 4), blk, 0, stream>>>(Cp, Cp2);
  gemm_reduce_s2<<<dim3(16, 2), blk, 0, stream>>>(Cp2, vtei, uteu);

  // ---- layer-1 full SpMM, both sides fused ----
  spmm_all<<<(N_U + N_I + 3) / 4, blk, 0, stream>>>(off_u, pay1_u, off_i, pay1_i,
                                                    E_u_0, E_i_0, EU1, EI1);

  // ---- layer-2 small GEMMs ----
  gemm_tiled<<<NCH_I + NCH_U, blk, 0, stream>>>(vt, EI1, ut, EU1, Cp);
  gemm_reduce_s1<<<dim3(16, 2, 4), blk, 0, stream>>>(Cp, Cp2);
  gemm_reduce_s2<<<dim3(16, 2), blk, 0, stream>>>(Cp2, vtei + 4096, uteu + 4096);

  // ---- layer-2 SpMM at batch rows only (region now free for phase B) ----
  spmm_batch3<<<dim3(row_grid, 3), blk, 0, stream>>>(uids, pos, neg,
      off_u, pay2_u, off_i, pay2_i, EU1, EI1, bu, bpos, bneg);

  // ---- contrastive ----
  h_kernel2<<<dim3(row_grid, LL), blk, 0, stream>>>(svd_u, noise_u1, noise_u2, sdiag,
                                                    vtei, W_u, uids, hu);
  h_kernel2<<<dim3(row_grid, LL), blk, 0, stream>>>(svd_v, noise_v1, noise_v2, sdiag,
                                                    uteu, W_i, iids, hv);
  score_tiles<<<dim3(32, 32, 4), blk, 0, stream>>>(hu, hv, negp);
  score_loss<<<dim3(8, 4), blk, 0, stream>>>(hu, hv, negp, u_mask, i_mask, accs + 1);

  // ---- BPR ----
  bpr_kernel<<<8, blk, 0, stream>>>(E_u_0, EU1, bu, E_i_0, EI1, bpos, bneg,
                                    uids, pos, neg, accs);

  finalize_kernel<<<1, 1, 0, stream>>>(accs, out);
}

// Round 8
// 589.077 us; speedup vs baseline: 1.7667x; 1.0604x over previous
//
#include <hip/hip_runtime.h>
#include <cstddef>

// ---- problem constants (from reference) ----
#define N_U   100000
#define N_I   50000
#define DD    64
#define NNZ_  1000000
#define LL    2
#define TEMP_ 0.2f
#define LAM1  0.2f
#define DROP_ 0.1f
#define EPS_  0.05f
#define BB    2048
#define KCH   320
#define NCH_I ((N_I + KCH - 1) / KCH)   /* 157 */
#define NCH_U ((N_U + KCH - 1) / KCH)   /* 313 */
#define REGION_SZ 2097152               /* floats, time-shared scratch */

// CSR binning constants
#define NBK   391        /* buckets per side: u 256 rows (shift 8), i 128 rows (shift 7) */
#define SH_U  8
#define SH_I  7
#define C1_CHUNK   3072  /* 48KB LDS staging */
#define C1_THREADS 512
#define C1_EPT     6     /* edges per thread = C1_CHUNK / C1_THREADS */
#define BH_BLOCKS  256

__device__ __forceinline__ float leaky(float x) { return x >= 0.0f ? x : 0.5f * x; }

__device__ __forceinline__ float waveReduceSum(float v) {
#pragma unroll
  for (int m = 32; m >= 1; m >>= 1) v += __shfl_xor(v, m, 64);
  return v;
}

__device__ __forceinline__ int rlanei(int v, int l) {
  return __builtin_amdgcn_readlane(v, l);
}
__device__ __forceinline__ float rlanef(float v, int l) {
  return __int_as_float(__builtin_amdgcn_readlane(__float_as_int(v), l));
}

// async global->LDS, 16B per lane. LDS dest is wave-uniform base; HW adds lane*16.
__device__ __forceinline__ void gload_lds16(const float* g, float* l) {
  __builtin_amdgcn_global_load_lds(
      (const __attribute__((address_space(1))) void*)g,
      (__attribute__((address_space(3))) void*)l, 16, 0, 0);
}

// ===========================================================================
// CSR build v3 (both sides fused per launch via blockIdx.y).
// Staging record: float4 { bitcast(gather_id), k_l1, k_l2, bitcast(row) }.
// ===========================================================================
__global__ void bhist(const int* __restrict__ rows, const int* __restrict__ cols,
                      int* __restrict__ bh) {
  __shared__ int lh[2 * NBK];
  int t = threadIdx.x;
  for (int j = t; j < 2 * NBK; j += 256) lh[j] = 0;
  __syncthreads();
  for (int e = blockIdx.x * 256 + t; e < NNZ_; e += BH_BLOCKS * 256) {
    atomicAdd(&lh[rows[e] >> SH_U], 1);
    atomicAdd(&lh[NBK + (cols[e] >> SH_I)], 1);
  }
  __syncthreads();
  for (int j = t; j < 2 * NBK; j += 256) bh[blockIdx.x * (2 * NBK) + j] = lh[j];
}

__global__ void bscan(const int* __restrict__ bh,
                      int* __restrict__ bbase_u, int* __restrict__ bbase_i,
                      int* __restrict__ bcur_u, int* __restrict__ bcur_i) {
  __shared__ int tot[2 * NBK];
  __shared__ int sc[512];
  int t = threadIdx.x;   // 256
  for (int j = t; j < 2 * NBK; j += 256) {
    int s = 0;
    for (int k = 0; k < BH_BLOCKS; ++k) s += bh[k * (2 * NBK) + j];
    tot[j] = s;
  }
  __syncthreads();
  // ---- side u ----
  sc[t] = (t < NBK) ? tot[t] : 0;
  sc[t + 256] = (t + 256 < NBK) ? tot[t + 256] : 0;
  __syncthreads();
  for (int ofs = 1; ofs < 512; ofs <<= 1) {
    int a = (t >= ofs) ? sc[t - ofs] : 0;
    int b = (t + 256 >= ofs) ? sc[t + 256 - ofs] : 0;
    __syncthreads();
    sc[t] += a; sc[t + 256] += b;
    __syncthreads();
  }
  if (t == 0) bbase_u[0] = 0;
  for (int j = t; j < NBK; j += 256) bbase_u[j + 1] = sc[j];
  __syncthreads();
  // ---- side i ----
  sc[t] = (t < NBK) ? tot[NBK + t] : 0;
  sc[t + 256] = (t + 256 < NBK) ? tot[NBK + t + 256] : 0;
  __syncthreads();
  for (int ofs = 1; ofs < 512; ofs <<= 1) {
    int a = (t >= ofs) ? sc[t - ofs] : 0;
    int b = (t + 256 >= ofs) ? sc[t + 256 - ofs] : 0;
    __syncthreads();
    sc[t] += a; sc[t + 256] += b;
    __syncthreads();
  }
  if (t == 0) bbase_i[0] = 0;
  for (int j = t; j < NBK; j += 256) bbase_i[j + 1] = sc[j];
  for (int j = t; j < NBK; j += 256) { bcur_u[j] = 0; bcur_i[j] = 0; }
}

// bucket-binned staging; blockIdx.y = side (0:u, 1:i).
__global__ __launch_bounds__(C1_THREADS)
void csr_bin(const int* __restrict__ rows, const int* __restrict__ cols,
             const float* __restrict__ vals, const float* __restrict__ dropr,
             const int* __restrict__ bbase_u, const int* __restrict__ bbase_i,
             int* __restrict__ bcur_u, int* __restrict__ bcur_i,
             float4* __restrict__ stg_u, float4* __restrict__ stg_i) {
  int side = blockIdx.y;
  const int* rws = side ? cols : rows;
  const int* oth = side ? rows : cols;
  const float* dA = dropr + (side ? (size_t)NNZ_ : 0);
  const float* dB = dropr + (side ? (size_t)3 * NNZ_ : (size_t)2 * NNZ_);
  const int* bbase = side ? bbase_i : bbase_u;
  int* bcur = side ? bcur_i : bcur_u;
  float4* stg = side ? stg_i : stg_u;
  int shift = side ? SH_I : SH_U;

  __shared__ float4 st[C1_CHUNK];                       // 48 KB
  __shared__ int hist[NBK], lbase[NBK], cur2[NBK], slab[NBK], lboff[NBK];
  __shared__ int sc[512];
  int t = threadIdx.x;
  int e0 = blockIdx.x * C1_CHUNK;
  int n = min(C1_CHUNK, NNZ_ - e0);
  for (int b = t; b < NBK; b += C1_THREADS) { hist[b] = 0; cur2[b] = 0; }
  __syncthreads();
  int myr[C1_EPT], myo[C1_EPT];
  float mk1[C1_EPT], mk2[C1_EPT];
#pragma unroll
  for (int k = 0; k < C1_EPT; ++k) {
    int li = t + k * C1_THREADS;
    if (li < n) {
      int e = e0 + li;
      int r = rws[e];
      myr[k] = r;
      myo[k] = oth[e];
      float v = vals[e] * (1.0f / (1.0f - DROP_));
      mk1[k] = (dA[e] >= DROP_) ? v : 0.0f;
      mk2[k] = (dB[e] >= DROP_) ? v : 0.0f;
      atomicAdd(&hist[r >> shift], 1);
    } else {
      myr[k] = -1;
    }
  }
  __syncthreads();
  sc[t] = (t < NBK) ? hist[t] : 0;
  __syncthreads();
  for (int ofs = 1; ofs < 512; ofs <<= 1) {
    int x = (t >= ofs) ? sc[t - ofs] : 0;
    __syncthreads();
    sc[t] += x;
    __syncthreads();
  }
  if (t < NBK) {
    lbase[t] = (t == 0) ? 0 : sc[t - 1];
    lboff[t] = bbase[t];
    if (hist[t] > 0) slab[t] = atomicAdd(&bcur[t], hist[t]);
  }
  __syncthreads();
#pragma unroll
  for (int k = 0; k < C1_EPT; ++k) {
    if (myr[k] >= 0) {
      int b = myr[k] >> shift;
      int pos = lbase[b] + atomicAdd(&cur2[b], 1);
      st[pos] = make_float4(__int_as_float(myo[k]), mk1[k], mk2[k],
                            __int_as_float(myr[k]));
    }
  }
  __syncthreads();
  for (int s = t; s < n; s += C1_THREADS) {
    float4 rec = st[s];
    int r = __float_as_int(rec.w);
    int b = r >> shift;
    stg[(size_t)lboff[b] + slab[b] + (s - lbase[b])] = rec;
  }
}

// per-bucket finalize; blockIdx.y = side.
__global__ void csr_final(const float4* __restrict__ stg_u, const float4* __restrict__ stg_i,
                          const int* __restrict__ bbase_u, const int* __restrict__ bbase_i,
                          float2* __restrict__ pay1_u, float2* __restrict__ pay2_u,
                          float2* __restrict__ pay1_i, float2* __restrict__ pay2_i,
                          int* __restrict__ off_u, int* __restrict__ off_i) {
  int side = blockIdx.y;
  const float4* stg = side ? stg_i : stg_u;
  const int* bbase = side ? bbase_i : bbase_u;
  float2* pay1 = side ? pay1_i : pay1_u;
  float2* pay2 = side ? pay2_i : pay2_u;
  int* off = side ? off_i : off_u;
  int N = side ? N_I : N_U;
  int shift = side ? SH_I : SH_U;

  __shared__ int h[256], incl[256], cur[256];
  int b = blockIdx.x;
  int t = threadIdx.x;
  int r0 = b << shift;
  int nrows = min(1 << shift, N - r0);
  int lo = bbase[b], hi = bbase[b + 1];
  h[t] = 0; cur[t] = 0;
  __syncthreads();
  for (int i = lo + t; i < hi; i += 256)
    atomicAdd(&h[__float_as_int(stg[i].w) - r0], 1);
  __syncthreads();
  incl[t] = h[t];
  __syncthreads();
  for (int ofs = 1; ofs < 256; ofs <<= 1) {
    int a = (t >= ofs) ? incl[t - ofs] : 0;
    __syncthreads();
    incl[t] += a;
    __syncthreads();
  }
  if (b == 0 && t == 0) off[0] = 0;
  if (t < nrows) off[r0 + t + 1] = lo + incl[t];
  for (int i = lo + t; i < hi; i += 256) {
    float4 rec = stg[i];
    int L = __float_as_int(rec.w) - r0;
    int pos = lo + (incl[L] - h[L]) + atomicAdd(&cur[L], 1);
    pay1[pos] = make_float2(rec.x, rec.y);
    pay2[pos] = make_float2(rec.x, rec.z);
  }
}

// ===========================================================================
// SpMM gather core: 16-lane x float4 layout. Wave processes 4 edges per load
// instruction (lane = 16*g + s: edge-group g, dims [4s,4s+4)); weights/ids
// distributed via shfl (2 bpermute / 4 edges vs 8 readlane); cross-group
// xor-reduce at the end. ~4x fewer gather instructions than lane-per-dim.
// ===========================================================================
__device__ __forceinline__ float4 spmm_gather(const int* __restrict__ off,
                                              const float2* __restrict__ pay,
                                              const float* __restrict__ Esrc,
                                              int r, int lane, int g, int s) {
  int i0 = off[r], i1 = off[r + 1];
  float4 acc = make_float4(0.f, 0.f, 0.f, 0.f);
  for (int p = i0; p < i1; p += 64) {
    int cn = min(64, i1 - p);
    float dvl = 0.0f; int gl = 0;
    if (lane < cn) {
      float2 pl = pay[p + lane];
      gl = __float_as_int(pl.x);
      dvl = pl.y;
    }
    // invalid edge slots hold gl=0, dvl=0 -> harmless gather of row 0, weight 0
    for (int j = 0; j < cn; j += 8) {
      int ga = __shfl(gl, j + g, 64);
      float da = __shfl(dvl, j + g, 64);
      int gb = __shfl(gl, j + 4 + g, 64);
      float db = __shfl(dvl, j + 4 + g, 64);
      float4 ea = *((const float4*)(Esrc + (size_t)ga * DD) + s);
      float4 eb = *((const float4*)(Esrc + (size_t)gb * DD) + s);
      acc.x += da * ea.x; acc.y += da * ea.y; acc.z += da * ea.z; acc.w += da * ea.w;
      acc.x += db * eb.x; acc.y += db * eb.y; acc.z += db * eb.z; acc.w += db * eb.w;
    }
  }
#pragma unroll
  for (int m = 16; m <= 32; m <<= 1) {
    acc.x += __shfl_xor(acc.x, m, 64);
    acc.y += __shfl_xor(acc.y, m, 64);
    acc.z += __shfl_xor(acc.z, m, 64);
    acc.w += __shfl_xor(acc.w, m, 64);
  }
  return acc;
}

// Layer-1 SpMM, both sides in one launch. One wave per row.
__global__ void spmm_all(const int* __restrict__ off_u, const float2* __restrict__ pu,
                         const int* __restrict__ off_i, const float2* __restrict__ pi,
                         const float* __restrict__ Eu0, const float* __restrict__ Ei0,
                         float* __restrict__ EU1, float* __restrict__ EI1) {
  int wid = threadIdx.x >> 6, lane = threadIdx.x & 63;
  int g = lane >> 4, s = lane & 15;
  int r = blockIdx.x * 4 + wid;
  const int* off; const float2* pay;
  const float* Esrc; const float* base; float* outp;
  if (r < N_U) {
    off = off_u; pay = pu; Esrc = Ei0; base = Eu0; outp = EU1;
  } else {
    r -= N_U;
    if (r >= N_I) return;
    off = off_i; pay = pi; Esrc = Eu0; base = Ei0; outp = EI1;
  }
  float4 acc = spmm_gather(off, pay, Esrc, r, lane, g, s);
  if (g == 0) {
    float4 bb = *((const float4*)(base + (size_t)r * DD) + s);
    float4 o;
    o.x = bb.x + leaky(acc.x); o.y = bb.y + leaky(acc.y);
    o.z = bb.z + leaky(acc.z); o.w = bb.w + leaky(acc.w);
    *((float4*)(outp + (size_t)r * DD) + s) = o;
  }
}

// Layer-2 SpMM at gathered batch rows (uids | pos | neg via blockIdx.y).
__global__ void spmm_batch3(const int* __restrict__ uids, const int* __restrict__ pos,
                            const int* __restrict__ neg,
                            const int* __restrict__ off_u, const float2* __restrict__ pu2,
                            const int* __restrict__ off_i, const float2* __restrict__ pi2,
                            const float* __restrict__ EU1, const float* __restrict__ EI1,
                            float* __restrict__ bu, float* __restrict__ bpos,
                            float* __restrict__ bneg) {
  int z = blockIdx.y;
  const int* ids = (z == 0) ? uids : ((z == 1) ? pos : neg);
  const int* off = (z == 0) ? off_u : off_i;
  const float2* pay = (z == 0) ? pu2 : pi2;
  const float* Esrc = (z == 0) ? EI1 : EU1;
  const float* base = (z == 0) ? EU1 : EI1;
  float* outp = (z == 0) ? bu : ((z == 1) ? bpos : bneg);
  int wid = threadIdx.x >> 6, lane = threadIdx.x & 63;
  int g = lane >> 4, s = lane & 15;
  int i = blockIdx.x * 4 + wid;
  int r = ids[i];
  float4 acc = spmm_gather(off, pay, Esrc, r, lane, g, s);
  if (g == 0) {
    float4 bb = *((const float4*)(base + (size_t)r * DD) + s);
    float4 o;
    o.x = bb.x + leaky(acc.x); o.y = bb.y + leaky(acc.y);
    o.z = bb.z + leaky(acc.z); o.w = bb.w + leaky(acc.w);
    *((float4*)(outp + (size_t)i * DD) + s) = o;
  }
}

// ===========================================================================
// Split-K dual GEMM with async global->LDS staging + LDS double-buffer.
// ===========================================================================
__global__ void gemm_tiled(const float* __restrict__ A0, const float* __restrict__ B0,
                           const float* __restrict__ A1, const float* __restrict__ B1,
                           float* __restrict__ Cp) {
  __shared__ __align__(16) float sA[2][4096];
  __shared__ __align__(16) float sB[2][4096];
  int bx = blockIdx.x;
  const float* A; const float* B; int N; int k0;
  if (bx < NCH_I) { A = A0; B = B0; N = N_I; k0 = bx * KCH; }
  else            { A = A1; B = B1; N = N_U; k0 = (bx - NCH_I) * KCH; }
  int t = threadIdx.x;
  int w = t >> 6, l = t & 63;
  int rseg = l >> 4;
  int c4 = (l & 15) * 4;
  int ti = t >> 4, tj = t & 15;
  int ti4 = ti * 4, tj4 = tj * 4;

  int NT = min(KCH / 64, (N - k0 + 63) >> 6);

  float acc[4][4];
#pragma unroll
  for (int x = 0; x < 4; ++x)
#pragma unroll
    for (int y = 0; y < 4; ++y) acc[x][y] = 0.0f;

  auto stage = [&](int tt, int b) {
    int kb = k0 + tt * 64;
    if (kb + 64 <= N) {
#pragma unroll
      for (int q = 0; q < 4; ++q) {
        int s = w * 4 + q;
        const float* ga = A + (size_t)(s * 4 + rseg) * N + kb + c4;
        gload_lds16(ga, &sA[b][s * 256]);
        const float* gb = B + (size_t)(kb + s * 4 + rseg) * DD + c4;
        gload_lds16(gb, &sB[b][s * 256]);
      }
    } else {
#pragma unroll
      for (int q = 0; q < 16; ++q) {
        int lin = t + q * 256;
        int r = lin >> 6, c = lin & 63;
        sA[b][lin] = (kb + c < N) ? A[(size_t)r * N + kb + c] : 0.0f;
        sB[b][lin] = (kb + r < N) ? B[(size_t)(kb + r) * DD + c] : 0.0f;
      }
    }
  };

  stage(0, 0);
  __syncthreads();
  int cur = 0;
  for (int tt = 0; tt < NT; ++tt) {
    if (tt + 1 < NT) stage(tt + 1, cur ^ 1);
    const float* cA = sA[cur];
    const float* cB = sB[cur];
#pragma unroll 8
    for (int k = 0; k < 64; ++k) {
      float4 b4 = *(const float4*)&cB[k * 64 + tj4];
      float a0 = cA[(ti4 + 0) * 64 + k];
      float a1 = cA[(ti4 + 1) * 64 + k];
      float a2 = cA[(ti4 + 2) * 64 + k];
      float a3 = cA[(ti4 + 3) * 64 + k];
      acc[0][0] += a0 * b4.x; acc[0][1] += a0 * b4.y; acc[0][2] += a0 * b4.z; acc[0][3] += a0 * b4.w;
      acc[1][0] += a1 * b4.x; acc[1][1] += a1 * b4.y; acc[1][2] += a1 * b4.z; acc[1][3] += a1 * b4.w;
      acc[2][0] += a2 * b4.x; acc[2][1] += a2 * b4.y; acc[2][2] += a2 * b4.z; acc[2][3] += a2 * b4.w;
      acc[3][0] += a3 * b4.x; acc[3][1] += a3 * b4.y; acc[3][2] += a3 * b4.z; acc[3][3] += a3 * b4.w;
    }
    __syncthreads();
    cur ^= 1;
  }

  float* cp = Cp + (size_t)bx * 4096;
#pragma unroll
  for (int x = 0; x < 4; ++x)
#pragma unroll
    for (int y = 0; y < 4; ++y)
      cp[(ti4 + x) * DD + tj4 + y] = acc[x][y];
}

__global__ void gemm_reduce_s1(const float* __restrict__ Cp, float* __restrict__ Cp2) {
  int y = blockIdx.y, z = blockIdx.z;
  const float* base = Cp + (y ? (size_t)NCH_I * 4096 : 0);
  int cnt = y ? NCH_U : NCH_I;
  int chunk = (cnt + 3) >> 2;
  int b0 = z * chunk, b1 = min(b0 + chunk, cnt);
  int idx = blockIdx.x * 256 + threadIdx.x;
  float s = 0.0f;
  for (int b = b0; b < b1; ++b) s += base[(size_t)b * 4096 + idx];
  Cp2[((size_t)(y * 4 + z)) * 4096 + idx] = s;
}

__global__ void gemm_reduce_s2(const float* __restrict__ Cp2,
                               float* __restrict__ C0, float* __restrict__ C1) {
  int y = blockIdx.y;
  float* C = y ? C1 : C0;
  int idx = blockIdx.x * 256 + threadIdx.x;
  float s = 0.0f;
#pragma unroll
  for (int z = 0; z < 4; ++z) s += Cp2[((size_t)(y * 4 + z)) * 4096 + idx];
  C[idx] = s;
}

// ===========================================================================
// h for both views, both layers, both sides (blockIdx.z = side).
// hout [layer][view][BB][64].
// ===========================================================================
__global__ void h_kernel2(const float* __restrict__ svd_u, const float* __restrict__ svd_v,
                          const float* __restrict__ n1u, const float* __restrict__ n2u,
                          const float* __restrict__ n1v, const float* __restrict__ n2v,
                          const float* __restrict__ sdiag,
                          const float* __restrict__ Mu, const float* __restrict__ Mv,
                          const float* __restrict__ Wu, const float* __restrict__ Wv,
                          const int* __restrict__ uids, const int* __restrict__ iids,
                          float* __restrict__ hu, float* __restrict__ hv) {
  int side = blockIdx.z;
  const float* svd = side ? svd_v : svd_u;
  const float* n1 = side ? n1v : n1u;
  const float* n2 = side ? n2v : n2u;
  const float* Mb = side ? Mv : Mu;
  const float* Wb = side ? Wv : Wu;
  const int* ids = side ? iids : uids;
  float* hout = side ? hv : hu;

  int layer = blockIdx.y;
  const float* M = Mb + layer * 4096;
  const float* W = Wb + layer * 4096;
  int wid  = threadIdx.x >> 6;
  int lane = threadIdx.x & 63;
  int i = blockIdx.x * 4 + wid;
  int id = ids[i];
  float sv = svd[(size_t)id * DD + lane];
  float sgn = (sv > 0.0f) ? 1.0f : ((sv < 0.0f) ? -1.0f : 0.0f);
  float sd = sdiag[lane];

  float z1 = n1[(size_t)id * DD + lane];
  float z2 = n2[(size_t)id * DD + lane];
  float d1 = fmaxf(sqrtf(waveReduceSum(z1 * z1)), 1e-12f);
  float d2 = fmaxf(sqrtf(waveReduceSum(z2 * z2)), 1e-12f);
  float g1 = (sv + sgn * (z1 / d1) * EPS_) * sd;
  float g2 = (sv + sgn * (z2 / d2) * EPS_) * sd;

  float a1 = 0.0f, a2 = 0.0f;
#pragma unroll
  for (int k = 0; k < 64; ++k) {
    float m = M[k * DD + lane];
    a1 += rlanef(g1, k) * m;
    a2 += rlanef(g2, k) * m;
  }
  a1 = leaky(a1); a2 = leaky(a2);
  float s1 = fmaxf(sqrtf(waveReduceSum(a1 * a1)), 1e-12f);
  float s2 = fmaxf(sqrtf(waveReduceSum(a2 * a2)), 1e-12f);
  float gn1 = a1 / s1, gn2 = a2 / s2;

  float h1 = 0.0f, h2 = 0.0f;
#pragma unroll
  for (int k = 0; k < 64; ++k) {
    float w = W[k * DD + lane];
    h1 += rlanef(gn1, k) * w;
    h2 += rlanef(gn2, k) * w;
  }
  size_t b0 = ((size_t)(layer * 2 + 0) * BB + i) * DD + lane;
  size_t b1 = ((size_t)(layer * 2 + 1) * BB + i) * DD + lane;
  hout[b0] = h1;
  hout[b1] = h2;
}

// ===========================================================================
// score tiles: 64x64 tile of exp(S/T), row-sum partials (non-atomic)
// ===========================================================================
__global__ void score_tiles(const float* __restrict__ hu, const float* __restrict__ hv,
                            float* __restrict__ negpart) {
  __shared__ float s1[64][65];
  __shared__ float s2[64][65];
  int z = blockIdx.z;
  int layer = z >> 1, side = z & 1;
  const float* hb = side ? hv : hu;
  const float* h1 = hb + (size_t)(layer * 2 + 0) * BB * DD;
  const float* h2 = hb + (size_t)(layer * 2 + 1) * BB * DD;
  int i0 = blockIdx.x * 64, j0 = blockIdx.y * 64;
  int t = threadIdx.x;
#pragma unroll
  for (int k = 0; k < 16; ++k) {
    int lin = t + k * 256;
    int r = lin >> 6, c = lin & 63;
    s1[r][c] = h1[(size_t)(i0 + r) * DD + c];
    s2[r][c] = h2[(size_t)(j0 + r) * DD + c];
  }
  __syncthreads();
  int ti = t >> 4, tj = t & 15;
  float acc[4][4];
#pragma unroll
  for (int x = 0; x < 4; ++x)
#pragma unroll
    for (int y = 0; y < 4; ++y) acc[x][y] = 0.0f;
  for (int d = 0; d < 64; ++d) {
    float a[4], b[4];
#pragma unroll
    for (int k = 0; k < 4; ++k) { a[k] = s1[ti * 4 + k][d]; b[k] = s2[tj * 4 + k][d]; }
#pragma unroll
    for (int x = 0; x < 4; ++x)
#pragma unroll
      for (int y = 0; y < 4; ++y) acc[x][y] += a[x] * b[y];
  }
  float rsum[4];
#pragma unroll
  for (int x = 0; x < 4; ++x) {
    float s = 0.0f;
#pragma unroll
    for (int y = 0; y < 4; ++y) s += expf(acc[x][y] * (1.0f / TEMP_));
    rsum[x] = s;
  }
  __syncthreads();
#pragma unroll
  for (int x = 0; x < 4; ++x) s1[ti * 4 + x][tj] = rsum[x];
  __syncthreads();
  if (t < 64) {
    float s = 0.0f;
#pragma unroll
    for (int c = 0; c < 16; ++c) s += s1[t][c];
    negpart[((size_t)z * 32 + blockIdx.y) * BB + i0 + t] = s;
  }
}

__global__ void score_loss(const float* __restrict__ hu, const float* __restrict__ hv,
                           const float* __restrict__ negpart,
                           const float* __restrict__ u_mask, const float* __restrict__ i_mask,
                           float* __restrict__ loss_acc) {
  __shared__ float red[256];
  int z = blockIdx.y;
  int layer = z >> 1, side = z & 1;
  const float* hb = side ? hv : hu;
  const float* h1 = hb + (size_t)(layer * 2 + 0) * BB * DD;
  const float* h2 = hb + (size_t)(layer * 2 + 1) * BB * DD;
  const float* mask = (side ? i_mask : u_mask) + layer * BB;
  int i = blockIdx.x * 256 + threadIdx.x;
  const float4* a = (const float4*)(h1 + (size_t)i * DD);
  const float4* b = (const float4*)(h2 + (size_t)i * DD);
  float pos = 0.0f;
#pragma unroll
  for (int k = 0; k < 16; ++k) {
    float4 av = a[k], bv = b[k];
    pos += av.x * bv.x + av.y * bv.y + av.z * bv.z + av.w * bv.w;
  }
  float ng = 0.0f;
  for (int jt = 0; jt < 32; ++jt) ng += negpart[((size_t)z * 32 + jt) * BB + i];
  float ps = expf(pos * (1.0f / TEMP_));
  float m = (mask[i] > 0.5f) ? 1.0f : 0.0f;
  float li = -logf(ps / (ng + 1e-8f) + 1e-8f) * m;
  red[threadIdx.x] = li;
  __syncthreads();
  for (int ofs = 128; ofs >= 1; ofs >>= 1) {
    if (threadIdx.x < ofs) red[threadIdx.x] += red[threadIdx.x + ofs];
    __syncthreads();
  }
  if (threadIdx.x == 0) unsafeAtomicAdd(loss_acc, red[0]);
}

// ===========================================================================
// BPR — one wave per batch item (512 blocks x 4 waves); lane = dim.
// ===========================================================================
__global__ void bpr_kernel(const float* __restrict__ Eu0, const float* __restrict__ EU1,
                           const float* __restrict__ bu,
                           const float* __restrict__ Ei0, const float* __restrict__ EI1,
                           const float* __restrict__ bpos, const float* __restrict__ bneg,
                           const int* __restrict__ uids, const int* __restrict__ pos,
                           const int* __restrict__ neg,
                           float* __restrict__ acc_r) {
  __shared__ float red[4];
  int wid = threadIdx.x >> 6, lane = threadIdx.x & 63;
  int i = blockIdx.x * 4 + wid;
  int u = uids[i], p = pos[i], n = neg[i];
  float ue = Eu0[(size_t)u * DD + lane] + EU1[(size_t)u * DD + lane]
           + bu[(size_t)i * DD + lane];
  float pe = Ei0[(size_t)p * DD + lane] + EI1[(size_t)p * DD + lane]
           + bpos[(size_t)i * DD + lane];
  float ne = Ei0[(size_t)n * DD + lane] + EI1[(size_t)n * DD + lane]
           + bneg[(size_t)i * DD + lane];
  float ps = waveReduceSum(ue * pe);
  float ns = waveReduceSum(ue * ne);
  if (lane == 0) red[wid] = fmaxf(1.0f - ps + ns, 0.0f);
  __syncthreads();
  if (threadIdx.x == 0)
    unsafeAtomicAdd(acc_r, red[0] + red[1] + red[2] + red[3]);
}

__global__ void finalize_kernel(const float* __restrict__ acc, float* __restrict__ out) {
  float lr = acc[0] / (float)BB;
  float ls = acc[1];
  out[0] = lr + LAM1 * ls;
  out[1] = lr;
  out[2] = ls;
}

// ===========================================================================
extern "C" void kernel_launch(void* const* d_in, const int* in_sizes, int n_in,
                              void* d_out, int out_size, void* d_ws, size_t ws_size,
                              hipStream_t stream) {
  const float* E_u_0   = (const float*)d_in[0];
  const float* E_i_0   = (const float*)d_in[1];
  const float* svd_u   = (const float*)d_in[2];
  const float* svd_v   = (const float*)d_in[3];
  const float* sdiag   = (const float*)d_in[4];
  const float* ut      = (const float*)d_in[5];
  const float* vt      = (const float*)d_in[6];
  const float* W_u     = (const float*)d_in[7];
  const float* W_i     = (const float*)d_in[8];
  const float* adjv    = (const float*)d_in[9];
  const float* dropr   = (const float*)d_in[10];
  const float* noise_u1= (const float*)d_in[11];
  const float* noise_v1= (const float*)d_in[12];
  const float* noise_u2= (const float*)d_in[13];
  const float* noise_v2= (const float*)d_in[14];
  const float* u_mask  = (const float*)d_in[15];
  const float* i_mask  = (const float*)d_in[16];
  const int*   rows    = (const int*)d_in[17];
  const int*   cols    = (const int*)d_in[18];
  const int*   uids    = (const int*)d_in[19];
  const int*   iids    = (const int*)d_in[20];
  const int*   pos     = (const int*)d_in[21];
  const int*   neg     = (const int*)d_in[22];
  float* out = (float*)d_out;

  // ---- workspace layout (~80 MB, with aliasing) ----
  float* ws     = (float*)d_ws;
  float* EU1    = ws;                           // 6,400,000
  float* EI1    = EU1 + (size_t)N_U * DD;       // 3,200,000
  float* vtei   = EI1 + (size_t)N_I * DD;       // 2*4096
  float* uteu   = vtei + 2 * DD * DD;           // 2*4096
  float* accs   = uteu + 2 * DD * DD;           // 16
  float* region = accs + 16;                    // REGION_SZ floats (time-shared)
  // phase A (gemm partials): (NCH_I+NCH_U)*4096 + 8*4096 = 1,957,888 < REGION_SZ
  float* Cp   = region;
  float* Cp2  = Cp + (size_t)(NCH_I + NCH_U) * 4096;
  // phase B (post-gemm buffers):
  float* bu   = region;                          // 131072
  float* bpos = bu   + (size_t)BB * DD;          // 131072
  float* bneg = bpos + (size_t)BB * DD;          // 131072
  float* hu   = bneg + (size_t)BB * DD;          // 524288
  float* hv   = hu   + (size_t)4 * BB * DD;      // 524288
  float* negp = hv   + (size_t)4 * BB * DD;      // 262144 (sum 1,703,936 < REGION_SZ)
  // split edge payloads (float2 per edge per side per layer): 8M floats total
  float2* pay1_u = (float2*)(region + (size_t)REGION_SZ);  // NNZ_
  float2* pay2_u = pay1_u + NNZ_;
  float2* pay1_i = pay2_u + NNZ_;
  float2* pay2_i = pay1_i + NNZ_;
  int* off_u   = (int*)(pay2_i + NNZ_);          // 100,001
  int* off_i   = off_u + (N_U + 1);              // 50,001
  int* bcur_u  = off_i + (N_I + 1);              // 391
  int* bcur_i  = bcur_u + NBK;                   // 391
  int* bbase_u = bcur_i + NBK;                   // 392
  int* bbase_i = bbase_u + (NBK + 1);            // 392
  // staging buffers alias EU1/EI1 (dead until spmm_all): 2M float4 = 8M floats
  float4* stg_u = (float4*)ws;
  float4* stg_i = stg_u + NNZ_;
  // bucket-hist partials alias region (dead before gemm): 256*782 ints = 800KB
  int* bh = (int*)region;

  const int TB = 256;
  dim3 blk(TB);
  int row_grid = BB / 4;

  hipMemsetAsync(accs, 0, 16 * sizeof(float), stream);

  // ---- CSR build v3: bucket hist -> bucket scan -> bin -> final ----
  bhist<<<BH_BLOCKS, blk, 0, stream>>>(rows, cols, bh);
  bscan<<<1, blk, 0, stream>>>(bh, bbase_u, bbase_i, bcur_u, bcur_i);
  {
    int c1g = (NNZ_ + C1_CHUNK - 1) / C1_CHUNK;   // 326
    csr_bin<<<dim3(c1g, 2), C1_THREADS, 0, stream>>>(rows, cols, adjv, dropr,
        bbase_u, bbase_i, bcur_u, bcur_i, stg_u, stg_i);
    csr_final<<<dim3(NBK, 2), blk, 0, stream>>>(stg_u, stg_i, bbase_u, bbase_i,
        pay1_u, pay2_u, pay1_i, pay2_i, off_u, off_i);
  }

  // ---- layer-1 small GEMMs (async-staged split-K, 2-stage reduce) ----
  gemm_tiled<<<NCH_I + NCH_U, blk, 0, stream>>>(vt, E_i_0, ut, E_u_0, Cp);
  gemm_reduce_s1<<<dim3(16, 2, 4), blk, 0, stream>>>(Cp, Cp2);
  gemm_reduce_s2<<<dim3(16, 2), blk, 0, stream>>>(Cp2, vtei, uteu);

  // ---- layer-1 full SpMM, both sides fused ----
  spmm_all<<<(N_U + N_I + 3) / 4, blk, 0, stream>>>(off_u, pay1_u, off_i, pay1_i,
                                                    E_u_0, E_i_0, EU1, EI1);

  // ---- layer-2 small GEMMs ----
  gemm_tiled<<<NCH_I + NCH_U, blk, 0, stream>>>(vt, EI1, ut, EU1, Cp);
  gemm_reduce_s1<<<dim3(16, 2, 4), blk, 0, stream>>>(Cp, Cp2);
  gemm_reduce_s2<<<dim3(16, 2), blk, 0, stream>>>(Cp2, vtei + 4096, uteu + 4096);

  // ---- layer-2 SpMM at batch rows only (region now free for phase B) ----
  spmm_batch3<<<dim3(row_grid, 3), blk, 0, stream>>>(uids, pos, neg,
      off_u, pay2_u, off_i, pay2_i, EU1, EI1, bu, bpos, bneg);

  // ---- contrastive ----
  h_kernel2<<<dim3(row_grid, LL, 2), blk, 0, stream>>>(svd_u, svd_v,
      noise_u1, noise_u2, noise_v1, noise_v2, sdiag,
      vtei, uteu, W_u, W_i, uids, iids, hu, hv);
  score_tiles<<<dim3(32, 32, 4), blk, 0, stream>>>(hu, hv, negp);
  score_loss<<<dim3(8, 4), blk, 0, stream>>>(hu, hv, negp, u_mask, i_mask, accs + 1);

  // ---- BPR ----
  bpr_kernel<<<row_grid, blk, 0, stream>>>(E_u_0, EU1, bu, E_i_0, EI1, bpos, bneg,
                                           uids, pos, neg, accs);

  finalize_kernel<<<1, 1, 0, stream>>>(accs, out);
}